// Round 6
// baseline (835.602 us; speedup 1.0000x reference)
//
#include <hip/hip_runtime.h>

typedef unsigned short u16;
typedef unsigned int   u32;
typedef __attribute__((ext_vector_type(8))) short bf16x8;
typedef __attribute__((ext_vector_type(4))) float f32x4;

#define MFMA16(a,b,c) __builtin_amdgcn_mfma_f32_16x16x32_bf16((a),(b),(c),0,0,0)

__device__ __forceinline__ float b2f(u32 h){ return __uint_as_float(h<<16); }
__device__ __forceinline__ u16 f2b(float f){
  u32 u = __float_as_uint(f);
  return (u16)((u + 0x7FFFu + ((u>>16)&1u))>>16);
}
__device__ __forceinline__ u32 pk2f(float a,float b){ return (u32)f2b(a) | ((u32)f2b(b)<<16); }
__device__ __forceinline__ u32 umin32(u32 a,u32 b){ return a<b?a:b; }
__device__ __forceinline__ u32 umax32(u32 a,u32 b){ return a>b?a:b; }

__device__ __forceinline__ void async_copy16(const void* g, void* l){
  __builtin_amdgcn_global_load_lds((const __attribute__((address_space(1))) u32*)g,
                                   (__attribute__((address_space(3))) u32*)l, 16, 0, 0);
}

// ---------------- workspace layout (bytes) ----------------
#define OFF_IDX    0ull
#define OFF_FEATB  1048576ull
#define OFF_WPRE   3145728ull
#define OFF_WQKV   3178496ull
#define OFF_WA1    3571712ull
#define OFF_WA2    3702784ull
#define OFF_WP2    3833856ull
#define OFF_WPROJ  3964928ull
#define OFF_WPOST  4096000ull
#define OFF_MCOMB  4128768ull
#define OFF_INP    4259840ull
#define OFF_QKV    12648448ull
#define OFF_LNQKV  37814272ull
#define OFF_QA     62980096ull
#define OFF_KA     71368704ull
#define OFF_RES    79757312ull
#define OFF_D1     88145920ull     // also hosts wp1pk early (d1 written only after attn)
#define OFF_R1     96534528ull
#define WS_NEED    104923136ull
#define OFF_WP1PK  OFF_D1
#define OFF_WP2T   OFF_QKV         // wp2^T consumed by mcomb GEMM before qkv GEMM writes here

// ---------------- f32 -> bf16 conversions ----------------
__global__ void convert_k(const float* __restrict__ feat, const float* __restrict__ wpre,
    const float* __restrict__ wq, const float* __restrict__ wk, const float* __restrict__ wv,
    const float* __restrict__ wa1, const float* __restrict__ wa2, const float* __restrict__ wp2,
    const float* __restrict__ wproj, const float* __restrict__ wpost,
    u16* __restrict__ dfeat, u16* __restrict__ dwpre, u16* __restrict__ dwqkv,
    u16* __restrict__ dwa1, u16* __restrict__ dwa2, u16* __restrict__ dwp2,
    u16* __restrict__ dwproj, u16* __restrict__ dwpost){
  int id = blockIdx.x*256 + threadIdx.x;
  const float* s; u16* d; int off;
  if      (id < 1048576){ s=feat;  d=dfeat;        off=id; }
  else if (id < 1064960){ s=wpre;  d=dwpre;        off=id-1048576; }
  else if (id < 1130496){ s=wq;    d=dwqkv;        off=id-1064960; }
  else if (id < 1196032){ s=wk;    d=dwqkv+65536;  off=id-1130496; }
  else if (id < 1261568){ s=wv;    d=dwqkv+131072; off=id-1196032; }
  else if (id < 1327104){ s=wa1;   d=dwa1;         off=id-1261568; }
  else if (id < 1392640){ s=wa2;   d=dwa2;         off=id-1327104; }
  else if (id < 1458176){ s=wp2;   d=dwp2;         off=id-1392640; }
  else if (id < 1523712){ s=wproj; d=dwproj;       off=id-1458176; }
  else if (id < 1540096){ s=wpost; d=dwpost;       off=id-1523712; }
  else return;
  d[off] = f2b(s[off]);
}

// 256x256 bf16 transpose (for Mcomb GEMM's B operand)
__global__ void transpose_k(const u16* __restrict__ in, u16* __restrict__ out){
  __shared__ u16 t[32][33];
  const int tid = threadIdx.x, tx = tid & 31, ty = tid >> 5;   // 8 rows
  const int bx = blockIdx.x & 7, by = blockIdx.x >> 3;
  #pragma unroll
  for (int r = 0; r < 4; ++r) t[ty+8*r][tx] = in[(by*32+ty+8*r)*256 + bx*32+tx];
  __syncthreads();
  #pragma unroll
  for (int r = 0; r < 4; ++r) out[(bx*32+ty+8*r)*256 + by*32+tx] = t[tx][ty+8*r];
}

// Wp1 packed for MFMA A-operand: [256 h][32 k] bf16, k=0..2 = Wp1[h][*], rest 0
__global__ void wp1pack_k(const float* __restrict__ wp1, u16* __restrict__ out){
  const int h = threadIdx.x;
  const float w0 = wp1[h*3], w1 = wp1[h*3+1], w2 = wp1[h*3+2];
  uint4 a; a.x = pk2f(w0,w1); a.y = pk2f(w2,0.f); a.z = 0u; a.w = 0u;
  uint4 z; z.x = z.y = z.z = z.w = 0u;
  *(uint4*)&out[h*32]    = a;
  *(uint4*)&out[h*32+8]  = z;
  *(uint4*)&out[h*32+16] = z;
  *(uint4*)&out[h*32+24] = z;
}

// ---------------- kNN: exact top-16 by (d2, idx) ----------------
__device__ __forceinline__ void ins16(u32 (&a)[16], u32 key){
  #pragma unroll
  for (int j = 15; j >= 1; --j) a[j] = umin32(umax32(a[j-1],key), a[j]);
  a[0] = umin32(a[0], key);
}

__device__ __forceinline__ float dist2(float ax,float ay,float az,float bx,float by,float bz){
  const float dx = ax-bx, dy = ay-by, dz = az-bz;
  return __fmaf_rn(dx,dx, __fmaf_rn(dy,dy, dz*dz));   // identical sequence both phases
}

__global__ __launch_bounds__(256,2) void knn_kernel(const float* __restrict__ xyz,
                                                    int* __restrict__ idxout){
  __shared__ __attribute__((aligned(16))) float sbuf[3*4104];
  __shared__ int lcnt[32];
  __shared__ int tcnt[32];
  __shared__ u32 tbuf[32];
  __shared__ int tiebuf[32*16];
  float* sx = sbuf; float* sy = sbuf + 4104; float* sz = sbuf + 8208;
  const int tid = threadIdx.x;
  const int b  = blockIdx.x >> 7;
  const int n0 = (blockIdx.x & 127) << 5;
  const float* base = xyz + (size_t)b*12288;
  #pragma unroll
  for (int i = 0; i < 12; ++i){
    const float4 v = *(const float4*)(base + tid*48 + i*4);
    const float vv[4] = {v.x, v.y, v.z, v.w};
    #pragma unroll
    for (int j = 0; j < 4; ++j){
      const int e = i*4 + j;
      const int c = e % 3;
      const int m = tid*16 + e/3;
      float* arr = (c==0)?sx:((c==1)?sy:sz);
      arr[m + (m>>9)] = vv[j];
    }
  }
  if (tid < 32){ lcnt[tid] = 0; tcnt[tid] = 0; }
  __syncthreads();
  const int qi = tid >> 3, p = tid & 7;
  const int n = n0 + qi;
  const int sn = n + (n>>9);
  const float qx = sx[sn], qy = sy[sn], qz = sz[sn];
  u32 a[16];
  #pragma unroll
  for (int j = 0; j < 16; ++j) a[j] = 0xFFFFFFFFu;
  const int sb = p*513;
  #pragma unroll 2
  for (int i = 0; i < 512; ++i){
    const float d2 = dist2(sx[sb+i],sy[sb+i],sz[sb+i],qx,qy,qz);
    ins16(a, __float_as_uint(d2));
  }
  #pragma unroll
  for (int s = 4; s >= 1; s >>= 1){
    u32 o[16];
    #pragma unroll
    for (int j = 0; j < 16; ++j) o[j] = __shfl_down(a[j], (unsigned)s, 64);
    if (p < s){
      #pragma unroll
      for (int j = 0; j < 16; ++j) ins16(a, o[j]);
    }
  }
  if (p == 0) tbuf[qi] = a[15];
  __syncthreads();
  const u32 T = tbuf[qi];
  int* orow = idxout + ((size_t)(b<<12)+n)*16;
  const int gbase = p*512;
  for (int i = 0; i < 512; ++i){
    const float d2 = dist2(sx[sb+i],sy[sb+i],sz[sb+i],qx,qy,qz);
    const u32 kb = __float_as_uint(d2);
    if (kb < T){
      const int pos = atomicAdd(&lcnt[qi],1);
      if (pos < 16) orow[pos] = gbase + i;
    } else if (kb == T){
      const int t = atomicAdd(&tcnt[qi],1);
      if (t < 16) tiebuf[qi*16+t] = gbase + i;
    }
  }
  __syncthreads();
  if (p == 0){
    int L = lcnt[qi]; if (L > 16) L = 16;
    int tc = tcnt[qi]; if (tc > 16) tc = 16;
    const int need = 16 - L;
    for (int r = 0; r < need; ++r){
      int best = 0x7FFFFFFF, bj = -1;
      for (int j = 0; j < tc; ++j){
        const int v = tiebuf[qi*16+j];
        if (v < best){ best = v; bj = j; }
      }
      if (bj >= 0){ tiebuf[qi*16+bj] = 0x7FFFFFFF; orow[L+r] = best; }
      else orow[L+r] = n;
    }
  }
}

// ---------------- generic 128x128 bf16 GEMM: C[m][n] = sum_k A[m][k]*B[n][k] (+bias) ----------------
__global__ __launch_bounds__(256,2) void gemm128_k(
    const u16* __restrict__ A, const int lda,
    const u16* __restrict__ Bw, const int ldb,
    u16* __restrict__ C, const int ldc,
    const int K, const float* __restrict__ bias){
  __shared__ __attribute__((aligned(16))) u16 As[128*32];
  __shared__ __attribute__((aligned(16))) u16 Bs[128*32];
  const int tid = threadIdx.x, lane = tid & 63, w = tid >> 6;
  const int mrow = lane & 15, quad = lane >> 4;
  const size_t mbase = (size_t)blockIdx.x*128, nbase = (size_t)blockIdx.y*128;
  const int wr = (w&1)*64, wc = (w>>1)*64;
  f32x4 acc[4][4];
  #pragma unroll
  for (int i=0;i<4;++i)
    #pragma unroll
    for (int j=0;j<4;++j)
      #pragma unroll
      for (int r=0;r<4;++r) acc[i][j][r] = 0.f;
  const int sr = tid >> 2, sk = (tid & 3)*8;
  u16* lA0 = &As[w*512]; u16* lA1 = &As[2048 + w*512];
  u16* lB0 = &Bs[w*512]; u16* lB1 = &Bs[2048 + w*512];
  for (int k0 = 0; k0 < K; k0 += 32){
    __syncthreads();
    async_copy16(A  + (mbase      + sr)*(size_t)lda + k0 + sk, lA0);
    async_copy16(A  + (mbase + 64 + sr)*(size_t)lda + k0 + sk, lA1);
    async_copy16(Bw + (nbase      + sr)*(size_t)ldb + k0 + sk, lB0);
    async_copy16(Bw + (nbase + 64 + sr)*(size_t)ldb + k0 + sk, lB1);
    __syncthreads();
    bf16x8 af[4], bf[4];
    #pragma unroll
    for (int rt=0;rt<4;++rt) af[rt] = *(const bf16x8*)&As[(wr+rt*16+mrow)*32 + quad*8];
    #pragma unroll
    for (int ct=0;ct<4;++ct) bf[ct] = *(const bf16x8*)&Bs[(wc+ct*16+mrow)*32 + quad*8];
    #pragma unroll
    for (int rt=0;rt<4;++rt)
      #pragma unroll
      for (int ct=0;ct<4;++ct) acc[rt][ct] = MFMA16(af[rt], bf[ct], acc[rt][ct]);
  }
  #pragma unroll
  for (int rt=0;rt<4;++rt)
    #pragma unroll
    for (int ct=0;ct<4;++ct){
      const size_t row0 = mbase + wr + rt*16 + quad*4;
      const int col = (int)nbase + wc + ct*16 + mrow;
      const float bv = bias ? bias[col] : 0.f;
      #pragma unroll
      for (int r=0;r<4;++r) C[(row0+r)*(size_t)ldc + col] = f2b(acc[rt][ct][r] + bv);
    }
}

// ---------------- LayerNorm over 256-element groups, bf16 in/out ----------------
__global__ __launch_bounds__(256,2) void ln256_k(const u16* __restrict__ in, u16* __restrict__ out,
    const float* __restrict__ g, const float* __restrict__ bta){
  const int tid = threadIdx.x, lane = tid & 63, w = tid >> 6;
  const size_t row = (size_t)blockIdx.x*4 + w;
  const uint2 u = *(const uint2*)(in + row*256 + lane*4);
  const float x0=b2f(u.x&0xffff), x1=b2f(u.x>>16), x2=b2f(u.y&0xffff), x3=b2f(u.y>>16);
  float s  = x0+x1+x2+x3;
  float ss = x0*x0+x1*x1+x2*x2+x3*x3;
  #pragma unroll
  for (int mk=1; mk<64; mk<<=1){ s += __shfl_xor(s,mk,64); ss += __shfl_xor(ss,mk,64); }
  const float mu = s*(1.f/256.f);
  const float var = ss*(1.f/256.f) - mu*mu;
  const float rs = rsqrtf(var + 1e-5f);
  const int c = lane*4;
  const float y0=(x0-mu)*rs*g[c  ]+bta[c  ];
  const float y1=(x1-mu)*rs*g[c+1]+bta[c+1];
  const float y2=(x2-mu)*rs*g[c+2]+bta[c+2];
  const float y3=(x3-mu)*rs*g[c+3]+bta[c+3];
  uint2 o; o.x = pk2f(y0,y1); o.y = pk2f(y2,y3);
  *(uint2*)(out + row*256 + lane*4) = o;
}

// ---------------- fused per-neighbor attention kernel (v6: 16 waves, 32x32 wave-tiles) ----------------
// block = 64 neighbor rows (4 queries x 16), 1024 threads = 16 waves:
//   wave w -> f-slice fr=(w&7)*32, m-half mh=(w>>3)*32. acc per wave = 32 regs -> no spill at 128-reg budget.
#define DP   264
#define RELP 40
__global__ __launch_bounds__(1024,4) void attn_k(
    const float* __restrict__ xyz, const int* __restrict__ idxb,
    const u16* __restrict__ lnqkv, const u16* __restrict__ qa, const u16* __restrict__ ka,
    const u16* __restrict__ mcomb, const u16* __restrict__ wp2, const u16* __restrict__ wa2,
    const u16* __restrict__ wp1pk, u16* __restrict__ res){
  __shared__ __attribute__((aligned(16))) u16 hbuf[64*DP];    // h1, then h2 (33.8 KB)
  __shared__ __attribute__((aligned(16))) u16 srel[64*RELP];  // rel bf16, k-padded to 32
  __shared__ int sidx[64];
  const int tid = threadIdx.x;
  const int b = blockIdx.x >> 10;                // 1024 blocks per batch
  const int nbase = (blockIdx.x & 1023) << 2;    // 4 queries
  const size_t gb = (size_t)b << 12;
  // ---- stage neighbor idx + rel
  if (tid < 64){
    const int m = tid;
    const int im = idxb[(gb + nbase + (m>>4))*16 + (m&15)] & 4095;
    sidx[m] = im;
    const int nn = nbase + (m>>4);
    const float* pq = xyz + (gb+nn)*3;
    const float* pm = xyz + (gb+im)*3;
    const float rx = pq[0]-pm[0], ry = pq[1]-pm[1], rz = pq[2]-pm[2];
    uint4 a; a.x = pk2f(rx,ry); a.y = pk2f(rz,0.f); a.z = 0u; a.w = 0u;
    uint4 z; z.x = z.y = z.z = z.w = 0u;
    *(uint4*)&srel[m*RELP]    = a;
    *(uint4*)&srel[m*RELP+8]  = z;
    *(uint4*)&srel[m*RELP+16] = z;
    *(uint4*)&srel[m*RELP+24] = z;
  }
  __syncthreads();
  const int lane = tid & 63, w = tid >> 6;
  const int mrow = lane & 15, quad = lane >> 4;
  const int fr = (w & 7) << 5;                   // 32-wide f/h slice
  const int mh = (w >> 3) << 5;                  // 32-row m half
  const int qloc = mh >> 4;
  // ---- h1 via MFMA: D[h][m] for h in [fr,fr+32), m in [mh,mh+32)
  {
    bf16x8 aW[2], bR[2];
    #pragma unroll
    for (int ht=0;ht<2;++ht) aW[ht] = *(const bf16x8*)&wp1pk[(fr+ht*16+mrow)*32 + quad*8];
    #pragma unroll
    for (int mt=0;mt<2;++mt) bR[mt] = *(const bf16x8*)&srel[(mh+mt*16+mrow)*RELP + quad*8];
    #pragma unroll
    for (int ht=0;ht<2;++ht)
      #pragma unroll
      for (int mt=0;mt<2;++mt){
        f32x4 hz;
        #pragma unroll
        for (int r=0;r<4;++r) hz[r]=0.f;
        hz = MFMA16(aW[ht], bR[mt], hz);
        float h0 = hz[0]>0.f?hz[0]:0.f, h1v = hz[1]>0.f?hz[1]:0.f;
        float h2v = hz[2]>0.f?hz[2]:0.f, h3 = hz[3]>0.f?hz[3]:0.f;
        uint2 o; o.x = pk2f(h0,h1v); o.y = pk2f(h2v,h3);
        *(uint2*)&hbuf[(mh+mt*16+mrow)*DP + fr + ht*16 + quad*4] = o;
      }
  }
  int midx[2];
  #pragma unroll
  for (int mt = 0; mt < 2; ++mt) midx[mt] = sidx[mh + mt*16 + mrow];
  // ---- v gather prefetch early (independent of hbuf; consumed after G2)
  uint2 vpre[2][2];
  #pragma unroll
  for (int ft=0;ft<2;++ft)
    #pragma unroll
    for (int mt=0;mt<2;++mt)
      vpre[ft][mt] = *(const uint2*)&lnqkv[(gb + (size_t)midx[mt])*768 + 512 + fr + ft*16 + quad*4];
  // ---- register prefetch of (qa - ka) in exact C-fragment layout
  uint2 qkp[2][2];
  #pragma unroll
  for (int ft = 0; ft < 2; ++ft)
    #pragma unroll
    for (int mt = 0; mt < 2; ++mt){
      const int f = fr + ft*16 + quad*4;
      const uint2 uq = *(const uint2*)&qa[(gb + nbase + qloc + mt)*256 + f];
      const uint2 uk = *(const uint2*)&ka[(gb + (size_t)midx[mt])*256 + f];
      uint2 o;
      o.x = pk2f(b2f(uq.x&0xffff)-b2f(uk.x&0xffff), b2f(uq.x>>16)-b2f(uk.x>>16));
      o.y = pk2f(b2f(uq.y&0xffff)-b2f(uk.y&0xffff), b2f(uq.y>>16)-b2f(uk.y>>16));
      qkp[ft][mt] = o;
    }
  __syncthreads();             // h1 complete
  // ---- G1: t.T and val.T
  f32x4 at[2][2], av[2][2];
  #pragma unroll
  for (int i=0;i<2;++i)
    #pragma unroll
    for (int j=0;j<2;++j)
      #pragma unroll
      for (int r=0;r<4;++r){ at[i][j][r]=0.f; av[i][j][r]=0.f; }
  #pragma unroll 1
  for (int ks = 0; ks < 8; ++ks){
    const int koff = ks*32 + quad*8;
    bf16x8 aM[2], aP[2], bH[2];
    #pragma unroll
    for (int ft=0;ft<2;++ft){
      aM[ft] = *(const bf16x8*)&mcomb[(fr+ft*16+mrow)*256 + koff];
      aP[ft] = *(const bf16x8*)&wp2  [(fr+ft*16+mrow)*256 + koff];
    }
    #pragma unroll
    for (int mt=0;mt<2;++mt) bH[mt] = *(const bf16x8*)&hbuf[(mh+mt*16+mrow)*DP + koff];
    #pragma unroll
    for (int ft=0;ft<2;++ft)
      #pragma unroll
      for (int mt=0;mt<2;++mt){
        at[ft][mt] = MFMA16(aM[ft], bH[mt], at[ft][mt]);
        av[ft][mt] = MFMA16(aP[ft], bH[mt], av[ft][mt]);
      }
  }
  __syncthreads();             // all waves done reading h1
  // ---- epilogue: h2 = relu(t + (qa-ka)) -> overwrite hbuf
  #pragma unroll
  for (int ft=0;ft<2;++ft)
    #pragma unroll
    for (int mt=0;mt<2;++mt){
      const int moff = (mh+mt*16+mrow)*DP + fr + ft*16 + quad*4;
      const uint2 qv = qkp[ft][mt];
      float t0 = at[ft][mt][0] + b2f(qv.x&0xffff);
      float t1 = at[ft][mt][1] + b2f(qv.x>>16);
      float t2 = at[ft][mt][2] + b2f(qv.y&0xffff);
      float t3 = at[ft][mt][3] + b2f(qv.y>>16);
      t0 = t0>0.f?t0:0.f; t1 = t1>0.f?t1:0.f; t2 = t2>0.f?t2:0.f; t3 = t3>0.f?t3:0.f;
      uint2 o; o.x = pk2f(t0,t1); o.y = pk2f(t2,t3);
      *(uint2*)&hbuf[moff] = o;
    }
  __syncthreads();
  // ---- G2: logits.T = Wa2 @ h2.T
  f32x4 al[2][2];
  #pragma unroll
  for (int i=0;i<2;++i)
    #pragma unroll
    for (int j=0;j<2;++j)
      #pragma unroll
      for (int r=0;r<4;++r) al[i][j][r]=0.f;
  #pragma unroll 1
  for (int ks = 0; ks < 8; ++ks){
    const int koff = ks*32 + quad*8;
    bf16x8 aW[2], bH[2];
    #pragma unroll
    for (int gt=0;gt<2;++gt) aW[gt] = *(const bf16x8*)&wa2[(fr+gt*16+mrow)*256 + koff];
    #pragma unroll
    for (int mt=0;mt<2;++mt) bH[mt] = *(const bf16x8*)&hbuf[(mh+mt*16+mrow)*DP + koff];
    #pragma unroll
    for (int gt=0;gt<2;++gt)
      #pragma unroll
      for (int mt=0;mt<2;++mt) al[gt][mt] = MFMA16(aW[gt], bH[mt], al[gt][mt]);
  }
  // ---- softmax over 16 neighbors (= lane&15) + weighted reduce
  const float sc = 0.0901684f;   // log2(e)/sqrt(256)
  #pragma unroll
  for (int gt=0;gt<2;++gt)
    #pragma unroll
    for (int mt=0;mt<2;++mt){
      float rv[4];
      #pragma unroll
      for (int r=0;r<4;++r){
        u32 hv;
        if      (r==0) hv = vpre[gt][mt].x & 0xffff;
        else if (r==1) hv = vpre[gt][mt].x >> 16;
        else if (r==2) hv = vpre[gt][mt].y & 0xffff;
        else           hv = vpre[gt][mt].y >> 16;
        const float val = av[gt][mt][r] + b2f(hv);
        float pr = exp2f(al[gt][mt][r]*sc);   // logits are O(1); no max-sub needed
        float wg = pr*val;
        #pragma unroll
        for (int mk=1; mk<16; mk<<=1){ pr += __shfl_xor(pr,mk,64); wg += __shfl_xor(wg,mk,64); }
        rv[r] = wg * __builtin_amdgcn_rcpf(pr);
      }
      if (mrow == 0){
        uint2 o; o.x = pk2f(rv[0],rv[1]); o.y = pk2f(rv[2],rv[3]);
        *(uint2*)&res[(gb + nbase + qloc + mt)*256 + fr + gt*16 + quad*4] = o;
      }
    }
}

// ---------------- final: out = ln(r1 @ W_post.T + b_post)*g+b + features ----------------
__global__ __launch_bounds__(256,2) void d2_k(
    const u16* __restrict__ r1, const u16* __restrict__ wpost,
    const float* __restrict__ bpost, const float* __restrict__ g, const float* __restrict__ bt,
    const float* __restrict__ feat, float* __restrict__ out){
  const int tid = threadIdx.x, lane = tid & 63, w = tid >> 6;
  const int mrow = lane & 15, quad = lane >> 4;
  const size_t rb = (size_t)blockIdx.x*128 + w*32;
  f32x4 acc[2][4];
  #pragma unroll
  for (int i=0;i<2;++i)
    #pragma unroll
    for (int j=0;j<4;++j)
      #pragma unroll
      for (int r=0;r<4;++r) acc[i][j][r]=0.f;
  #pragma unroll 1
  for (int ks = 0; ks < 8; ++ks){
    const int koff = ks*32 + quad*8;
    bf16x8 af[2], bf[4];
    #pragma unroll
    for (int rt=0;rt<2;++rt) af[rt] = *(const bf16x8*)&r1[(rb+rt*16+mrow)*256 + koff];
    #pragma unroll
    for (int ct=0;ct<4;++ct) bf[ct] = *(const bf16x8*)&wpost[(ct*16+mrow)*256 + koff];
    #pragma unroll
    for (int rt=0;rt<2;++rt)
      #pragma unroll
      for (int ct=0;ct<4;++ct) acc[rt][ct] = MFMA16(af[rt], bf[ct], acc[rt][ct]);
  }
  #pragma unroll
  for (int ct=0;ct<4;++ct){
    const float bv = bpost[ct*16+mrow];
    #pragma unroll
    for (int rt=0;rt<2;++rt)
      #pragma unroll
      for (int r=0;r<4;++r) acc[rt][ct][r] += bv;
  }
  #pragma unroll
  for (int rt=0;rt<2;++rt)
    #pragma unroll
    for (int r=0;r<4;++r){
      float s  = acc[rt][0][r]+acc[rt][1][r]+acc[rt][2][r]+acc[rt][3][r];
      float ss = acc[rt][0][r]*acc[rt][0][r]+acc[rt][1][r]*acc[rt][1][r]
               + acc[rt][2][r]*acc[rt][2][r]+acc[rt][3][r]*acc[rt][3][r];
      #pragma unroll
      for (int mk=1; mk<16; mk<<=1){ s += __shfl_xor(s,mk,64); ss += __shfl_xor(ss,mk,64); }
      const float mu = s*(1.f/64.f);
      const float var = ss*(1.f/64.f) - mu*mu;
      const float rs = rsqrtf(var + 1e-5f);
      const size_t row = rb + rt*16 + quad*4 + r;
      #pragma unroll
      for (int ct=0;ct<4;++ct){
        const int n = ct*16 + mrow;
        out[row*64 + n] = (acc[rt][ct][r]-mu)*rs*g[n] + bt[n] + feat[row*64 + n];
      }
    }
}

// ---------------- launcher ----------------
extern "C" void kernel_launch(void* const* d_in, const int* in_sizes, int n_in,
                              void* d_out, int out_size, void* d_ws, size_t ws_size,
                              hipStream_t stream){
  const float* xyz    = (const float*)d_in[0];
  const float* feat   = (const float*)d_in[1];
  const float* W_pre  = (const float*)d_in[2];
  const float* b_pre  = (const float*)d_in[3];
  const float* W_post = (const float*)d_in[4];
  const float* b_post = (const float*)d_in[5];
  const float* Wp1    = (const float*)d_in[6];
  const float* Wp2    = (const float*)d_in[7];
  const float* Wa1    = (const float*)d_in[8];
  const float* Wa2    = (const float*)d_in[9];
  const float* WQ     = (const float*)d_in[10];
  const float* WK     = (const float*)d_in[11];
  const float* WV     = (const float*)d_in[12];
  const float* Wproj  = (const float*)d_in[13];
  const float* g_dm   = (const float*)d_in[14];
  const float* b_dm   = (const float*)d_in[15];
  const float* g_dp   = (const float*)d_in[16];
  const float* b_dp   = (const float*)d_in[17];
  float* out = (float*)d_out;
  if (ws_size < WS_NEED) return;
  char* ws = (char*)d_ws;
  int* idxw   = (int*)(ws + OFF_IDX);
  u16* featb  = (u16*)(ws + OFF_FEATB);
  u16* wpreb  = (u16*)(ws + OFF_WPRE);
  u16* wqkvb  = (u16*)(ws + OFF_WQKV);
  u16* wa1b   = (u16*)(ws + OFF_WA1);
  u16* wa2b   = (u16*)(ws + OFF_WA2);
  u16* wp2b   = (u16*)(ws + OFF_WP2);
  u16* wprojb = (u16*)(ws + OFF_WPROJ);
  u16* wpostb = (u16*)(ws + OFF_WPOST);
  u16* mcombb = (u16*)(ws + OFF_MCOMB);
  u16* inp    = (u16*)(ws + OFF_INP);
  u16* qkv    = (u16*)(ws + OFF_QKV);
  u16* lnqkv  = (u16*)(ws + OFF_LNQKV);
  u16* qab    = (u16*)(ws + OFF_QA);
  u16* kab    = (u16*)(ws + OFF_KA);
  u16* resb   = (u16*)(ws + OFF_RES);
  u16* d1raw  = (u16*)(ws + OFF_D1);
  u16* r1b    = (u16*)(ws + OFF_R1);
  u16* wp1pk  = (u16*)(ws + OFF_WP1PK);   // aliases d1raw: read by attn_k before d1 GEMM writes
  u16* wp2T   = (u16*)(ws + OFF_WP2T);    // aliases qkv: consumed before qkv GEMM writes

  convert_k<<<6016,256,0,stream>>>(feat,W_pre,WQ,WK,WV,Wa1,Wa2,Wp2,Wproj,W_post,
                                   featb,wpreb,wqkvb,wa1b,wa2b,wp2b,wprojb,wpostb);
  transpose_k<<<64,256,0,stream>>>(wp2b, wp2T);
  // Mcomb = Wa1 @ Wp2 : C[f][h] = sum_k wa1[f][k] * wp2T[h][k]
  gemm128_k<<<dim3(2,2),256,0,stream>>>(wa1b,256, wp2T,256, mcombb,256, 256, nullptr);
  wp1pack_k<<<1,256,0,stream>>>(Wp1,wp1pk);
  knn_kernel<<<512,256,0,stream>>>(xyz,idxw);
  // inp = features @ W_pre.T + b_pre
  gemm128_k<<<dim3(128,2),256,0,stream>>>(featb,64,  wpreb,64,  inp,256, 64,  b_pre);
  // qkv = inp @ [WQ|WK|WV].T
  gemm128_k<<<dim3(128,6),256,0,stream>>>(inp,256,   wqkvb,256, qkv,768, 256, nullptr);
  ln256_k<<<12288,256,0,stream>>>(qkv,lnqkv,g_dm,b_dm);
  // qa = ln(q) @ Wa1.T ; ka = ln(k) @ Wa1.T
  gemm128_k<<<dim3(128,2),256,0,stream>>>(lnqkv,768,     wa1b,256, qab,256, 256, nullptr);
  gemm128_k<<<dim3(128,2),256,0,stream>>>(lnqkv+256,768, wa1b,256, kab,256, 256, nullptr);
  attn_k<<<4096,1024,0,stream>>>(xyz,idxw,lnqkv,qab,kab,mcombb,wp2b,wa2b,wp1pk,resb);
  // d1 = res @ Wproj.T ; r1 = ln(d1)
  gemm128_k<<<dim3(128,2),256,0,stream>>>(resb,256, wprojb,256, d1raw,256, 256, nullptr);
  ln256_k<<<4096,256,0,stream>>>(d1raw,r1b,g_dm,b_dm);
  d2_k<<<128,256,0,stream>>>(r1b,wpostb,b_post,g_dp,b_dp,feat,out);
}

// Round 7
// 661.889 us; speedup vs baseline: 1.2625x; 1.2625x over previous
//
#include <hip/hip_runtime.h>

typedef unsigned short u16;
typedef unsigned int   u32;
typedef __attribute__((ext_vector_type(8))) short bf16x8;
typedef __attribute__((ext_vector_type(4))) float f32x4;

#define MFMA16(a,b,c) __builtin_amdgcn_mfma_f32_16x16x32_bf16((a),(b),(c),0,0,0)

__device__ __forceinline__ float b2f(u32 h){ return __uint_as_float(h<<16); }
__device__ __forceinline__ u16 f2b(float f){
  u32 u = __float_as_uint(f);
  return (u16)((u + 0x7FFFu + ((u>>16)&1u))>>16);
}
__device__ __forceinline__ u32 pk2f(float a,float b){ return (u32)f2b(a) | ((u32)f2b(b)<<16); }
__device__ __forceinline__ u32 umin32(u32 a,u32 b){ return a<b?a:b; }
__device__ __forceinline__ u32 umax32(u32 a,u32 b){ return a>b?a:b; }

__device__ __forceinline__ void async_copy16(const void* g, void* l){
  __builtin_amdgcn_global_load_lds((const __attribute__((address_space(1))) u32*)g,
                                   (__attribute__((address_space(3))) u32*)l, 16, 0, 0);
}

// ---------------- workspace layout (bytes) ----------------
#define OFF_IDX    0ull
#define OFF_FEATB  1048576ull
#define OFF_WPRE   3145728ull
#define OFF_WQKV   3178496ull
#define OFF_WA1    3571712ull
#define OFF_WA2    3702784ull
#define OFF_WP2    3833856ull
#define OFF_WPROJ  3964928ull
#define OFF_WPOST  4096000ull
#define OFF_MCOMB  4128768ull
#define OFF_INP    4259840ull
#define OFF_QKV    12648448ull
#define OFF_LNQKV  37814272ull
#define OFF_QA     62980096ull
#define OFF_KA     71368704ull
#define OFF_RES    79757312ull
#define OFF_D1     88145920ull     // also hosts wp1pk early (d1 written only after attn)
#define OFF_R1     96534528ull
#define WS_NEED    104923136ull
#define OFF_WP1PK  OFF_D1
#define OFF_WP2T   OFF_QKV         // wp2^T consumed by mcomb GEMM before qkv GEMM writes here

// ---------------- f32 -> bf16 conversions ----------------
__global__ void convert_k(const float* __restrict__ feat, const float* __restrict__ wpre,
    const float* __restrict__ wq, const float* __restrict__ wk, const float* __restrict__ wv,
    const float* __restrict__ wa1, const float* __restrict__ wa2, const float* __restrict__ wp2,
    const float* __restrict__ wproj, const float* __restrict__ wpost,
    u16* __restrict__ dfeat, u16* __restrict__ dwpre, u16* __restrict__ dwqkv,
    u16* __restrict__ dwa1, u16* __restrict__ dwa2, u16* __restrict__ dwp2,
    u16* __restrict__ dwproj, u16* __restrict__ dwpost){
  int id = blockIdx.x*256 + threadIdx.x;
  const float* s; u16* d; int off;
  if      (id < 1048576){ s=feat;  d=dfeat;        off=id; }
  else if (id < 1064960){ s=wpre;  d=dwpre;        off=id-1048576; }
  else if (id < 1130496){ s=wq;    d=dwqkv;        off=id-1064960; }
  else if (id < 1196032){ s=wk;    d=dwqkv+65536;  off=id-1130496; }
  else if (id < 1261568){ s=wv;    d=dwqkv+131072; off=id-1196032; }
  else if (id < 1327104){ s=wa1;   d=dwa1;         off=id-1261568; }
  else if (id < 1392640){ s=wa2;   d=dwa2;         off=id-1327104; }
  else if (id < 1458176){ s=wp2;   d=dwp2;         off=id-1392640; }
  else if (id < 1523712){ s=wproj; d=dwproj;       off=id-1458176; }
  else if (id < 1540096){ s=wpost; d=dwpost;       off=id-1523712; }
  else return;
  d[off] = f2b(s[off]);
}

// 256x256 bf16 transpose (for Mcomb GEMM's B operand)
__global__ void transpose_k(const u16* __restrict__ in, u16* __restrict__ out){
  __shared__ u16 t[32][33];
  const int tid = threadIdx.x, tx = tid & 31, ty = tid >> 5;   // 8 rows
  const int bx = blockIdx.x & 7, by = blockIdx.x >> 3;
  #pragma unroll
  for (int r = 0; r < 4; ++r) t[ty+8*r][tx] = in[(by*32+ty+8*r)*256 + bx*32+tx];
  __syncthreads();
  #pragma unroll
  for (int r = 0; r < 4; ++r) out[(bx*32+ty+8*r)*256 + by*32+tx] = t[tx][ty+8*r];
}

// Wp1 packed for MFMA A-operand: [256 h][32 k] bf16, k=0..2 = Wp1[h][*], rest 0
__global__ void wp1pack_k(const float* __restrict__ wp1, u16* __restrict__ out){
  const int h = threadIdx.x;
  const float w0 = wp1[h*3], w1 = wp1[h*3+1], w2 = wp1[h*3+2];
  uint4 a; a.x = pk2f(w0,w1); a.y = pk2f(w2,0.f); a.z = 0u; a.w = 0u;
  uint4 z; z.x = z.y = z.z = z.w = 0u;
  *(uint4*)&out[h*32]    = a;
  *(uint4*)&out[h*32+8]  = z;
  *(uint4*)&out[h*32+16] = z;
  *(uint4*)&out[h*32+24] = z;
}

// ---------------- kNN: exact top-16 by (d2, idx) ----------------
__device__ __forceinline__ void ins16(u32 (&a)[16], u32 key){
  #pragma unroll
  for (int j = 15; j >= 1; --j) a[j] = umin32(umax32(a[j-1],key), a[j]);
  a[0] = umin32(a[0], key);
}

__device__ __forceinline__ float dist2(float ax,float ay,float az,float bx,float by,float bz){
  const float dx = ax-bx, dy = ay-by, dz = az-bz;
  return __fmaf_rn(dx,dx, __fmaf_rn(dy,dy, dz*dz));   // identical sequence both phases
}

__global__ __launch_bounds__(256,2) void knn_kernel(const float* __restrict__ xyz,
                                                    int* __restrict__ idxout){
  __shared__ __attribute__((aligned(16))) float sbuf[3*4104];
  __shared__ int lcnt[32];
  __shared__ int tcnt[32];
  __shared__ u32 tbuf[32];
  __shared__ int tiebuf[32*16];
  float* sx = sbuf; float* sy = sbuf + 4104; float* sz = sbuf + 8208;
  const int tid = threadIdx.x;
  const int b  = blockIdx.x >> 7;
  const int n0 = (blockIdx.x & 127) << 5;
  const float* base = xyz + (size_t)b*12288;
  #pragma unroll
  for (int i = 0; i < 12; ++i){
    const float4 v = *(const float4*)(base + tid*48 + i*4);
    const float vv[4] = {v.x, v.y, v.z, v.w};
    #pragma unroll
    for (int j = 0; j < 4; ++j){
      const int e = i*4 + j;
      const int c = e % 3;
      const int m = tid*16 + e/3;
      float* arr = (c==0)?sx:((c==1)?sy:sz);
      arr[m + (m>>9)] = vv[j];
    }
  }
  if (tid < 32){ lcnt[tid] = 0; tcnt[tid] = 0; }
  __syncthreads();
  const int qi = tid >> 3, p = tid & 7;
  const int n = n0 + qi;
  const int sn = n + (n>>9);
  const float qx = sx[sn], qy = sy[sn], qz = sz[sn];
  u32 a[16];
  #pragma unroll
  for (int j = 0; j < 16; ++j) a[j] = 0xFFFFFFFFu;
  const int sb = p*513;
  #pragma unroll 2
  for (int i = 0; i < 512; ++i){
    const float d2 = dist2(sx[sb+i],sy[sb+i],sz[sb+i],qx,qy,qz);
    ins16(a, __float_as_uint(d2));
  }
  #pragma unroll
  for (int s = 4; s >= 1; s >>= 1){
    u32 o[16];
    #pragma unroll
    for (int j = 0; j < 16; ++j) o[j] = __shfl_down(a[j], (unsigned)s, 64);
    if (p < s){
      #pragma unroll
      for (int j = 0; j < 16; ++j) ins16(a, o[j]);
    }
  }
  if (p == 0) tbuf[qi] = a[15];
  __syncthreads();
  const u32 T = tbuf[qi];
  int* orow = idxout + ((size_t)(b<<12)+n)*16;
  const int gbase = p*512;
  for (int i = 0; i < 512; ++i){
    const float d2 = dist2(sx[sb+i],sy[sb+i],sz[sb+i],qx,qy,qz);
    const u32 kb = __float_as_uint(d2);
    if (kb < T){
      const int pos = atomicAdd(&lcnt[qi],1);
      if (pos < 16) orow[pos] = gbase + i;
    } else if (kb == T){
      const int t = atomicAdd(&tcnt[qi],1);
      if (t < 16) tiebuf[qi*16+t] = gbase + i;
    }
  }
  __syncthreads();
  if (p == 0){
    int L = lcnt[qi]; if (L > 16) L = 16;
    int tc = tcnt[qi]; if (tc > 16) tc = 16;
    const int need = 16 - L;
    for (int r = 0; r < need; ++r){
      int best = 0x7FFFFFFF, bj = -1;
      for (int j = 0; j < tc; ++j){
        const int v = tiebuf[qi*16+j];
        if (v < best){ best = v; bj = j; }
      }
      if (bj >= 0){ tiebuf[qi*16+bj] = 0x7FFFFFFF; orow[L+r] = best; }
      else orow[L+r] = n;
    }
  }
}

// ---------------- generic 128x128 bf16 GEMM: C[m][n] = sum_k A[m][k]*B[n][k] (+bias) ----------------
__global__ __launch_bounds__(256,2) void gemm128_k(
    const u16* __restrict__ A, const int lda,
    const u16* __restrict__ Bw, const int ldb,
    u16* __restrict__ C, const int ldc,
    const int K, const float* __restrict__ bias){
  __shared__ __attribute__((aligned(16))) u16 As[128*32];
  __shared__ __attribute__((aligned(16))) u16 Bs[128*32];
  const int tid = threadIdx.x, lane = tid & 63, w = tid >> 6;
  const int mrow = lane & 15, quad = lane >> 4;
  const size_t mbase = (size_t)blockIdx.x*128, nbase = (size_t)blockIdx.y*128;
  const int wr = (w&1)*64, wc = (w>>1)*64;
  f32x4 acc[4][4];
  #pragma unroll
  for (int i=0;i<4;++i)
    #pragma unroll
    for (int j=0;j<4;++j)
      #pragma unroll
      for (int r=0;r<4;++r) acc[i][j][r] = 0.f;
  const int sr = tid >> 2, sk = (tid & 3)*8;
  u16* lA0 = &As[w*512]; u16* lA1 = &As[2048 + w*512];
  u16* lB0 = &Bs[w*512]; u16* lB1 = &Bs[2048 + w*512];
  for (int k0 = 0; k0 < K; k0 += 32){
    __syncthreads();
    async_copy16(A  + (mbase      + sr)*(size_t)lda + k0 + sk, lA0);
    async_copy16(A  + (mbase + 64 + sr)*(size_t)lda + k0 + sk, lA1);
    async_copy16(Bw + (nbase      + sr)*(size_t)ldb + k0 + sk, lB0);
    async_copy16(Bw + (nbase + 64 + sr)*(size_t)ldb + k0 + sk, lB1);
    __syncthreads();
    bf16x8 af[4], bf[4];
    #pragma unroll
    for (int rt=0;rt<4;++rt) af[rt] = *(const bf16x8*)&As[(wr+rt*16+mrow)*32 + quad*8];
    #pragma unroll
    for (int ct=0;ct<4;++ct) bf[ct] = *(const bf16x8*)&Bs[(wc+ct*16+mrow)*32 + quad*8];
    #pragma unroll
    for (int rt=0;rt<4;++rt)
      #pragma unroll
      for (int ct=0;ct<4;++ct) acc[rt][ct] = MFMA16(af[rt], bf[ct], acc[rt][ct]);
  }
  #pragma unroll
  for (int rt=0;rt<4;++rt)
    #pragma unroll
    for (int ct=0;ct<4;++ct){
      const size_t row0 = mbase + wr + rt*16 + quad*4;
      const int col = (int)nbase + wc + ct*16 + mrow;
      const float bv = bias ? bias[col] : 0.f;
      #pragma unroll
      for (int r=0;r<4;++r) C[(row0+r)*(size_t)ldc + col] = f2b(acc[rt][ct][r] + bv);
    }
}

// ---------------- LayerNorm over 256-element groups, bf16 in/out ----------------
__global__ __launch_bounds__(256,2) void ln256_k(const u16* __restrict__ in, u16* __restrict__ out,
    const float* __restrict__ g, const float* __restrict__ bta){
  const int tid = threadIdx.x, lane = tid & 63, w = tid >> 6;
  const size_t row = (size_t)blockIdx.x*4 + w;
  const uint2 u = *(const uint2*)(in + row*256 + lane*4);
  const float x0=b2f(u.x&0xffff), x1=b2f(u.x>>16), x2=b2f(u.y&0xffff), x3=b2f(u.y>>16);
  float s  = x0+x1+x2+x3;
  float ss = x0*x0+x1*x1+x2*x2+x3*x3;
  #pragma unroll
  for (int mk=1; mk<64; mk<<=1){ s += __shfl_xor(s,mk,64); ss += __shfl_xor(ss,mk,64); }
  const float mu = s*(1.f/256.f);
  const float var = ss*(1.f/256.f) - mu*mu;
  const float rs = rsqrtf(var + 1e-5f);
  const int c = lane*4;
  const float y0=(x0-mu)*rs*g[c  ]+bta[c  ];
  const float y1=(x1-mu)*rs*g[c+1]+bta[c+1];
  const float y2=(x2-mu)*rs*g[c+2]+bta[c+2];
  const float y3=(x3-mu)*rs*g[c+3]+bta[c+3];
  uint2 o; o.x = pk2f(y0,y1); o.y = pk2f(y2,y3);
  *(uint2*)(out + row*256 + lane*4) = o;
}

// ---------------- fused per-neighbor attention kernel (v7: v5 shape, 168-reg budget, no spill) ----------------
// block = 64 rows (4 queries x 16), 512 threads = 8 waves, wave w owns f-slice [w*32, w*32+32), all 64 m.
// __launch_bounds__(512,3): ~168 regs/wave — fits G1 live set (~130) and G2 (~135) without spill.
// qkp gather issued AFTER the G1 MFMA loop: the barrier wait overlaps the gather latency.
#define DP   264
#define RELP 40
__global__ __launch_bounds__(512,3) void attn_k(
    const float* __restrict__ xyz, const int* __restrict__ idxb,
    const u16* __restrict__ lnqkv, const u16* __restrict__ qa, const u16* __restrict__ ka,
    const u16* __restrict__ mcomb, const u16* __restrict__ wp2, const u16* __restrict__ wa2,
    const u16* __restrict__ wp1pk, u16* __restrict__ res){
  __shared__ __attribute__((aligned(16))) u16 hbuf[64*DP];    // h1, then h2 (33.8 KB)
  __shared__ __attribute__((aligned(16))) u16 srel[64*RELP];  // rel bf16, k-padded to 32
  __shared__ int sidx[64];
  const int tid = threadIdx.x;
  const int b = blockIdx.x >> 10;                // 1024 blocks per batch
  const int nbase = (blockIdx.x & 1023) << 2;    // 4 queries
  const size_t gb = (size_t)b << 12;
  // ---- stage neighbor idx + rel
  if (tid < 64){
    const int m = tid;
    const int im = idxb[(gb + nbase + (m>>4))*16 + (m&15)] & 4095;
    sidx[m] = im;
    const int nn = nbase + (m>>4);
    const float* pq = xyz + (gb+nn)*3;
    const float* pm = xyz + (gb+im)*3;
    const float rx = pq[0]-pm[0], ry = pq[1]-pm[1], rz = pq[2]-pm[2];
    uint4 a; a.x = pk2f(rx,ry); a.y = pk2f(rz,0.f); a.z = 0u; a.w = 0u;
    uint4 z; z.x = z.y = z.z = z.w = 0u;
    *(uint4*)&srel[m*RELP]    = a;
    *(uint4*)&srel[m*RELP+8]  = z;
    *(uint4*)&srel[m*RELP+16] = z;
    *(uint4*)&srel[m*RELP+24] = z;
  }
  __syncthreads();
  const int lane = tid & 63, w = tid >> 6;
  const int mrow = lane & 15, quad = lane >> 4;
  const int fr = w << 5;                         // 32-wide f/h slice of this wave
  // ---- h1 via MFMA: D[h][m] for h in [fr,fr+32), m in [0,64)
  {
    bf16x8 aW[2], bR[4];
    #pragma unroll
    for (int ht=0;ht<2;++ht) aW[ht] = *(const bf16x8*)&wp1pk[(fr+ht*16+mrow)*32 + quad*8];
    #pragma unroll
    for (int mt=0;mt<4;++mt) bR[mt] = *(const bf16x8*)&srel[(mt*16+mrow)*RELP + quad*8];
    #pragma unroll
    for (int ht=0;ht<2;++ht)
      #pragma unroll
      for (int mt=0;mt<4;++mt){
        f32x4 hz;
        #pragma unroll
        for (int r=0;r<4;++r) hz[r]=0.f;
        hz = MFMA16(aW[ht], bR[mt], hz);
        float h0 = hz[0]>0.f?hz[0]:0.f, h1v = hz[1]>0.f?hz[1]:0.f;
        float h2v = hz[2]>0.f?hz[2]:0.f, h3 = hz[3]>0.f?hz[3]:0.f;
        uint2 o; o.x = pk2f(h0,h1v); o.y = pk2f(h2v,h3);
        *(uint2*)&hbuf[(mt*16+mrow)*DP + fr + ht*16 + quad*4] = o;
      }
  }
  int midx[4];
  #pragma unroll
  for (int mt = 0; mt < 4; ++mt) midx[mt] = sidx[mt*16 + mrow];
  __syncthreads();             // h1 complete
  // ---- G1: t.T and val.T
  f32x4 at[2][4], av[2][4];
  #pragma unroll
  for (int i=0;i<2;++i)
    #pragma unroll
    for (int j=0;j<4;++j)
      #pragma unroll
      for (int r=0;r<4;++r){ at[i][j][r]=0.f; av[i][j][r]=0.f; }
  #pragma unroll 1
  for (int ks = 0; ks < 8; ++ks){
    const int koff = ks*32 + quad*8;
    bf16x8 aM[2], aP[2], bH[4];
    #pragma unroll
    for (int ft=0;ft<2;++ft){
      aM[ft] = *(const bf16x8*)&mcomb[(fr+ft*16+mrow)*256 + koff];
      aP[ft] = *(const bf16x8*)&wp2  [(fr+ft*16+mrow)*256 + koff];
    }
    #pragma unroll
    for (int mt=0;mt<4;++mt) bH[mt] = *(const bf16x8*)&hbuf[(mt*16+mrow)*DP + koff];
    #pragma unroll
    for (int ft=0;ft<2;++ft)
      #pragma unroll
      for (int mt=0;mt<4;++mt){
        at[ft][mt] = MFMA16(aM[ft], bH[mt], at[ft][mt]);
        av[ft][mt] = MFMA16(aP[ft], bH[mt], av[ft][mt]);
      }
  }
  // ---- qkp gather AFTER G1 (barrier wait below hides the latency; keeps G1 live-set small)
  uint2 qkp[2][4];
  #pragma unroll
  for (int ft = 0; ft < 2; ++ft)
    #pragma unroll
    for (int mt = 0; mt < 4; ++mt){
      const int f = fr + ft*16 + quad*4;
      const uint2 uq = *(const uint2*)&qa[(gb + nbase + mt)*256 + f];
      const uint2 uk = *(const uint2*)&ka[(gb + (size_t)midx[mt])*256 + f];
      uint2 o;
      o.x = pk2f(b2f(uq.x&0xffff)-b2f(uk.x&0xffff), b2f(uq.x>>16)-b2f(uk.x>>16));
      o.y = pk2f(b2f(uq.y&0xffff)-b2f(uk.y&0xffff), b2f(uq.y>>16)-b2f(uk.y>>16));
      qkp[ft][mt] = o;
    }
  __syncthreads();             // all waves done reading h1
  // ---- epilogue: h2 = relu(t + (qa-ka)) -> overwrite hbuf
  #pragma unroll
  for (int ft=0;ft<2;++ft)
    #pragma unroll
    for (int mt=0;mt<4;++mt){
      const int moff = (mt*16+mrow)*DP + fr + ft*16 + quad*4;
      const uint2 qv = qkp[ft][mt];
      float t0 = at[ft][mt][0] + b2f(qv.x&0xffff);
      float t1 = at[ft][mt][1] + b2f(qv.x>>16);
      float t2 = at[ft][mt][2] + b2f(qv.y&0xffff);
      float t3 = at[ft][mt][3] + b2f(qv.y>>16);
      t0 = t0>0.f?t0:0.f; t1 = t1>0.f?t1:0.f; t2 = t2>0.f?t2:0.f; t3 = t3>0.f?t3:0.f;
      uint2 o; o.x = pk2f(t0,t1); o.y = pk2f(t2,t3);
      *(uint2*)&hbuf[moff] = o;
    }
  // ---- v gather prefetch (at[] dead now; consumed after G2; barrier hides latency)
  uint2 vpre[2][4];
  #pragma unroll
  for (int ft=0;ft<2;++ft)
    #pragma unroll
    for (int mt=0;mt<4;++mt)
      vpre[ft][mt] = *(const uint2*)&lnqkv[(gb + (size_t)midx[mt])*768 + 512 + fr + ft*16 + quad*4];
  __syncthreads();
  // ---- G2: logits.T = Wa2 @ h2.T
  f32x4 al[2][4];
  #pragma unroll
  for (int i=0;i<2;++i)
    #pragma unroll
    for (int j=0;j<4;++j)
      #pragma unroll
      for (int r=0;r<4;++r) al[i][j][r]=0.f;
  #pragma unroll 1
  for (int ks = 0; ks < 8; ++ks){
    const int koff = ks*32 + quad*8;
    bf16x8 aW[2], bH[4];
    #pragma unroll
    for (int gt=0;gt<2;++gt) aW[gt] = *(const bf16x8*)&wa2[(fr+gt*16+mrow)*256 + koff];
    #pragma unroll
    for (int mt=0;mt<4;++mt) bH[mt] = *(const bf16x8*)&hbuf[(mt*16+mrow)*DP + koff];
    #pragma unroll
    for (int gt=0;gt<2;++gt)
      #pragma unroll
      for (int mt=0;mt<4;++mt) al[gt][mt] = MFMA16(aW[gt], bH[mt], al[gt][mt]);
  }
  // ---- softmax over 16 neighbors (= lane&15) + weighted reduce
  const float sc = 0.0901684f;   // log2(e)/sqrt(256)
  #pragma unroll
  for (int gt=0;gt<2;++gt)
    #pragma unroll
    for (int mt=0;mt<4;++mt){
      float rv[4];
      #pragma unroll
      for (int r=0;r<4;++r){
        u32 hv;
        if      (r==0) hv = vpre[gt][mt].x & 0xffff;
        else if (r==1) hv = vpre[gt][mt].x >> 16;
        else if (r==2) hv = vpre[gt][mt].y & 0xffff;
        else           hv = vpre[gt][mt].y >> 16;
        const float val = av[gt][mt][r] + b2f(hv);
        float pr = exp2f(al[gt][mt][r]*sc);   // logits are O(1); no max-sub needed
        float wg = pr*val;
        #pragma unroll
        for (int mk=1; mk<16; mk<<=1){ pr += __shfl_xor(pr,mk,64); wg += __shfl_xor(wg,mk,64); }
        rv[r] = wg * __builtin_amdgcn_rcpf(pr);
      }
      if (mrow == 0){
        uint2 o; o.x = pk2f(rv[0],rv[1]); o.y = pk2f(rv[2],rv[3]);
        *(uint2*)&res[(gb + nbase + mt)*256 + fr + gt*16 + quad*4] = o;
      }
    }
}

// ---------------- final: out = ln(r1 @ W_post.T + b_post)*g+b + features ----------------
__global__ __launch_bounds__(256,2) void d2_k(
    const u16* __restrict__ r1, const u16* __restrict__ wpost,
    const float* __restrict__ bpost, const float* __restrict__ g, const float* __restrict__ bt,
    const float* __restrict__ feat, float* __restrict__ out){
  const int tid = threadIdx.x, lane = tid & 63, w = tid >> 6;
  const int mrow = lane & 15, quad = lane >> 4;
  const size_t rb = (size_t)blockIdx.x*128 + w*32;
  f32x4 acc[2][4];
  #pragma unroll
  for (int i=0;i<2;++i)
    #pragma unroll
    for (int j=0;j<4;++j)
      #pragma unroll
      for (int r=0;r<4;++r) acc[i][j][r]=0.f;
  #pragma unroll 1
  for (int ks = 0; ks < 8; ++ks){
    const int koff = ks*32 + quad*8;
    bf16x8 af[2], bf[4];
    #pragma unroll
    for (int rt=0;rt<2;++rt) af[rt] = *(const bf16x8*)&r1[(rb+rt*16+mrow)*256 + koff];
    #pragma unroll
    for (int ct=0;ct<4;++ct) bf[ct] = *(const bf16x8*)&wpost[(ct*16+mrow)*256 + koff];
    #pragma unroll
    for (int rt=0;rt<2;++rt)
      #pragma unroll
      for (int ct=0;ct<4;++ct) acc[rt][ct] = MFMA16(af[rt], bf[ct], acc[rt][ct]);
  }
  #pragma unroll
  for (int ct=0;ct<4;++ct){
    const float bv = bpost[ct*16+mrow];
    #pragma unroll
    for (int rt=0;rt<2;++rt)
      #pragma unroll
      for (int r=0;r<4;++r) acc[rt][ct][r] += bv;
  }
  #pragma unroll
  for (int rt=0;rt<2;++rt)
    #pragma unroll
    for (int r=0;r<4;++r){
      float s  = acc[rt][0][r]+acc[rt][1][r]+acc[rt][2][r]+acc[rt][3][r];
      float ss = acc[rt][0][r]*acc[rt][0][r]+acc[rt][1][r]*acc[rt][1][r]
               + acc[rt][2][r]*acc[rt][2][r]+acc[rt][3][r]*acc[rt][3][r];
      #pragma unroll
      for (int mk=1; mk<16; mk<<=1){ s += __shfl_xor(s,mk,64); ss += __shfl_xor(ss,mk,64); }
      const float mu = s*(1.f/64.f);
      const float var = ss*(1.f/64.f) - mu*mu;
      const float rs = rsqrtf(var + 1e-5f);
      const size_t row = rb + rt*16 + quad*4 + r;
      #pragma unroll
      for (int ct=0;ct<4;++ct){
        const int n = ct*16 + mrow;
        out[row*64 + n] = (acc[rt][ct][r]-mu)*rs*g[n] + bt[n] + feat[row*64 + n];
      }
    }
}

// ---------------- launcher ----------------
extern "C" void kernel_launch(void* const* d_in, const int* in_sizes, int n_in,
                              void* d_out, int out_size, void* d_ws, size_t ws_size,
                              hipStream_t stream){
  const float* xyz    = (const float*)d_in[0];
  const float* feat   = (const float*)d_in[1];
  const float* W_pre  = (const float*)d_in[2];
  const float* b_pre  = (const float*)d_in[3];
  const float* W_post = (const float*)d_in[4];
  const float* b_post = (const float*)d_in[5];
  const float* Wp1    = (const float*)d_in[6];
  const float* Wp2    = (const float*)d_in[7];
  const float* Wa1    = (const float*)d_in[8];
  const float* Wa2    = (const float*)d_in[9];
  const float* WQ     = (const float*)d_in[10];
  const float* WK     = (const float*)d_in[11];
  const float* WV     = (const float*)d_in[12];
  const float* Wproj  = (const float*)d_in[13];
  const float* g_dm   = (const float*)d_in[14];
  const float* b_dm   = (const float*)d_in[15];
  const float* g_dp   = (const float*)d_in[16];
  const float* b_dp   = (const float*)d_in[17];
  float* out = (float*)d_out;
  if (ws_size < WS_NEED) return;
  char* ws = (char*)d_ws;
  int* idxw   = (int*)(ws + OFF_IDX);
  u16* featb  = (u16*)(ws + OFF_FEATB);
  u16* wpreb  = (u16*)(ws + OFF_WPRE);
  u16* wqkvb  = (u16*)(ws + OFF_WQKV);
  u16* wa1b   = (u16*)(ws + OFF_WA1);
  u16* wa2b   = (u16*)(ws + OFF_WA2);
  u16* wp2b   = (u16*)(ws + OFF_WP2);
  u16* wprojb = (u16*)(ws + OFF_WPROJ);
  u16* wpostb = (u16*)(ws + OFF_WPOST);
  u16* mcombb = (u16*)(ws + OFF_MCOMB);
  u16* inp    = (u16*)(ws + OFF_INP);
  u16* qkv    = (u16*)(ws + OFF_QKV);
  u16* lnqkv  = (u16*)(ws + OFF_LNQKV);
  u16* qab    = (u16*)(ws + OFF_QA);
  u16* kab    = (u16*)(ws + OFF_KA);
  u16* resb   = (u16*)(ws + OFF_RES);
  u16* d1raw  = (u16*)(ws + OFF_D1);
  u16* r1b    = (u16*)(ws + OFF_R1);
  u16* wp1pk  = (u16*)(ws + OFF_WP1PK);   // aliases d1raw: read by attn_k before d1 GEMM writes
  u16* wp2T   = (u16*)(ws + OFF_WP2T);    // aliases qkv: consumed before qkv GEMM writes

  convert_k<<<6016,256,0,stream>>>(feat,W_pre,WQ,WK,WV,Wa1,Wa2,Wp2,Wproj,W_post,
                                   featb,wpreb,wqkvb,wa1b,wa2b,wp2b,wprojb,wpostb);
  transpose_k<<<64,256,0,stream>>>(wp2b, wp2T);
  // Mcomb = Wa1 @ Wp2 : C[f][h] = sum_k wa1[f][k] * wp2T[h][k]
  gemm128_k<<<dim3(2,2),256,0,stream>>>(wa1b,256, wp2T,256, mcombb,256, 256, nullptr);
  wp1pack_k<<<1,256,0,stream>>>(Wp1,wp1pk);
  knn_kernel<<<512,256,0,stream>>>(xyz,idxw);
  // inp = features @ W_pre.T + b_pre
  gemm128_k<<<dim3(128,2),256,0,stream>>>(featb,64,  wpreb,64,  inp,256, 64,  b_pre);
  // qkv = inp @ [WQ|WK|WV].T
  gemm128_k<<<dim3(128,6),256,0,stream>>>(inp,256,   wqkvb,256, qkv,768, 256, nullptr);
  ln256_k<<<12288,256,0,stream>>>(qkv,lnqkv,g_dm,b_dm);
  // qa = ln(q) @ Wa1.T ; ka = ln(k) @ Wa1.T
  gemm128_k<<<dim3(128,2),256,0,stream>>>(lnqkv,768,     wa1b,256, qab,256, 256, nullptr);
  gemm128_k<<<dim3(128,2),256,0,stream>>>(lnqkv+256,768, wa1b,256, kab,256, 256, nullptr);
  attn_k<<<4096,512,0,stream>>>(xyz,idxw,lnqkv,qab,kab,mcombb,wp2b,wa2b,wp1pk,resb);
  // d1 = res @ Wproj.T ; r1 = ln(d1)
  gemm128_k<<<dim3(128,2),256,0,stream>>>(resb,256, wprojb,256, d1raw,256, 256, nullptr);
  ln256_k<<<4096,256,0,stream>>>(d1raw,r1b,g_dm,b_dm);
  d2_k<<<128,256,0,stream>>>(r1b,wpostb,b_post,g_dp,b_dp,feat,out);
}

// Round 8
// 597.204 us; speedup vs baseline: 1.3992x; 1.1083x over previous
//
#include <hip/hip_runtime.h>

typedef unsigned short u16;
typedef unsigned int   u32;
typedef __attribute__((ext_vector_type(8))) short bf16x8;
typedef __attribute__((ext_vector_type(4))) float f32x4;

#define MFMA16(a,b,c) __builtin_amdgcn_mfma_f32_16x16x32_bf16((a),(b),(c),0,0,0)

__device__ __forceinline__ float b2f(u32 h){ return __uint_as_float(h<<16); }
__device__ __forceinline__ u16 f2b(float f){
  u32 u = __float_as_uint(f);
  return (u16)((u + 0x7FFFu + ((u>>16)&1u))>>16);
}
__device__ __forceinline__ u32 pk2f(float a,float b){ return (u32)f2b(a) | ((u32)f2b(b)<<16); }
__device__ __forceinline__ u32 umin32(u32 a,u32 b){ return a<b?a:b; }
__device__ __forceinline__ u32 umax32(u32 a,u32 b){ return a>b?a:b; }

__device__ __forceinline__ void async_copy16(const void* g, void* l){
  __builtin_amdgcn_global_load_lds((const __attribute__((address_space(1))) u32*)g,
                                   (__attribute__((address_space(3))) u32*)l, 16, 0, 0);
}

// ---------------- workspace layout (bytes) ----------------
#define OFF_IDX    0ull
#define OFF_FEATB  1048576ull
#define OFF_WPRE   3145728ull
#define OFF_WQKV   3178496ull
#define OFF_WA1    3571712ull
#define OFF_WA2    3702784ull
#define OFF_WP2    3833856ull
#define OFF_WPROJ  3964928ull
#define OFF_WPOST  4096000ull
#define OFF_MCOMB  4128768ull
#define OFF_INP    4259840ull
#define OFF_QKV    12648448ull
#define OFF_LNQKV  37814272ull
#define OFF_QA     62980096ull
#define OFF_KA     71368704ull
#define OFF_RES    79757312ull
#define OFF_D1     88145920ull     // also hosts wp1pk early (d1 written only after attn)
#define OFF_R1     96534528ull
#define WS_NEED    104923136ull
#define OFF_WP1PK  OFF_D1
#define OFF_WP2T   OFF_QKV         // wp2^T consumed by mcomb GEMM before qkv GEMM writes here

// ---------------- f32 -> bf16 conversions ----------------
__global__ void convert_k(const float* __restrict__ feat, const float* __restrict__ wpre,
    const float* __restrict__ wq, const float* __restrict__ wk, const float* __restrict__ wv,
    const float* __restrict__ wa1, const float* __restrict__ wa2, const float* __restrict__ wp2,
    const float* __restrict__ wproj, const float* __restrict__ wpost,
    u16* __restrict__ dfeat, u16* __restrict__ dwpre, u16* __restrict__ dwqkv,
    u16* __restrict__ dwa1, u16* __restrict__ dwa2, u16* __restrict__ dwp2,
    u16* __restrict__ dwproj, u16* __restrict__ dwpost){
  int id = blockIdx.x*256 + threadIdx.x;
  const float* s; u16* d; int off;
  if      (id < 1048576){ s=feat;  d=dfeat;        off=id; }
  else if (id < 1064960){ s=wpre;  d=dwpre;        off=id-1048576; }
  else if (id < 1130496){ s=wq;    d=dwqkv;        off=id-1064960; }
  else if (id < 1196032){ s=wk;    d=dwqkv+65536;  off=id-1130496; }
  else if (id < 1261568){ s=wv;    d=dwqkv+131072; off=id-1196032; }
  else if (id < 1327104){ s=wa1;   d=dwa1;         off=id-1261568; }
  else if (id < 1392640){ s=wa2;   d=dwa2;         off=id-1327104; }
  else if (id < 1458176){ s=wp2;   d=dwp2;         off=id-1392640; }
  else if (id < 1523712){ s=wproj; d=dwproj;       off=id-1458176; }
  else if (id < 1540096){ s=wpost; d=dwpost;       off=id-1523712; }
  else return;
  d[off] = f2b(s[off]);
}

// 256x256 bf16 transpose (for Mcomb GEMM's B operand)
__global__ void transpose_k(const u16* __restrict__ in, u16* __restrict__ out){
  __shared__ u16 t[32][33];
  const int tid = threadIdx.x, tx = tid & 31, ty = tid >> 5;   // 8 rows
  const int bx = blockIdx.x & 7, by = blockIdx.x >> 3;
  #pragma unroll
  for (int r = 0; r < 4; ++r) t[ty+8*r][tx] = in[(by*32+ty+8*r)*256 + bx*32+tx];
  __syncthreads();
  #pragma unroll
  for (int r = 0; r < 4; ++r) out[(bx*32+ty+8*r)*256 + by*32+tx] = t[tx][ty+8*r];
}

// Wp1 packed for MFMA A-operand: [256 h][32 k] bf16, k=0..2 = Wp1[h][*], rest 0
__global__ void wp1pack_k(const float* __restrict__ wp1, u16* __restrict__ out){
  const int h = threadIdx.x;
  const float w0 = wp1[h*3], w1 = wp1[h*3+1], w2 = wp1[h*3+2];
  uint4 a; a.x = pk2f(w0,w1); a.y = pk2f(w2,0.f); a.z = 0u; a.w = 0u;
  uint4 z; z.x = z.y = z.z = z.w = 0u;
  *(uint4*)&out[h*32]    = a;
  *(uint4*)&out[h*32+8]  = z;
  *(uint4*)&out[h*32+16] = z;
  *(uint4*)&out[h*32+24] = z;
}

// ---------------- kNN: exact top-16 by (d2, idx) ----------------
__device__ __forceinline__ void ins16(u32 (&a)[16], u32 key){
  #pragma unroll
  for (int j = 15; j >= 1; --j) a[j] = umin32(umax32(a[j-1],key), a[j]);
  a[0] = umin32(a[0], key);
}

__device__ __forceinline__ float dist2(float ax,float ay,float az,float bx,float by,float bz){
  const float dx = ax-bx, dy = ay-by, dz = az-bz;
  return __fmaf_rn(dx,dx, __fmaf_rn(dy,dy, dz*dz));   // identical sequence both phases
}

__global__ __launch_bounds__(256,2) void knn_kernel(const float* __restrict__ xyz,
                                                    int* __restrict__ idxout){
  __shared__ __attribute__((aligned(16))) float sbuf[3*4104];
  __shared__ int lcnt[32];
  __shared__ int tcnt[32];
  __shared__ u32 tbuf[32];
  __shared__ int tiebuf[32*16];
  float* sx = sbuf; float* sy = sbuf + 4104; float* sz = sbuf + 8208;
  const int tid = threadIdx.x;
  const int b  = blockIdx.x >> 7;
  const int n0 = (blockIdx.x & 127) << 5;
  const float* base = xyz + (size_t)b*12288;
  #pragma unroll
  for (int i = 0; i < 12; ++i){
    const float4 v = *(const float4*)(base + tid*48 + i*4);
    const float vv[4] = {v.x, v.y, v.z, v.w};
    #pragma unroll
    for (int j = 0; j < 4; ++j){
      const int e = i*4 + j;
      const int c = e % 3;
      const int m = tid*16 + e/3;
      float* arr = (c==0)?sx:((c==1)?sy:sz);
      arr[m + (m>>9)] = vv[j];
    }
  }
  if (tid < 32){ lcnt[tid] = 0; tcnt[tid] = 0; }
  __syncthreads();
  const int qi = tid >> 3, p = tid & 7;
  const int n = n0 + qi;
  const int sn = n + (n>>9);
  const float qx = sx[sn], qy = sy[sn], qz = sz[sn];
  u32 a[16];
  #pragma unroll
  for (int j = 0; j < 16; ++j) a[j] = 0xFFFFFFFFu;
  const int sb = p*513;
  #pragma unroll 2
  for (int i = 0; i < 512; ++i){
    const float d2 = dist2(sx[sb+i],sy[sb+i],sz[sb+i],qx,qy,qz);
    ins16(a, __float_as_uint(d2));
  }
  #pragma unroll
  for (int s = 4; s >= 1; s >>= 1){
    u32 o[16];
    #pragma unroll
    for (int j = 0; j < 16; ++j) o[j] = __shfl_down(a[j], (unsigned)s, 64);
    if (p < s){
      #pragma unroll
      for (int j = 0; j < 16; ++j) ins16(a, o[j]);
    }
  }
  if (p == 0) tbuf[qi] = a[15];
  __syncthreads();
  const u32 T = tbuf[qi];
  int* orow = idxout + ((size_t)(b<<12)+n)*16;
  const int gbase = p*512;
  for (int i = 0; i < 512; ++i){
    const float d2 = dist2(sx[sb+i],sy[sb+i],sz[sb+i],qx,qy,qz);
    const u32 kb = __float_as_uint(d2);
    if (kb < T){
      const int pos = atomicAdd(&lcnt[qi],1);
      if (pos < 16) orow[pos] = gbase + i;
    } else if (kb == T){
      const int t = atomicAdd(&tcnt[qi],1);
      if (t < 16) tiebuf[qi*16+t] = gbase + i;
    }
  }
  __syncthreads();
  if (p == 0){
    int L = lcnt[qi]; if (L > 16) L = 16;
    int tc = tcnt[qi]; if (tc > 16) tc = 16;
    const int need = 16 - L;
    for (int r = 0; r < need; ++r){
      int best = 0x7FFFFFFF, bj = -1;
      for (int j = 0; j < tc; ++j){
        const int v = tiebuf[qi*16+j];
        if (v < best){ best = v; bj = j; }
      }
      if (bj >= 0){ tiebuf[qi*16+bj] = 0x7FFFFFFF; orow[L+r] = best; }
      else orow[L+r] = n;
    }
  }
}

// ---------------- generic 128x128 bf16 GEMM: C[m][n] = sum_k A[m][k]*B[n][k] (+bias) ----------------
__global__ __launch_bounds__(256,2) void gemm128_k(
    const u16* __restrict__ A, const int lda,
    const u16* __restrict__ Bw, const int ldb,
    u16* __restrict__ C, const int ldc,
    const int K, const float* __restrict__ bias){
  __shared__ __attribute__((aligned(16))) u16 As[128*32];
  __shared__ __attribute__((aligned(16))) u16 Bs[128*32];
  const int tid = threadIdx.x, lane = tid & 63, w = tid >> 6;
  const int mrow = lane & 15, quad = lane >> 4;
  const size_t mbase = (size_t)blockIdx.x*128, nbase = (size_t)blockIdx.y*128;
  const int wr = (w&1)*64, wc = (w>>1)*64;
  f32x4 acc[4][4];
  #pragma unroll
  for (int i=0;i<4;++i)
    #pragma unroll
    for (int j=0;j<4;++j)
      #pragma unroll
      for (int r=0;r<4;++r) acc[i][j][r] = 0.f;
  const int sr = tid >> 2, sk = (tid & 3)*8;
  u16* lA0 = &As[w*512]; u16* lA1 = &As[2048 + w*512];
  u16* lB0 = &Bs[w*512]; u16* lB1 = &Bs[2048 + w*512];
  for (int k0 = 0; k0 < K; k0 += 32){
    __syncthreads();
    async_copy16(A  + (mbase      + sr)*(size_t)lda + k0 + sk, lA0);
    async_copy16(A  + (mbase + 64 + sr)*(size_t)lda + k0 + sk, lA1);
    async_copy16(Bw + (nbase      + sr)*(size_t)ldb + k0 + sk, lB0);
    async_copy16(Bw + (nbase + 64 + sr)*(size_t)ldb + k0 + sk, lB1);
    __syncthreads();
    bf16x8 af[4], bf[4];
    #pragma unroll
    for (int rt=0;rt<4;++rt) af[rt] = *(const bf16x8*)&As[(wr+rt*16+mrow)*32 + quad*8];
    #pragma unroll
    for (int ct=0;ct<4;++ct) bf[ct] = *(const bf16x8*)&Bs[(wc+ct*16+mrow)*32 + quad*8];
    #pragma unroll
    for (int rt=0;rt<4;++rt)
      #pragma unroll
      for (int ct=0;ct<4;++ct) acc[rt][ct] = MFMA16(af[rt], bf[ct], acc[rt][ct]);
  }
  #pragma unroll
  for (int rt=0;rt<4;++rt)
    #pragma unroll
    for (int ct=0;ct<4;++ct){
      const size_t row0 = mbase + wr + rt*16 + quad*4;
      const int col = (int)nbase + wc + ct*16 + mrow;
      const float bv = bias ? bias[col] : 0.f;
      #pragma unroll
      for (int r=0;r<4;++r) C[(row0+r)*(size_t)ldc + col] = f2b(acc[rt][ct][r] + bv);
    }
}

// ---------------- LayerNorm over 256-element groups, bf16 in/out ----------------
__global__ __launch_bounds__(256,2) void ln256_k(const u16* __restrict__ in, u16* __restrict__ out,
    const float* __restrict__ g, const float* __restrict__ bta){
  const int tid = threadIdx.x, lane = tid & 63, w = tid >> 6;
  const size_t row = (size_t)blockIdx.x*4 + w;
  const uint2 u = *(const uint2*)(in + row*256 + lane*4);
  const float x0=b2f(u.x&0xffff), x1=b2f(u.x>>16), x2=b2f(u.y&0xffff), x3=b2f(u.y>>16);
  float s  = x0+x1+x2+x3;
  float ss = x0*x0+x1*x1+x2*x2+x3*x3;
  #pragma unroll
  for (int mk=1; mk<64; mk<<=1){ s += __shfl_xor(s,mk,64); ss += __shfl_xor(ss,mk,64); }
  const float mu = s*(1.f/256.f);
  const float var = ss*(1.f/256.f) - mu*mu;
  const float rs = rsqrtf(var + 1e-5f);
  const int c = lane*4;
  const float y0=(x0-mu)*rs*g[c  ]+bta[c  ];
  const float y1=(x1-mu)*rs*g[c+1]+bta[c+1];
  const float y2=(x2-mu)*rs*g[c+2]+bta[c+2];
  const float y3=(x3-mu)*rs*g[c+3]+bta[c+3];
  uint2 o; o.x = pk2f(y0,y1); o.y = pk2f(y2,y3);
  *(uint2*)(out + row*256 + lane*4) = o;
}

// ---------------- fused per-neighbor attention kernel (v8: av->LDS so 128-reg budget holds) ----------------
// block = 64 rows (4 queries x 16), 512 threads = 8 waves, wave w owns f-slice [w*32,w*32+32), all 64 m.
// __launch_bounds__(512,4): 128-reg budget. av tile parked in LDS (bf16) across G2 so G2's live set
// fits; 2 blocks/CU (LDS 73KB x2 = 146 <= 160) -> 16 waves/CU.
#define DP   264
#define RELP 40
__global__ __launch_bounds__(512,4) void attn_k(
    const float* __restrict__ xyz, const int* __restrict__ idxb,
    const u16* __restrict__ lnqkv, const u16* __restrict__ qa, const u16* __restrict__ ka,
    const u16* __restrict__ mcomb, const u16* __restrict__ wp2, const u16* __restrict__ wa2,
    const u16* __restrict__ wp1pk, u16* __restrict__ res){
  __shared__ __attribute__((aligned(16))) u16 hbuf[64*DP];    // h1, then h2 (33.8 KB)
  __shared__ __attribute__((aligned(16))) u16 avbuf[64*DP];   // av parked across G2 (33.8 KB)
  __shared__ __attribute__((aligned(16))) u16 srel[64*RELP];  // rel bf16, k-padded to 32
  __shared__ int sidx[64];
  const int tid = threadIdx.x;
  const int b = blockIdx.x >> 10;                // 1024 blocks per batch
  const int nbase = (blockIdx.x & 1023) << 2;    // 4 queries
  const size_t gb = (size_t)b << 12;
  // ---- stage neighbor idx + rel
  if (tid < 64){
    const int m = tid;
    const int im = idxb[(gb + nbase + (m>>4))*16 + (m&15)] & 4095;
    sidx[m] = im;
    const int nn = nbase + (m>>4);
    const float* pq = xyz + (gb+nn)*3;
    const float* pm = xyz + (gb+im)*3;
    const float rx = pq[0]-pm[0], ry = pq[1]-pm[1], rz = pq[2]-pm[2];
    uint4 a; a.x = pk2f(rx,ry); a.y = pk2f(rz,0.f); a.z = 0u; a.w = 0u;
    uint4 z; z.x = z.y = z.z = z.w = 0u;
    *(uint4*)&srel[m*RELP]    = a;
    *(uint4*)&srel[m*RELP+8]  = z;
    *(uint4*)&srel[m*RELP+16] = z;
    *(uint4*)&srel[m*RELP+24] = z;
  }
  __syncthreads();
  const int lane = tid & 63, w = tid >> 6;
  const int mrow = lane & 15, quad = lane >> 4;
  const int fr = w << 5;                         // 32-wide f/h slice of this wave
  // ---- h1 via MFMA: D[h][m] for h in [fr,fr+32), m in [0,64)
  {
    bf16x8 aW[2], bR[4];
    #pragma unroll
    for (int ht=0;ht<2;++ht) aW[ht] = *(const bf16x8*)&wp1pk[(fr+ht*16+mrow)*32 + quad*8];
    #pragma unroll
    for (int mt=0;mt<4;++mt) bR[mt] = *(const bf16x8*)&srel[(mt*16+mrow)*RELP + quad*8];
    #pragma unroll
    for (int ht=0;ht<2;++ht)
      #pragma unroll
      for (int mt=0;mt<4;++mt){
        f32x4 hz;
        #pragma unroll
        for (int r=0;r<4;++r) hz[r]=0.f;
        hz = MFMA16(aW[ht], bR[mt], hz);
        float h0 = hz[0]>0.f?hz[0]:0.f, h1v = hz[1]>0.f?hz[1]:0.f;
        float h2v = hz[2]>0.f?hz[2]:0.f, h3 = hz[3]>0.f?hz[3]:0.f;
        uint2 o; o.x = pk2f(h0,h1v); o.y = pk2f(h2v,h3);
        *(uint2*)&hbuf[(mt*16+mrow)*DP + fr + ht*16 + quad*4] = o;
      }
  }
  int midx[4];
  #pragma unroll
  for (int mt = 0; mt < 4; ++mt) midx[mt] = sidx[mt*16 + mrow];
  __syncthreads();             // h1 complete
  // ---- G1: t.T and val.T
  f32x4 at[2][4], av[2][4];
  #pragma unroll
  for (int i=0;i<2;++i)
    #pragma unroll
    for (int j=0;j<4;++j)
      #pragma unroll
      for (int r=0;r<4;++r){ at[i][j][r]=0.f; av[i][j][r]=0.f; }
  #pragma unroll 1
  for (int ks = 0; ks < 8; ++ks){
    const int koff = ks*32 + quad*8;
    bf16x8 aM[2], aP[2], bH[4];
    #pragma unroll
    for (int ft=0;ft<2;++ft){
      aM[ft] = *(const bf16x8*)&mcomb[(fr+ft*16+mrow)*256 + koff];
      aP[ft] = *(const bf16x8*)&wp2  [(fr+ft*16+mrow)*256 + koff];
    }
    #pragma unroll
    for (int mt=0;mt<4;++mt) bH[mt] = *(const bf16x8*)&hbuf[(mt*16+mrow)*DP + koff];
    #pragma unroll
    for (int ft=0;ft<2;++ft)
      #pragma unroll
      for (int mt=0;mt<4;++mt){
        at[ft][mt] = MFMA16(aM[ft], bH[mt], at[ft][mt]);
        av[ft][mt] = MFMA16(aP[ft], bH[mt], av[ft][mt]);
      }
  }
  // ---- qkp gather AFTER G1 (barrier wait below hides the latency; keeps G1 live-set small)
  uint2 qkp[2][4];
  #pragma unroll
  for (int ft = 0; ft < 2; ++ft)
    #pragma unroll
    for (int mt = 0; mt < 4; ++mt){
      const int f = fr + ft*16 + quad*4;
      const uint2 uq = *(const uint2*)&qa[(gb + nbase + mt)*256 + f];
      const uint2 uk = *(const uint2*)&ka[(gb + (size_t)midx[mt])*256 + f];
      uint2 o;
      o.x = pk2f(b2f(uq.x&0xffff)-b2f(uk.x&0xffff), b2f(uq.x>>16)-b2f(uk.x>>16));
      o.y = pk2f(b2f(uq.y&0xffff)-b2f(uk.y&0xffff), b2f(uq.y>>16)-b2f(uk.y>>16));
      qkp[ft][mt] = o;
    }
  __syncthreads();             // all waves done reading h1
  // ---- epilogue: h2 = relu(t + (qa-ka)) -> hbuf ; av -> avbuf (bf16), regs freed
  #pragma unroll
  for (int ft=0;ft<2;++ft)
    #pragma unroll
    for (int mt=0;mt<4;++mt){
      const int moff = (mt*16+mrow)*DP + fr + ft*16 + quad*4;
      const uint2 qv = qkp[ft][mt];
      float t0 = at[ft][mt][0] + b2f(qv.x&0xffff);
      float t1 = at[ft][mt][1] + b2f(qv.x>>16);
      float t2 = at[ft][mt][2] + b2f(qv.y&0xffff);
      float t3 = at[ft][mt][3] + b2f(qv.y>>16);
      t0 = t0>0.f?t0:0.f; t1 = t1>0.f?t1:0.f; t2 = t2>0.f?t2:0.f; t3 = t3>0.f?t3:0.f;
      uint2 o; o.x = pk2f(t0,t1); o.y = pk2f(t2,t3);
      *(uint2*)&hbuf[moff] = o;
      uint2 va; va.x = pk2f(av[ft][mt][0],av[ft][mt][1]); va.y = pk2f(av[ft][mt][2],av[ft][mt][3]);
      *(uint2*)&avbuf[moff] = va;
    }
  // ---- v gather prefetch (av/at regs dead; consumed after G2; barrier hides latency)
  uint2 vpre[2][4];
  #pragma unroll
  for (int ft=0;ft<2;++ft)
    #pragma unroll
    for (int mt=0;mt<4;++mt)
      vpre[ft][mt] = *(const uint2*)&lnqkv[(gb + (size_t)midx[mt])*768 + 512 + fr + ft*16 + quad*4];
  __syncthreads();
  // ---- G2: logits.T = Wa2 @ h2.T
  f32x4 al[2][4];
  #pragma unroll
  for (int i=0;i<2;++i)
    #pragma unroll
    for (int j=0;j<4;++j)
      #pragma unroll
      for (int r=0;r<4;++r) al[i][j][r]=0.f;
  #pragma unroll 1
  for (int ks = 0; ks < 8; ++ks){
    const int koff = ks*32 + quad*8;
    bf16x8 aW[2], bH[4];
    #pragma unroll
    for (int gt=0;gt<2;++gt) aW[gt] = *(const bf16x8*)&wa2[(fr+gt*16+mrow)*256 + koff];
    #pragma unroll
    for (int mt=0;mt<4;++mt) bH[mt] = *(const bf16x8*)&hbuf[(mt*16+mrow)*DP + koff];
    #pragma unroll
    for (int gt=0;gt<2;++gt)
      #pragma unroll
      for (int mt=0;mt<4;++mt) al[gt][mt] = MFMA16(aW[gt], bH[mt], al[gt][mt]);
  }
  // ---- softmax over 16 neighbors (= lane&15) + weighted reduce (av reloaded from LDS)
  const float sc = 0.0901684f;   // log2(e)/sqrt(256)
  #pragma unroll
  for (int gt=0;gt<2;++gt)
    #pragma unroll
    for (int mt=0;mt<4;++mt){
      const uint2 va = *(const uint2*)&avbuf[(mt*16+mrow)*DP + fr + gt*16 + quad*4];
      float avv[4];
      avv[0] = b2f(va.x&0xffff); avv[1] = b2f(va.x>>16);
      avv[2] = b2f(va.y&0xffff); avv[3] = b2f(va.y>>16);
      float rv[4];
      #pragma unroll
      for (int r=0;r<4;++r){
        u32 hv;
        if      (r==0) hv = vpre[gt][mt].x & 0xffff;
        else if (r==1) hv = vpre[gt][mt].x >> 16;
        else if (r==2) hv = vpre[gt][mt].y & 0xffff;
        else           hv = vpre[gt][mt].y >> 16;
        const float val = avv[r] + b2f(hv);
        float pr = exp2f(al[gt][mt][r]*sc);   // logits are O(1); no max-sub needed
        float wg = pr*val;
        #pragma unroll
        for (int mk=1; mk<16; mk<<=1){ pr += __shfl_xor(pr,mk,64); wg += __shfl_xor(wg,mk,64); }
        rv[r] = wg * __builtin_amdgcn_rcpf(pr);
      }
      if (mrow == 0){
        uint2 o; o.x = pk2f(rv[0],rv[1]); o.y = pk2f(rv[2],rv[3]);
        *(uint2*)&res[(gb + nbase + mt)*256 + fr + gt*16 + quad*4] = o;
      }
    }
}

// ---------------- final: out = ln(r1 @ W_post.T + b_post)*g+b + features ----------------
__global__ __launch_bounds__(256,2) void d2_k(
    const u16* __restrict__ r1, const u16* __restrict__ wpost,
    const float* __restrict__ bpost, const float* __restrict__ g, const float* __restrict__ bt,
    const float* __restrict__ feat, float* __restrict__ out){
  const int tid = threadIdx.x, lane = tid & 63, w = tid >> 6;
  const int mrow = lane & 15, quad = lane >> 4;
  const size_t rb = (size_t)blockIdx.x*128 + w*32;
  f32x4 acc[2][4];
  #pragma unroll
  for (int i=0;i<2;++i)
    #pragma unroll
    for (int j=0;j<4;++j)
      #pragma unroll
      for (int r=0;r<4;++r) acc[i][j][r]=0.f;
  #pragma unroll 1
  for (int ks = 0; ks < 8; ++ks){
    const int koff = ks*32 + quad*8;
    bf16x8 af[2], bf[4];
    #pragma unroll
    for (int rt=0;rt<2;++rt) af[rt] = *(const bf16x8*)&r1[(rb+rt*16+mrow)*256 + koff];
    #pragma unroll
    for (int ct=0;ct<4;++ct) bf[ct] = *(const bf16x8*)&wpost[(ct*16+mrow)*256 + koff];
    #pragma unroll
    for (int rt=0;rt<2;++rt)
      #pragma unroll
      for (int ct=0;ct<4;++ct) acc[rt][ct] = MFMA16(af[rt], bf[ct], acc[rt][ct]);
  }
  #pragma unroll
  for (int ct=0;ct<4;++ct){
    const float bv = bpost[ct*16+mrow];
    #pragma unroll
    for (int rt=0;rt<2;++rt)
      #pragma unroll
      for (int r=0;r<4;++r) acc[rt][ct][r] += bv;
  }
  #pragma unroll
  for (int rt=0;rt<2;++rt)
    #pragma unroll
    for (int r=0;r<4;++r){
      float s  = acc[rt][0][r]+acc[rt][1][r]+acc[rt][2][r]+acc[rt][3][r];
      float ss = acc[rt][0][r]*acc[rt][0][r]+acc[rt][1][r]*acc[rt][1][r]
               + acc[rt][2][r]*acc[rt][2][r]+acc[rt][3][r]*acc[rt][3][r];
      #pragma unroll
      for (int mk=1; mk<16; mk<<=1){ s += __shfl_xor(s,mk,64); ss += __shfl_xor(ss,mk,64); }
      const float mu = s*(1.f/64.f);
      const float var = ss*(1.f/64.f) - mu*mu;
      const float rs = rsqrtf(var + 1e-5f);
      const size_t row = rb + rt*16 + quad*4 + r;
      #pragma unroll
      for (int ct=0;ct<4;++ct){
        const int n = ct*16 + mrow;
        out[row*64 + n] = (acc[rt][ct][r]-mu)*rs*g[n] + bt[n] + feat[row*64 + n];
      }
    }
}

// ---------------- launcher ----------------
extern "C" void kernel_launch(void* const* d_in, const int* in_sizes, int n_in,
                              void* d_out, int out_size, void* d_ws, size_t ws_size,
                              hipStream_t stream){
  const float* xyz    = (const float*)d_in[0];
  const float* feat   = (const float*)d_in[1];
  const float* W_pre  = (const float*)d_in[2];
  const float* b_pre  = (const float*)d_in[3];
  const float* W_post = (const float*)d_in[4];
  const float* b_post = (const float*)d_in[5];
  const float* Wp1    = (const float*)d_in[6];
  const float* Wp2    = (const float*)d_in[7];
  const float* Wa1    = (const float*)d_in[8];
  const float* Wa2    = (const float*)d_in[9];
  const float* WQ     = (const float*)d_in[10];
  const float* WK     = (const float*)d_in[11];
  const float* WV     = (const float*)d_in[12];
  const float* Wproj  = (const float*)d_in[13];
  const float* g_dm   = (const float*)d_in[14];
  const float* b_dm   = (const float*)d_in[15];
  const float* g_dp   = (const float*)d_in[16];
  const float* b_dp   = (const float*)d_in[17];
  float* out = (float*)d_out;
  if (ws_size < WS_NEED) return;
  char* ws = (char*)d_ws;
  int* idxw   = (int*)(ws + OFF_IDX);
  u16* featb  = (u16*)(ws + OFF_FEATB);
  u16* wpreb  = (u16*)(ws + OFF_WPRE);
  u16* wqkvb  = (u16*)(ws + OFF_WQKV);
  u16* wa1b   = (u16*)(ws + OFF_WA1);
  u16* wa2b   = (u16*)(ws + OFF_WA2);
  u16* wp2b   = (u16*)(ws + OFF_WP2);
  u16* wprojb = (u16*)(ws + OFF_WPROJ);
  u16* wpostb = (u16*)(ws + OFF_WPOST);
  u16* mcombb = (u16*)(ws + OFF_MCOMB);
  u16* inp    = (u16*)(ws + OFF_INP);
  u16* qkv    = (u16*)(ws + OFF_QKV);
  u16* lnqkv  = (u16*)(ws + OFF_LNQKV);
  u16* qab    = (u16*)(ws + OFF_QA);
  u16* kab    = (u16*)(ws + OFF_KA);
  u16* resb   = (u16*)(ws + OFF_RES);
  u16* d1raw  = (u16*)(ws + OFF_D1);
  u16* r1b    = (u16*)(ws + OFF_R1);
  u16* wp1pk  = (u16*)(ws + OFF_WP1PK);   // aliases d1raw: read by attn_k before d1 GEMM writes
  u16* wp2T   = (u16*)(ws + OFF_WP2T);    // aliases qkv: consumed before qkv GEMM writes

  convert_k<<<6016,256,0,stream>>>(feat,W_pre,WQ,WK,WV,Wa1,Wa2,Wp2,Wproj,W_post,
                                   featb,wpreb,wqkvb,wa1b,wa2b,wp2b,wprojb,wpostb);
  transpose_k<<<64,256,0,stream>>>(wp2b, wp2T);
  // Mcomb = Wa1 @ Wp2 : C[f][h] = sum_k wa1[f][k] * wp2T[h][k]
  gemm128_k<<<dim3(2,2),256,0,stream>>>(wa1b,256, wp2T,256, mcombb,256, 256, nullptr);
  wp1pack_k<<<1,256,0,stream>>>(Wp1,wp1pk);
  knn_kernel<<<512,256,0,stream>>>(xyz,idxw);
  // inp = features @ W_pre.T + b_pre
  gemm128_k<<<dim3(128,2),256,0,stream>>>(featb,64,  wpreb,64,  inp,256, 64,  b_pre);
  // qkv = inp @ [WQ|WK|WV].T
  gemm128_k<<<dim3(128,6),256,0,stream>>>(inp,256,   wqkvb,256, qkv,768, 256, nullptr);
  ln256_k<<<12288,256,0,stream>>>(qkv,lnqkv,g_dm,b_dm);
  // qa = ln(q) @ Wa1.T ; ka = ln(k) @ Wa1.T
  gemm128_k<<<dim3(128,2),256,0,stream>>>(lnqkv,768,     wa1b,256, qab,256, 256, nullptr);
  gemm128_k<<<dim3(128,2),256,0,stream>>>(lnqkv+256,768, wa1b,256, kab,256, 256, nullptr);
  attn_k<<<4096,512,0,stream>>>(xyz,idxw,lnqkv,qab,kab,mcombb,wp2b,wa2b,wp1pk,resb);
  // d1 = res @ Wproj.T ; r1 = ln(d1)
  gemm128_k<<<dim3(128,2),256,0,stream>>>(resb,256, wprojb,256, d1raw,256, 256, nullptr);
  ln256_k<<<4096,256,0,stream>>>(d1raw,r1b,g_dm,b_dm);
  d2_k<<<128,256,0,stream>>>(r1b,wpostb,b_post,g_dp,b_dp,feat,out);
}

// Round 9
// 589.288 us; speedup vs baseline: 1.4180x; 1.0134x over previous
//
#include <hip/hip_runtime.h>
#include <hip/hip_bf16.h>

typedef unsigned short u16;
typedef unsigned int   u32;
typedef __attribute__((ext_vector_type(8))) short bf16x8;
typedef __attribute__((ext_vector_type(4))) float f32x4;

#define MFMA16(a,b,c) __builtin_amdgcn_mfma_f32_16x16x32_bf16((a),(b),(c),0,0,0)

__device__ __forceinline__ float b2f(u32 h){ return __uint_as_float(h<<16); }
__device__ __forceinline__ u16 f2b(float f){
  u32 u = __float_as_uint(f);
  return (u16)((u + 0x7FFFu + ((u>>16)&1u))>>16);
}
// HW packed convert: v_cvt_pk_bf16_f32 (RNE, same as manual path)
__device__ __forceinline__ u32 pk2f(float a,float b){
  __hip_bfloat162 h = __float22bfloat162_rn(float2{a,b});
  return *reinterpret_cast<u32*>(&h);
}
__device__ __forceinline__ u32 umin32(u32 a,u32 b){ return a<b?a:b; }
__device__ __forceinline__ u32 umax32(u32 a,u32 b){ return a>b?a:b; }

__device__ __forceinline__ void async_copy16(const void* g, void* l){
  __builtin_amdgcn_global_load_lds((const __attribute__((address_space(1))) u32*)g,
                                   (__attribute__((address_space(3))) u32*)l, 16, 0, 0);
}

// ---------------- workspace layout (bytes) ----------------
#define OFF_IDX    0ull
#define OFF_FEATB  1048576ull
#define OFF_WPRE   3145728ull
#define OFF_WQKV   3178496ull
#define OFF_WA1    3571712ull
#define OFF_WA2    3702784ull
#define OFF_WP2    3833856ull
#define OFF_WPROJ  3964928ull
#define OFF_WPOST  4096000ull
#define OFF_MCOMB  4128768ull
#define OFF_INP    4259840ull
#define OFF_QKV    12648448ull
#define OFF_LNQKV  37814272ull
#define OFF_QA     62980096ull
#define OFF_KA     71368704ull
#define OFF_RES    79757312ull
#define OFF_D1     88145920ull     // also hosts wp1pk early (d1 written only after attn)
#define OFF_R1     96534528ull
#define WS_NEED    104923136ull
#define OFF_WP1PK  OFF_D1
#define OFF_WP2T   OFF_QKV         // wp2^T consumed by mcomb GEMM before qkv GEMM writes here

// ---------------- f32 -> bf16 conversions ----------------
__global__ void convert_k(const float* __restrict__ feat, const float* __restrict__ wpre,
    const float* __restrict__ wq, const float* __restrict__ wk, const float* __restrict__ wv,
    const float* __restrict__ wa1, const float* __restrict__ wa2, const float* __restrict__ wp2,
    const float* __restrict__ wproj, const float* __restrict__ wpost,
    u16* __restrict__ dfeat, u16* __restrict__ dwpre, u16* __restrict__ dwqkv,
    u16* __restrict__ dwa1, u16* __restrict__ dwa2, u16* __restrict__ dwp2,
    u16* __restrict__ dwproj, u16* __restrict__ dwpost){
  int id = blockIdx.x*256 + threadIdx.x;
  const float* s; u16* d; int off;
  if      (id < 1048576){ s=feat;  d=dfeat;        off=id; }
  else if (id < 1064960){ s=wpre;  d=dwpre;        off=id-1048576; }
  else if (id < 1130496){ s=wq;    d=dwqkv;        off=id-1064960; }
  else if (id < 1196032){ s=wk;    d=dwqkv+65536;  off=id-1130496; }
  else if (id < 1261568){ s=wv;    d=dwqkv+131072; off=id-1196032; }
  else if (id < 1327104){ s=wa1;   d=dwa1;         off=id-1261568; }
  else if (id < 1392640){ s=wa2;   d=dwa2;         off=id-1327104; }
  else if (id < 1458176){ s=wp2;   d=dwp2;         off=id-1392640; }
  else if (id < 1523712){ s=wproj; d=dwproj;       off=id-1458176; }
  else if (id < 1540096){ s=wpost; d=dwpost;       off=id-1523712; }
  else return;
  d[off] = f2b(s[off]);
}

// 256x256 bf16 transpose (for Mcomb GEMM's B operand)
__global__ void transpose_k(const u16* __restrict__ in, u16* __restrict__ out){
  __shared__ u16 t[32][33];
  const int tid = threadIdx.x, tx = tid & 31, ty = tid >> 5;   // 8 rows
  const int bx = blockIdx.x & 7, by = blockIdx.x >> 3;
  #pragma unroll
  for (int r = 0; r < 4; ++r) t[ty+8*r][tx] = in[(by*32+ty+8*r)*256 + bx*32+tx];
  __syncthreads();
  #pragma unroll
  for (int r = 0; r < 4; ++r) out[(bx*32+ty+8*r)*256 + by*32+tx] = t[tx][ty+8*r];
}

// Wp1 packed for MFMA A-operand: [256 h][32 k] bf16, k=0..2 = Wp1[h][*], rest 0
__global__ void wp1pack_k(const float* __restrict__ wp1, u16* __restrict__ out){
  const int h = threadIdx.x;
  const float w0 = wp1[h*3], w1 = wp1[h*3+1], w2 = wp1[h*3+2];
  uint4 a; a.x = pk2f(w0,w1); a.y = pk2f(w2,0.f); a.z = 0u; a.w = 0u;
  uint4 z; z.x = z.y = z.z = z.w = 0u;
  *(uint4*)&out[h*32]    = a;
  *(uint4*)&out[h*32+8]  = z;
  *(uint4*)&out[h*32+16] = z;
  *(uint4*)&out[h*32+24] = z;
}

// ---------------- kNN: exact top-16 by (d2, idx) ----------------
__device__ __forceinline__ void ins16(u32 (&a)[16], u32 key){
  #pragma unroll
  for (int j = 15; j >= 1; --j) a[j] = umin32(umax32(a[j-1],key), a[j]);
  a[0] = umin32(a[0], key);
}

__device__ __forceinline__ float dist2(float ax,float ay,float az,float bx,float by,float bz){
  const float dx = ax-bx, dy = ay-by, dz = az-bz;
  return __fmaf_rn(dx,dx, __fmaf_rn(dy,dy, dz*dz));   // identical sequence both phases
}

__global__ __launch_bounds__(256,2) void knn_kernel(const float* __restrict__ xyz,
                                                    int* __restrict__ idxout){
  __shared__ __attribute__((aligned(16))) float sbuf[3*4104];
  __shared__ int lcnt[32];
  __shared__ int tcnt[32];
  __shared__ u32 tbuf[32];
  __shared__ int tiebuf[32*16];
  float* sx = sbuf; float* sy = sbuf + 4104; float* sz = sbuf + 8208;
  const int tid = threadIdx.x;
  const int b  = blockIdx.x >> 7;
  const int n0 = (blockIdx.x & 127) << 5;
  const float* base = xyz + (size_t)b*12288;
  #pragma unroll
  for (int i = 0; i < 12; ++i){
    const float4 v = *(const float4*)(base + tid*48 + i*4);
    const float vv[4] = {v.x, v.y, v.z, v.w};
    #pragma unroll
    for (int j = 0; j < 4; ++j){
      const int e = i*4 + j;
      const int c = e % 3;
      const int m = tid*16 + e/3;
      float* arr = (c==0)?sx:((c==1)?sy:sz);
      arr[m + (m>>9)] = vv[j];
    }
  }
  if (tid < 32){ lcnt[tid] = 0; tcnt[tid] = 0; }
  __syncthreads();
  const int qi = tid >> 3, p = tid & 7;
  const int n = n0 + qi;
  const int sn = n + (n>>9);
  const float qx = sx[sn], qy = sy[sn], qz = sz[sn];
  u32 a[16];
  #pragma unroll
  for (int j = 0; j < 16; ++j) a[j] = 0xFFFFFFFFu;
  const int sb = p*513;
  #pragma unroll 2
  for (int i = 0; i < 512; ++i){
    const float d2 = dist2(sx[sb+i],sy[sb+i],sz[sb+i],qx,qy,qz);
    ins16(a, __float_as_uint(d2));
  }
  #pragma unroll
  for (int s = 4; s >= 1; s >>= 1){
    u32 o[16];
    #pragma unroll
    for (int j = 0; j < 16; ++j) o[j] = __shfl_down(a[j], (unsigned)s, 64);
    if (p < s){
      #pragma unroll
      for (int j = 0; j < 16; ++j) ins16(a, o[j]);
    }
  }
  if (p == 0) tbuf[qi] = a[15];
  __syncthreads();
  const u32 T = tbuf[qi];
  int* orow = idxout + ((size_t)(b<<12)+n)*16;
  const int gbase = p*512;
  for (int i = 0; i < 512; ++i){
    const float d2 = dist2(sx[sb+i],sy[sb+i],sz[sb+i],qx,qy,qz);
    const u32 kb = __float_as_uint(d2);
    if (kb < T){
      const int pos = atomicAdd(&lcnt[qi],1);
      if (pos < 16) orow[pos] = gbase + i;
    } else if (kb == T){
      const int t = atomicAdd(&tcnt[qi],1);
      if (t < 16) tiebuf[qi*16+t] = gbase + i;
    }
  }
  __syncthreads();
  if (p == 0){
    int L = lcnt[qi]; if (L > 16) L = 16;
    int tc = tcnt[qi]; if (tc > 16) tc = 16;
    const int need = 16 - L;
    for (int r = 0; r < need; ++r){
      int best = 0x7FFFFFFF, bj = -1;
      for (int j = 0; j < tc; ++j){
        const int v = tiebuf[qi*16+j];
        if (v < best){ best = v; bj = j; }
      }
      if (bj >= 0){ tiebuf[qi*16+bj] = 0x7FFFFFFF; orow[L+r] = best; }
      else orow[L+r] = n;
    }
  }
}

// ---------------- generic 128x128 bf16 GEMM: C[m][n] = sum_k A[m][k]*B[n][k] (+bias) ----------------
__global__ __launch_bounds__(256,2) void gemm128_k(
    const u16* __restrict__ A, const int lda,
    const u16* __restrict__ Bw, const int ldb,
    u16* __restrict__ C, const int ldc,
    const int K, const float* __restrict__ bias){
  __shared__ __attribute__((aligned(16))) u16 As[128*32];
  __shared__ __attribute__((aligned(16))) u16 Bs[128*32];
  const int tid = threadIdx.x, lane = tid & 63, w = tid >> 6;
  const int mrow = lane & 15, quad = lane >> 4;
  const size_t mbase = (size_t)blockIdx.x*128, nbase = (size_t)blockIdx.y*128;
  const int wr = (w&1)*64, wc = (w>>1)*64;
  f32x4 acc[4][4];
  #pragma unroll
  for (int i=0;i<4;++i)
    #pragma unroll
    for (int j=0;j<4;++j)
      #pragma unroll
      for (int r=0;r<4;++r) acc[i][j][r] = 0.f;
  const int sr = tid >> 2, sk = (tid & 3)*8;
  u16* lA0 = &As[w*512]; u16* lA1 = &As[2048 + w*512];
  u16* lB0 = &Bs[w*512]; u16* lB1 = &Bs[2048 + w*512];
  for (int k0 = 0; k0 < K; k0 += 32){
    __syncthreads();
    async_copy16(A  + (mbase      + sr)*(size_t)lda + k0 + sk, lA0);
    async_copy16(A  + (mbase + 64 + sr)*(size_t)lda + k0 + sk, lA1);
    async_copy16(Bw + (nbase      + sr)*(size_t)ldb + k0 + sk, lB0);
    async_copy16(Bw + (nbase + 64 + sr)*(size_t)ldb + k0 + sk, lB1);
    __syncthreads();
    bf16x8 af[4], bf[4];
    #pragma unroll
    for (int rt=0;rt<4;++rt) af[rt] = *(const bf16x8*)&As[(wr+rt*16+mrow)*32 + quad*8];
    #pragma unroll
    for (int ct=0;ct<4;++ct) bf[ct] = *(const bf16x8*)&Bs[(wc+ct*16+mrow)*32 + quad*8];
    #pragma unroll
    for (int rt=0;rt<4;++rt)
      #pragma unroll
      for (int ct=0;ct<4;++ct) acc[rt][ct] = MFMA16(af[rt], bf[ct], acc[rt][ct]);
  }
  #pragma unroll
  for (int rt=0;rt<4;++rt)
    #pragma unroll
    for (int ct=0;ct<4;++ct){
      const size_t row0 = mbase + wr + rt*16 + quad*4;
      const int col = (int)nbase + wc + ct*16 + mrow;
      const float bv = bias ? bias[col] : 0.f;
      #pragma unroll
      for (int r=0;r<4;++r) C[(row0+r)*(size_t)ldc + col] = f2b(acc[rt][ct][r] + bv);
    }
}

// ---------------- LayerNorm over 256-element groups, bf16 in/out ----------------
__global__ __launch_bounds__(256,2) void ln256_k(const u16* __restrict__ in, u16* __restrict__ out,
    const float* __restrict__ g, const float* __restrict__ bta){
  const int tid = threadIdx.x, lane = tid & 63, w = tid >> 6;
  const size_t row = (size_t)blockIdx.x*4 + w;
  const uint2 u = *(const uint2*)(in + row*256 + lane*4);
  const float x0=b2f(u.x&0xffff), x1=b2f(u.x>>16), x2=b2f(u.y&0xffff), x3=b2f(u.y>>16);
  float s  = x0+x1+x2+x3;
  float ss = x0*x0+x1*x1+x2*x2+x3*x3;
  #pragma unroll
  for (int mk=1; mk<64; mk<<=1){ s += __shfl_xor(s,mk,64); ss += __shfl_xor(ss,mk,64); }
  const float mu = s*(1.f/256.f);
  const float var = ss*(1.f/256.f) - mu*mu;
  const float rs = rsqrtf(var + 1e-5f);
  const int c = lane*4;
  const float y0=(x0-mu)*rs*g[c  ]+bta[c  ];
  const float y1=(x1-mu)*rs*g[c+1]+bta[c+1];
  const float y2=(x2-mu)*rs*g[c+2]+bta[c+2];
  const float y3=(x3-mu)*rs*g[c+3]+bta[c+3];
  uint2 o; o.x = pk2f(y0,y1); o.y = pk2f(y2,y3);
  *(uint2*)(out + row*256 + lane*4) = o;
}

// ---------------- fused per-neighbor attention kernel (v9 = v8 + HW packed bf16 converts) ----------------
// block = 64 rows (4 queries x 16), 512 threads = 8 waves, wave w owns f-slice [w*32,w*32+32), all 64 m.
// __launch_bounds__(512,4): 128-reg budget; av parked in LDS across G2; 2 blocks/CU -> 16 waves/CU.
#define DP   264
#define RELP 40
__global__ __launch_bounds__(512,4) void attn_k(
    const float* __restrict__ xyz, const int* __restrict__ idxb,
    const u16* __restrict__ lnqkv, const u16* __restrict__ qa, const u16* __restrict__ ka,
    const u16* __restrict__ mcomb, const u16* __restrict__ wp2, const u16* __restrict__ wa2,
    const u16* __restrict__ wp1pk, u16* __restrict__ res){
  __shared__ __attribute__((aligned(16))) u16 hbuf[64*DP];    // h1, then h2 (33.8 KB)
  __shared__ __attribute__((aligned(16))) u16 avbuf[64*DP];   // av parked across G2 (33.8 KB)
  __shared__ __attribute__((aligned(16))) u16 srel[64*RELP];  // rel bf16, k-padded to 32
  __shared__ int sidx[64];
  const int tid = threadIdx.x;
  const int b = blockIdx.x >> 10;                // 1024 blocks per batch
  const int nbase = (blockIdx.x & 1023) << 2;    // 4 queries
  const size_t gb = (size_t)b << 12;
  // ---- stage neighbor idx + rel
  if (tid < 64){
    const int m = tid;
    const int im = idxb[(gb + nbase + (m>>4))*16 + (m&15)] & 4095;
    sidx[m] = im;
    const int nn = nbase + (m>>4);
    const float* pq = xyz + (gb+nn)*3;
    const float* pm = xyz + (gb+im)*3;
    const float rx = pq[0]-pm[0], ry = pq[1]-pm[1], rz = pq[2]-pm[2];
    uint4 a; a.x = pk2f(rx,ry); a.y = pk2f(rz,0.f); a.z = 0u; a.w = 0u;
    uint4 z; z.x = z.y = z.z = z.w = 0u;
    *(uint4*)&srel[m*RELP]    = a;
    *(uint4*)&srel[m*RELP+8]  = z;
    *(uint4*)&srel[m*RELP+16] = z;
    *(uint4*)&srel[m*RELP+24] = z;
  }
  __syncthreads();
  const int lane = tid & 63, w = tid >> 6;
  const int mrow = lane & 15, quad = lane >> 4;
  const int fr = w << 5;                         // 32-wide f/h slice of this wave
  // ---- h1 via MFMA: D[h][m] for h in [fr,fr+32), m in [0,64)
  {
    bf16x8 aW[2], bR[4];
    #pragma unroll
    for (int ht=0;ht<2;++ht) aW[ht] = *(const bf16x8*)&wp1pk[(fr+ht*16+mrow)*32 + quad*8];
    #pragma unroll
    for (int mt=0;mt<4;++mt) bR[mt] = *(const bf16x8*)&srel[(mt*16+mrow)*RELP + quad*8];
    #pragma unroll
    for (int ht=0;ht<2;++ht)
      #pragma unroll
      for (int mt=0;mt<4;++mt){
        f32x4 hz;
        #pragma unroll
        for (int r=0;r<4;++r) hz[r]=0.f;
        hz = MFMA16(aW[ht], bR[mt], hz);
        float h0 = hz[0]>0.f?hz[0]:0.f, h1v = hz[1]>0.f?hz[1]:0.f;
        float h2v = hz[2]>0.f?hz[2]:0.f, h3 = hz[3]>0.f?hz[3]:0.f;
        uint2 o; o.x = pk2f(h0,h1v); o.y = pk2f(h2v,h3);
        *(uint2*)&hbuf[(mt*16+mrow)*DP + fr + ht*16 + quad*4] = o;
      }
  }
  int midx[4];
  #pragma unroll
  for (int mt = 0; mt < 4; ++mt) midx[mt] = sidx[mt*16 + mrow];
  __syncthreads();             // h1 complete
  // ---- G1: t.T and val.T
  f32x4 at[2][4], av[2][4];
  #pragma unroll
  for (int i=0;i<2;++i)
    #pragma unroll
    for (int j=0;j<4;++j)
      #pragma unroll
      for (int r=0;r<4;++r){ at[i][j][r]=0.f; av[i][j][r]=0.f; }
  #pragma unroll 1
  for (int ks = 0; ks < 8; ++ks){
    const int koff = ks*32 + quad*8;
    bf16x8 aM[2], aP[2], bH[4];
    #pragma unroll
    for (int ft=0;ft<2;++ft){
      aM[ft] = *(const bf16x8*)&mcomb[(fr+ft*16+mrow)*256 + koff];
      aP[ft] = *(const bf16x8*)&wp2  [(fr+ft*16+mrow)*256 + koff];
    }
    #pragma unroll
    for (int mt=0;mt<4;++mt) bH[mt] = *(const bf16x8*)&hbuf[(mt*16+mrow)*DP + koff];
    #pragma unroll
    for (int ft=0;ft<2;++ft)
      #pragma unroll
      for (int mt=0;mt<4;++mt){
        at[ft][mt] = MFMA16(aM[ft], bH[mt], at[ft][mt]);
        av[ft][mt] = MFMA16(aP[ft], bH[mt], av[ft][mt]);
      }
  }
  // ---- qkp gather AFTER G1 (barrier wait below hides the latency; keeps G1 live-set small)
  uint2 qkp[2][4];
  #pragma unroll
  for (int ft = 0; ft < 2; ++ft)
    #pragma unroll
    for (int mt = 0; mt < 4; ++mt){
      const int f = fr + ft*16 + quad*4;
      const uint2 uq = *(const uint2*)&qa[(gb + nbase + mt)*256 + f];
      const uint2 uk = *(const uint2*)&ka[(gb + (size_t)midx[mt])*256 + f];
      uint2 o;
      o.x = pk2f(b2f(uq.x&0xffff)-b2f(uk.x&0xffff), b2f(uq.x>>16)-b2f(uk.x>>16));
      o.y = pk2f(b2f(uq.y&0xffff)-b2f(uk.y&0xffff), b2f(uq.y>>16)-b2f(uk.y>>16));
      qkp[ft][mt] = o;
    }
  __syncthreads();             // all waves done reading h1
  // ---- epilogue: h2 = relu(t + (qa-ka)) -> hbuf ; av -> avbuf (bf16), regs freed
  #pragma unroll
  for (int ft=0;ft<2;++ft)
    #pragma unroll
    for (int mt=0;mt<4;++mt){
      const int moff = (mt*16+mrow)*DP + fr + ft*16 + quad*4;
      const uint2 qv = qkp[ft][mt];
      float t0 = at[ft][mt][0] + b2f(qv.x&0xffff);
      float t1 = at[ft][mt][1] + b2f(qv.x>>16);
      float t2 = at[ft][mt][2] + b2f(qv.y&0xffff);
      float t3 = at[ft][mt][3] + b2f(qv.y>>16);
      t0 = t0>0.f?t0:0.f; t1 = t1>0.f?t1:0.f; t2 = t2>0.f?t2:0.f; t3 = t3>0.f?t3:0.f;
      uint2 o; o.x = pk2f(t0,t1); o.y = pk2f(t2,t3);
      *(uint2*)&hbuf[moff] = o;
      uint2 va; va.x = pk2f(av[ft][mt][0],av[ft][mt][1]); va.y = pk2f(av[ft][mt][2],av[ft][mt][3]);
      *(uint2*)&avbuf[moff] = va;
    }
  // ---- v gather prefetch (av/at regs dead; consumed after G2; barrier hides latency)
  uint2 vpre[2][4];
  #pragma unroll
  for (int ft=0;ft<2;++ft)
    #pragma unroll
    for (int mt=0;mt<4;++mt)
      vpre[ft][mt] = *(const uint2*)&lnqkv[(gb + (size_t)midx[mt])*768 + 512 + fr + ft*16 + quad*4];
  __syncthreads();
  // ---- G2: logits.T = Wa2 @ h2.T
  f32x4 al[2][4];
  #pragma unroll
  for (int i=0;i<2;++i)
    #pragma unroll
    for (int j=0;j<4;++j)
      #pragma unroll
      for (int r=0;r<4;++r) al[i][j][r]=0.f;
  #pragma unroll 1
  for (int ks = 0; ks < 8; ++ks){
    const int koff = ks*32 + quad*8;
    bf16x8 aW[2], bH[4];
    #pragma unroll
    for (int gt=0;gt<2;++gt) aW[gt] = *(const bf16x8*)&wa2[(fr+gt*16+mrow)*256 + koff];
    #pragma unroll
    for (int mt=0;mt<4;++mt) bH[mt] = *(const bf16x8*)&hbuf[(mt*16+mrow)*DP + koff];
    #pragma unroll
    for (int gt=0;gt<2;++gt)
      #pragma unroll
      for (int mt=0;mt<4;++mt) al[gt][mt] = MFMA16(aW[gt], bH[mt], al[gt][mt]);
  }
  // ---- softmax over 16 neighbors (= lane&15) + weighted reduce (av reloaded from LDS)
  const float sc = 0.0901684f;   // log2(e)/sqrt(256)
  #pragma unroll
  for (int gt=0;gt<2;++gt)
    #pragma unroll
    for (int mt=0;mt<4;++mt){
      const uint2 va = *(const uint2*)&avbuf[(mt*16+mrow)*DP + fr + gt*16 + quad*4];
      float avv[4];
      avv[0] = b2f(va.x&0xffff); avv[1] = b2f(va.x>>16);
      avv[2] = b2f(va.y&0xffff); avv[3] = b2f(va.y>>16);
      float rv[4];
      #pragma unroll
      for (int r=0;r<4;++r){
        u32 hv;
        if      (r==0) hv = vpre[gt][mt].x & 0xffff;
        else if (r==1) hv = vpre[gt][mt].x >> 16;
        else if (r==2) hv = vpre[gt][mt].y & 0xffff;
        else           hv = vpre[gt][mt].y >> 16;
        const float val = avv[r] + b2f(hv);
        float pr = exp2f(al[gt][mt][r]*sc);   // logits are O(1); no max-sub needed
        float wg = pr*val;
        #pragma unroll
        for (int mk=1; mk<16; mk<<=1){ pr += __shfl_xor(pr,mk,64); wg += __shfl_xor(wg,mk,64); }
        rv[r] = wg * __builtin_amdgcn_rcpf(pr);
      }
      if (mrow == 0){
        uint2 o; o.x = pk2f(rv[0],rv[1]); o.y = pk2f(rv[2],rv[3]);
        *(uint2*)&res[(gb + nbase + mt)*256 + fr + gt*16 + quad*4] = o;
      }
    }
}

// ---------------- final: out = ln(r1 @ W_post.T + b_post)*g+b + features ----------------
__global__ __launch_bounds__(256,2) void d2_k(
    const u16* __restrict__ r1, const u16* __restrict__ wpost,
    const float* __restrict__ bpost, const float* __restrict__ g, const float* __restrict__ bt,
    const float* __restrict__ feat, float* __restrict__ out){
  const int tid = threadIdx.x, lane = tid & 63, w = tid >> 6;
  const int mrow = lane & 15, quad = lane >> 4;
  const size_t rb = (size_t)blockIdx.x*128 + w*32;
  f32x4 acc[2][4];
  #pragma unroll
  for (int i=0;i<2;++i)
    #pragma unroll
    for (int j=0;j<4;++j)
      #pragma unroll
      for (int r=0;r<4;++r) acc[i][j][r]=0.f;
  #pragma unroll 1
  for (int ks = 0; ks < 8; ++ks){
    const int koff = ks*32 + quad*8;
    bf16x8 af[2], bf[4];
    #pragma unroll
    for (int rt=0;rt<2;++rt) af[rt] = *(const bf16x8*)&r1[(rb+rt*16+mrow)*256 + koff];
    #pragma unroll
    for (int ct=0;ct<4;++ct) bf[ct] = *(const bf16x8*)&wpost[(ct*16+mrow)*256 + koff];
    #pragma unroll
    for (int rt=0;rt<2;++rt)
      #pragma unroll
      for (int ct=0;ct<4;++ct) acc[rt][ct] = MFMA16(af[rt], bf[ct], acc[rt][ct]);
  }
  #pragma unroll
  for (int ct=0;ct<4;++ct){
    const float bv = bpost[ct*16+mrow];
    #pragma unroll
    for (int rt=0;rt<2;++rt)
      #pragma unroll
      for (int r=0;r<4;++r) acc[rt][ct][r] += bv;
  }
  #pragma unroll
  for (int rt=0;rt<2;++rt)
    #pragma unroll
    for (int r=0;r<4;++r){
      float s  = acc[rt][0][r]+acc[rt][1][r]+acc[rt][2][r]+acc[rt][3][r];
      float ss = acc[rt][0][r]*acc[rt][0][r]+acc[rt][1][r]*acc[rt][1][r]
               + acc[rt][2][r]*acc[rt][2][r]+acc[rt][3][r]*acc[rt][3][r];
      #pragma unroll
      for (int mk=1; mk<16; mk<<=1){ s += __shfl_xor(s,mk,64); ss += __shfl_xor(ss,mk,64); }
      const float mu = s*(1.f/64.f);
      const float var = ss*(1.f/64.f) - mu*mu;
      const float rs = rsqrtf(var + 1e-5f);
      const size_t row = rb + rt*16 + quad*4 + r;
      #pragma unroll
      for (int ct=0;ct<4;++ct){
        const int n = ct*16 + mrow;
        out[row*64 + n] = (acc[rt][ct][r]-mu)*rs*g[n] + bt[n] + feat[row*64 + n];
      }
    }
}

// ---------------- launcher ----------------
extern "C" void kernel_launch(void* const* d_in, const int* in_sizes, int n_in,
                              void* d_out, int out_size, void* d_ws, size_t ws_size,
                              hipStream_t stream){
  const float* xyz    = (const float*)d_in[0];
  const float* feat   = (const float*)d_in[1];
  const float* W_pre  = (const float*)d_in[2];
  const float* b_pre  = (const float*)d_in[3];
  const float* W_post = (const float*)d_in[4];
  const float* b_post = (const float*)d_in[5];
  const float* Wp1    = (const float*)d_in[6];
  const float* Wp2    = (const float*)d_in[7];
  const float* Wa1    = (const float*)d_in[8];
  const float* Wa2    = (const float*)d_in[9];
  const float* WQ     = (const float*)d_in[10];
  const float* WK     = (const float*)d_in[11];
  const float* WV     = (const float*)d_in[12];
  const float* Wproj  = (const float*)d_in[13];
  const float* g_dm   = (const float*)d_in[14];
  const float* b_dm   = (const float*)d_in[15];
  const float* g_dp   = (const float*)d_in[16];
  const float* b_dp   = (const float*)d_in[17];
  float* out = (float*)d_out;
  if (ws_size < WS_NEED) return;
  char* ws = (char*)d_ws;
  int* idxw   = (int*)(ws + OFF_IDX);
  u16* featb  = (u16*)(ws + OFF_FEATB);
  u16* wpreb  = (u16*)(ws + OFF_WPRE);
  u16* wqkvb  = (u16*)(ws + OFF_WQKV);
  u16* wa1b   = (u16*)(ws + OFF_WA1);
  u16* wa2b   = (u16*)(ws + OFF_WA2);
  u16* wp2b   = (u16*)(ws + OFF_WP2);
  u16* wprojb = (u16*)(ws + OFF_WPROJ);
  u16* wpostb = (u16*)(ws + OFF_WPOST);
  u16* mcombb = (u16*)(ws + OFF_MCOMB);
  u16* inp    = (u16*)(ws + OFF_INP);
  u16* qkv    = (u16*)(ws + OFF_QKV);
  u16* lnqkv  = (u16*)(ws + OFF_LNQKV);
  u16* qab    = (u16*)(ws + OFF_QA);
  u16* kab    = (u16*)(ws + OFF_KA);
  u16* resb   = (u16*)(ws + OFF_RES);
  u16* d1raw  = (u16*)(ws + OFF_D1);
  u16* r1b    = (u16*)(ws + OFF_R1);
  u16* wp1pk  = (u16*)(ws + OFF_WP1PK);   // aliases d1raw: read by attn_k before d1 GEMM writes
  u16* wp2T   = (u16*)(ws + OFF_WP2T);    // aliases qkv: consumed before qkv GEMM writes

  convert_k<<<6016,256,0,stream>>>(feat,W_pre,WQ,WK,WV,Wa1,Wa2,Wp2,Wproj,W_post,
                                   featb,wpreb,wqkvb,wa1b,wa2b,wp2b,wprojb,wpostb);
  transpose_k<<<64,256,0,stream>>>(wp2b, wp2T);
  // Mcomb = Wa1 @ Wp2 : C[f][h] = sum_k wa1[f][k] * wp2T[h][k]
  gemm128_k<<<dim3(2,2),256,0,stream>>>(wa1b,256, wp2T,256, mcombb,256, 256, nullptr);
  wp1pack_k<<<1,256,0,stream>>>(Wp1,wp1pk);
  knn_kernel<<<512,256,0,stream>>>(xyz,idxw);
  // inp = features @ W_pre.T + b_pre
  gemm128_k<<<dim3(128,2),256,0,stream>>>(featb,64,  wpreb,64,  inp,256, 64,  b_pre);
  // qkv = inp @ [WQ|WK|WV].T
  gemm128_k<<<dim3(128,6),256,0,stream>>>(inp,256,   wqkvb,256, qkv,768, 256, nullptr);
  ln256_k<<<12288,256,0,stream>>>(qkv,lnqkv,g_dm,b_dm);
  // qa = ln(q) @ Wa1.T ; ka = ln(k) @ Wa1.T
  gemm128_k<<<dim3(128,2),256,0,stream>>>(lnqkv,768,     wa1b,256, qab,256, 256, nullptr);
  gemm128_k<<<dim3(128,2),256,0,stream>>>(lnqkv+256,768, wa1b,256, kab,256, 256, nullptr);
  attn_k<<<4096,512,0,stream>>>(xyz,idxw,lnqkv,qab,kab,mcombb,wp2b,wa2b,wp1pk,resb);
  // d1 = res @ Wproj.T ; r1 = ln(d1)
  gemm128_k<<<dim3(128,2),256,0,stream>>>(resb,256, wprojb,256, d1raw,256, 256, nullptr);
  ln256_k<<<4096,256,0,stream>>>(d1raw,r1b,g_dm,b_dm);
  d2_k<<<128,256,0,stream>>>(r1b,wpostb,b_post,g_dp,b_dp,feat,out);
}

// Round 10
// 561.742 us; speedup vs baseline: 1.4875x; 1.0490x over previous
//
#include <hip/hip_runtime.h>
#include <hip/hip_bf16.h>

typedef unsigned short u16;
typedef unsigned int   u32;
typedef __attribute__((ext_vector_type(8))) short bf16x8;
typedef __attribute__((ext_vector_type(4))) float f32x4;

#define MFMA16(a,b,c) __builtin_amdgcn_mfma_f32_16x16x32_bf16((a),(b),(c),0,0,0)

__device__ __forceinline__ float b2f(u32 h){ return __uint_as_float(h<<16); }
__device__ __forceinline__ u16 f2b(float f){
  u32 u = __float_as_uint(f);
  return (u16)((u + 0x7FFFu + ((u>>16)&1u))>>16);
}
// HW packed convert: v_cvt_pk_bf16_f32 (RNE)
__device__ __forceinline__ u32 pk2f(float a,float b){
  __hip_bfloat162 h = __float22bfloat162_rn(float2{a,b});
  return *reinterpret_cast<u32*>(&h);
}
__device__ __forceinline__ u32 umin32(u32 a,u32 b){ return a<b?a:b; }
__device__ __forceinline__ u32 umax32(u32 a,u32 b){ return a>b?a:b; }

// 16-lane row-sum on the VALU pipe via DPP row_ror (keeps LDS pipe free for MFMA operands)
template<int CTRL>
__device__ __forceinline__ float dpp_add(float x){
  int t = __builtin_amdgcn_update_dpp(0, __float_as_int(x), CTRL, 0xF, 0xF, true);
  return x + __int_as_float(t);
}
__device__ __forceinline__ float rowsum16(float x){
  x = dpp_add<0x121>(x);   // row_ror:1
  x = dpp_add<0x122>(x);   // row_ror:2
  x = dpp_add<0x124>(x);   // row_ror:4
  x = dpp_add<0x128>(x);   // row_ror:8
  return x;
}

__device__ __forceinline__ void async_copy16(const void* g, void* l){
  __builtin_amdgcn_global_load_lds((const __attribute__((address_space(1))) u32*)g,
                                   (__attribute__((address_space(3))) u32*)l, 16, 0, 0);
}

// ---------------- workspace layout (bytes) ----------------
#define OFF_IDX    0ull
#define OFF_FEATB  1048576ull
#define OFF_WPRE   3145728ull
#define OFF_WQKV   3178496ull
#define OFF_WA1    3571712ull
#define OFF_WA2    3702784ull
#define OFF_WP2    3833856ull
#define OFF_WPROJ  3964928ull
#define OFF_WPOST  4096000ull
#define OFF_MCOMB  4128768ull
#define OFF_INP    4259840ull
#define OFF_QKV    12648448ull
#define OFF_LNQKV  37814272ull
#define OFF_QA     62980096ull
#define OFF_KA     71368704ull
#define OFF_RES    79757312ull
#define OFF_D1     88145920ull     // also hosts wp1pk early (d1 written only after attn)
#define OFF_R1     96534528ull
#define WS_NEED    104923136ull
#define OFF_WP1PK  OFF_D1
#define OFF_WP2T   OFF_QKV         // wp2^T consumed by mcomb GEMM before qkv GEMM writes here

// ---------------- f32 -> bf16 conversions + wp1 pack + wp2 transpose (fused) ----------------
__global__ void convert_k(const float* __restrict__ feat, const float* __restrict__ wpre,
    const float* __restrict__ wq, const float* __restrict__ wk, const float* __restrict__ wv,
    const float* __restrict__ wa1, const float* __restrict__ wa2, const float* __restrict__ wp2,
    const float* __restrict__ wproj, const float* __restrict__ wpost,
    const float* __restrict__ wp1,
    u16* __restrict__ dfeat, u16* __restrict__ dwpre, u16* __restrict__ dwqkv,
    u16* __restrict__ dwa1, u16* __restrict__ dwa2, u16* __restrict__ dwp2,
    u16* __restrict__ dwproj, u16* __restrict__ dwpost,
    u16* __restrict__ dwp1pk, u16* __restrict__ dwp2T){
  __shared__ u16 t[32][33];
  const int bid = blockIdx.x, tid = threadIdx.x;
  if (bid < 6016){
    int id = bid*256 + tid;
    const float* s; u16* d; int off;
    if      (id < 1048576){ s=feat;  d=dfeat;        off=id; }
    else if (id < 1064960){ s=wpre;  d=dwpre;        off=id-1048576; }
    else if (id < 1130496){ s=wq;    d=dwqkv;        off=id-1064960; }
    else if (id < 1196032){ s=wk;    d=dwqkv+65536;  off=id-1130496; }
    else if (id < 1261568){ s=wv;    d=dwqkv+131072; off=id-1196032; }
    else if (id < 1327104){ s=wa1;   d=dwa1;         off=id-1261568; }
    else if (id < 1392640){ s=wa2;   d=dwa2;         off=id-1327104; }
    else if (id < 1458176){ s=wp2;   d=dwp2;         off=id-1392640; }
    else if (id < 1523712){ s=wproj; d=dwproj;       off=id-1458176; }
    else if (id < 1540096){ s=wpost; d=dwpost;       off=id-1523712; }
    else return;
    d[off] = f2b(s[off]);
  } else if (bid == 6016){
    // Wp1 packed for MFMA A-operand: [256 h][32 k], k=0..2 = Wp1[h][*], rest 0
    const int h = tid;
    const float w0 = wp1[h*3], w1 = wp1[h*3+1], w2 = wp1[h*3+2];
    uint4 a; a.x = pk2f(w0,w1); a.y = pk2f(w2,0.f); a.z = 0u; a.w = 0u;
    uint4 z; z.x = z.y = z.z = z.w = 0u;
    *(uint4*)&dwp1pk[h*32]    = a;
    *(uint4*)&dwp1pk[h*32+8]  = z;
    *(uint4*)&dwp1pk[h*32+16] = z;
    *(uint4*)&dwp1pk[h*32+24] = z;
  } else {
    // 256x256 transpose straight from f32 Wp2 -> bf16 wp2T
    const int tb = bid - 6017;
    const int bx = tb & 7, by = tb >> 3;
    const int tx = tid & 31, ty = tid >> 5;   // 8 rows
    #pragma unroll
    for (int r = 0; r < 4; ++r) t[ty+8*r][tx] = f2b(wp2[(by*32+ty+8*r)*256 + bx*32+tx]);
    __syncthreads();
    #pragma unroll
    for (int r = 0; r < 4; ++r) dwp2T[(bx*32+ty+8*r)*256 + by*32+tx] = t[tx][ty+8*r];
  }
}

// ---------------- kNN: exact top-16 by (d2, idx) ----------------
// v2: 1024 blocks x 16 queries (16 partials x 256 candidates) -> 3 blocks/CU resident
__device__ __forceinline__ void ins16(u32 (&a)[16], u32 key){
  #pragma unroll
  for (int j = 15; j >= 1; --j) a[j] = umin32(umax32(a[j-1],key), a[j]);
  a[0] = umin32(a[0], key);
}

__device__ __forceinline__ float dist2(float ax,float ay,float az,float bx,float by,float bz){
  const float dx = ax-bx, dy = ay-by, dz = az-bz;
  return __fmaf_rn(dx,dx, __fmaf_rn(dy,dy, dz*dz));   // identical sequence both phases
}

__global__ __launch_bounds__(256,3) void knn_kernel(const float* __restrict__ xyz,
                                                    int* __restrict__ idxout){
  __shared__ __attribute__((aligned(16))) float sbuf[3*4104];
  __shared__ int lcnt[16];
  __shared__ int tcnt[16];
  __shared__ u32 tbuf[16];
  __shared__ int tiebuf[16*16];
  float* sx = sbuf; float* sy = sbuf + 4104; float* sz = sbuf + 8208;
  const int tid = threadIdx.x;
  const int b  = blockIdx.x >> 8;
  const int n0 = (blockIdx.x & 255) << 4;
  const float* base = xyz + (size_t)b*12288;
  #pragma unroll
  for (int i = 0; i < 12; ++i){
    const float4 v = *(const float4*)(base + tid*48 + i*4);
    const float vv[4] = {v.x, v.y, v.z, v.w};
    #pragma unroll
    for (int j = 0; j < 4; ++j){
      const int e = i*4 + j;
      const int c = e % 3;
      const int m = tid*16 + e/3;
      float* arr = (c==0)?sx:((c==1)?sy:sz);
      arr[m + (m>>9)] = vv[j];
    }
  }
  if (tid < 16){ lcnt[tid] = 0; tcnt[tid] = 0; }
  __syncthreads();
  const int qi = tid >> 4, p = tid & 15;
  const int n = n0 + qi;
  const int sn = n + (n>>9);
  const float qx = sx[sn], qy = sy[sn], qz = sz[sn];
  u32 a[16];
  #pragma unroll
  for (int j = 0; j < 16; ++j) a[j] = 0xFFFFFFFFu;
  const int sb = p*256 + (p>>1);     // swizzled base; 256-chunk never crosses a 512 boundary
  #pragma unroll 2
  for (int i = 0; i < 256; ++i){
    const float d2 = dist2(sx[sb+i],sy[sb+i],sz[sb+i],qx,qy,qz);
    ins16(a, __float_as_uint(d2));
  }
  // shfl tree merge of the 16 partials (answer lands at p==0); p+s<16 stays in-query
  #pragma unroll
  for (int s = 8; s >= 1; s >>= 1){
    u32 o[16];
    #pragma unroll
    for (int j = 0; j < 16; ++j) o[j] = __shfl_down(a[j], (unsigned)s, 64);
    if (p < s){
      #pragma unroll
      for (int j = 0; j < 16; ++j) ins16(a, o[j]);
    }
  }
  if (p == 0) tbuf[qi] = a[15];
  __syncthreads();
  const u32 T = tbuf[qi];
  int* orow = idxout + ((size_t)(b<<12)+n)*16;
  const int gbase = p*256;
  for (int i = 0; i < 256; ++i){
    const float d2 = dist2(sx[sb+i],sy[sb+i],sz[sb+i],qx,qy,qz);
    const u32 kb = __float_as_uint(d2);
    if (kb < T){
      const int pos = atomicAdd(&lcnt[qi],1);
      if (pos < 16) orow[pos] = gbase + i;
    } else if (kb == T){
      const int t = atomicAdd(&tcnt[qi],1);
      if (t < 16) tiebuf[qi*16+t] = gbase + i;
    }
  }
  __syncthreads();
  if (p == 0){
    int L = lcnt[qi]; if (L > 16) L = 16;
    int tc = tcnt[qi]; if (tc > 16) tc = 16;
    const int need = 16 - L;
    for (int r = 0; r < need; ++r){
      int best = 0x7FFFFFFF, bj = -1;
      for (int j = 0; j < tc; ++j){
        const int v = tiebuf[qi*16+j];
        if (v < best){ best = v; bj = j; }
      }
      if (bj >= 0){ tiebuf[qi*16+bj] = 0x7FFFFFFF; orow[L+r] = best; }
      else orow[L+r] = n;
    }
  }
}

// ---------------- generic 128x128 bf16 GEMM: C[m][n] = sum_k A[m][k]*B[n][k] (+bias) ----------------
// zA/zC: element offsets applied per blockIdx.z (lets qa/ka share one launch)
__global__ __launch_bounds__(256,2) void gemm128_k(
    const u16* __restrict__ A, const int lda,
    const u16* __restrict__ Bw, const int ldb,
    u16* __restrict__ C, const int ldc,
    const int K, const float* __restrict__ bias,
    const size_t zA, const size_t zC){
  __shared__ __attribute__((aligned(16))) u16 As[128*32];
  __shared__ __attribute__((aligned(16))) u16 Bs[128*32];
  A += blockIdx.z * zA;
  C += blockIdx.z * zC;
  const int tid = threadIdx.x, lane = tid & 63, w = tid >> 6;
  const int mrow = lane & 15, quad = lane >> 4;
  const size_t mbase = (size_t)blockIdx.x*128, nbase = (size_t)blockIdx.y*128;
  const int wr = (w&1)*64, wc = (w>>1)*64;
  f32x4 acc[4][4];
  #pragma unroll
  for (int i=0;i<4;++i)
    #pragma unroll
    for (int j=0;j<4;++j)
      #pragma unroll
      for (int r=0;r<4;++r) acc[i][j][r] = 0.f;
  const int sr = tid >> 2, sk = (tid & 3)*8;
  u16* lA0 = &As[w*512]; u16* lA1 = &As[2048 + w*512];
  u16* lB0 = &Bs[w*512]; u16* lB1 = &Bs[2048 + w*512];
  for (int k0 = 0; k0 < K; k0 += 32){
    __syncthreads();
    async_copy16(A  + (mbase      + sr)*(size_t)lda + k0 + sk, lA0);
    async_copy16(A  + (mbase + 64 + sr)*(size_t)lda + k0 + sk, lA1);
    async_copy16(Bw + (nbase      + sr)*(size_t)ldb + k0 + sk, lB0);
    async_copy16(Bw + (nbase + 64 + sr)*(size_t)ldb + k0 + sk, lB1);
    __syncthreads();
    bf16x8 af[4], bf[4];
    #pragma unroll
    for (int rt=0;rt<4;++rt) af[rt] = *(const bf16x8*)&As[(wr+rt*16+mrow)*32 + quad*8];
    #pragma unroll
    for (int ct=0;ct<4;++ct) bf[ct] = *(const bf16x8*)&Bs[(wc+ct*16+mrow)*32 + quad*8];
    #pragma unroll
    for (int rt=0;rt<4;++rt)
      #pragma unroll
      for (int ct=0;ct<4;++ct) acc[rt][ct] = MFMA16(af[rt], bf[ct], acc[rt][ct]);
  }
  #pragma unroll
  for (int rt=0;rt<4;++rt)
    #pragma unroll
    for (int ct=0;ct<4;++ct){
      const size_t row0 = mbase + wr + rt*16 + quad*4;
      const int col = (int)nbase + wc + ct*16 + mrow;
      const float bv = bias ? bias[col] : 0.f;
      #pragma unroll
      for (int r=0;r<4;++r) C[(row0+r)*(size_t)ldc + col] = f2b(acc[rt][ct][r] + bv);
    }
}

// ---------------- LayerNorm over 256-element groups, bf16 in/out ----------------
__global__ __launch_bounds__(256,2) void ln256_k(const u16* __restrict__ in, u16* __restrict__ out,
    const float* __restrict__ g, const float* __restrict__ bta){
  const int tid = threadIdx.x, lane = tid & 63, w = tid >> 6;
  const size_t row = (size_t)blockIdx.x*4 + w;
  const uint2 u = *(const uint2*)(in + row*256 + lane*4);
  const float x0=b2f(u.x&0xffff), x1=b2f(u.x>>16), x2=b2f(u.y&0xffff), x3=b2f(u.y>>16);
  float s  = x0+x1+x2+x3;
  float ss = x0*x0+x1*x1+x2*x2+x3*x3;
  #pragma unroll
  for (int mk=1; mk<64; mk<<=1){ s += __shfl_xor(s,mk,64); ss += __shfl_xor(ss,mk,64); }
  const float mu = s*(1.f/256.f);
  const float var = ss*(1.f/256.f) - mu*mu;
  const float rs = rsqrtf(var + 1e-5f);
  const int c = lane*4;
  const float y0=(x0-mu)*rs*g[c  ]+bta[c  ];
  const float y1=(x1-mu)*rs*g[c+1]+bta[c+1];
  const float y2=(x2-mu)*rs*g[c+2]+bta[c+2];
  const float y3=(x3-mu)*rs*g[c+3]+bta[c+3];
  uint2 o; o.x = pk2f(y0,y1); o.y = pk2f(y2,y3);
  *(uint2*)(out + row*256 + lane*4) = o;
}

// ---------------- fused per-neighbor attention kernel (v10 = v9 + DPP softmax + G2 unroll) ----------------
// block = 64 rows (4 queries x 16), 512 threads = 8 waves, wave w owns f-slice [w*32,w*32+32), all 64 m.
// __launch_bounds__(512,4): 128-reg budget; av parked in LDS across G2; 2 blocks/CU -> 16 waves/CU.
#define DP   264
#define RELP 40
__global__ __launch_bounds__(512,4) void attn_k(
    const float* __restrict__ xyz, const int* __restrict__ idxb,
    const u16* __restrict__ lnqkv, const u16* __restrict__ qa, const u16* __restrict__ ka,
    const u16* __restrict__ mcomb, const u16* __restrict__ wp2, const u16* __restrict__ wa2,
    const u16* __restrict__ wp1pk, u16* __restrict__ res){
  __shared__ __attribute__((aligned(16))) u16 hbuf[64*DP];    // h1, then h2 (33.8 KB)
  __shared__ __attribute__((aligned(16))) u16 avbuf[64*DP];   // av parked across G2 (33.8 KB)
  __shared__ __attribute__((aligned(16))) u16 srel[64*RELP];  // rel bf16, k-padded to 32
  __shared__ int sidx[64];
  const int tid = threadIdx.x;
  const int b = blockIdx.x >> 10;                // 1024 blocks per batch
  const int nbase = (blockIdx.x & 1023) << 2;    // 4 queries
  const size_t gb = (size_t)b << 12;
  // ---- stage neighbor idx + rel
  if (tid < 64){
    const int m = tid;
    const int im = idxb[(gb + nbase + (m>>4))*16 + (m&15)] & 4095;
    sidx[m] = im;
    const int nn = nbase + (m>>4);
    const float* pq = xyz + (gb+nn)*3;
    const float* pm = xyz + (gb+im)*3;
    const float rx = pq[0]-pm[0], ry = pq[1]-pm[1], rz = pq[2]-pm[2];
    uint4 a; a.x = pk2f(rx,ry); a.y = pk2f(rz,0.f); a.z = 0u; a.w = 0u;
    uint4 z; z.x = z.y = z.z = z.w = 0u;
    *(uint4*)&srel[m*RELP]    = a;
    *(uint4*)&srel[m*RELP+8]  = z;
    *(uint4*)&srel[m*RELP+16] = z;
    *(uint4*)&srel[m*RELP+24] = z;
  }
  __syncthreads();
  const int lane = tid & 63, w = tid >> 6;
  const int mrow = lane & 15, quad = lane >> 4;
  const int fr = w << 5;                         // 32-wide f/h slice of this wave
  // ---- h1 via MFMA: D[h][m] for h in [fr,fr+32), m in [0,64)
  {
    bf16x8 aW[2], bR[4];
    #pragma unroll
    for (int ht=0;ht<2;++ht) aW[ht] = *(const bf16x8*)&wp1pk[(fr+ht*16+mrow)*32 + quad*8];
    #pragma unroll
    for (int mt=0;mt<4;++mt) bR[mt] = *(const bf16x8*)&srel[(mt*16+mrow)*RELP + quad*8];
    #pragma unroll
    for (int ht=0;ht<2;++ht)
      #pragma unroll
      for (int mt=0;mt<4;++mt){
        f32x4 hz;
        #pragma unroll
        for (int r=0;r<4;++r) hz[r]=0.f;
        hz = MFMA16(aW[ht], bR[mt], hz);
        float h0 = hz[0]>0.f?hz[0]:0.f, h1v = hz[1]>0.f?hz[1]:0.f;
        float h2v = hz[2]>0.f?hz[2]:0.f, h3 = hz[3]>0.f?hz[3]:0.f;
        uint2 o; o.x = pk2f(h0,h1v); o.y = pk2f(h2v,h3);
        *(uint2*)&hbuf[(mt*16+mrow)*DP + fr + ht*16 + quad*4] = o;
      }
  }
  int midx[4];
  #pragma unroll
  for (int mt = 0; mt < 4; ++mt) midx[mt] = sidx[mt*16 + mrow];
  __syncthreads();             // h1 complete
  // ---- G1: t.T and val.T
  f32x4 at[2][4], av[2][4];
  #pragma unroll
  for (int i=0;i<2;++i)
    #pragma unroll
    for (int j=0;j<4;++j)
      #pragma unroll
      for (int r=0;r<4;++r){ at[i][j][r]=0.f; av[i][j][r]=0.f; }
  #pragma unroll 1
  for (int ks = 0; ks < 8; ++ks){
    const int koff = ks*32 + quad*8;
    bf16x8 aM[2], aP[2], bH[4];
    #pragma unroll
    for (int ft=0;ft<2;++ft){
      aM[ft] = *(const bf16x8*)&mcomb[(fr+ft*16+mrow)*256 + koff];
      aP[ft] = *(const bf16x8*)&wp2  [(fr+ft*16+mrow)*256 + koff];
    }
    #pragma unroll
    for (int mt=0;mt<4;++mt) bH[mt] = *(const bf16x8*)&hbuf[(mt*16+mrow)*DP + koff];
    #pragma unroll
    for (int ft=0;ft<2;++ft)
      #pragma unroll
      for (int mt=0;mt<4;++mt){
        at[ft][mt] = MFMA16(aM[ft], bH[mt], at[ft][mt]);
        av[ft][mt] = MFMA16(aP[ft], bH[mt], av[ft][mt]);
      }
  }
  // ---- qkp gather AFTER G1 (barrier wait below hides the latency; keeps G1 live-set small)
  uint2 qkp[2][4];
  #pragma unroll
  for (int ft = 0; ft < 2; ++ft)
    #pragma unroll
    for (int mt = 0; mt < 4; ++mt){
      const int f = fr + ft*16 + quad*4;
      const uint2 uq = *(const uint2*)&qa[(gb + nbase + mt)*256 + f];
      const uint2 uk = *(const uint2*)&ka[(gb + (size_t)midx[mt])*256 + f];
      uint2 o;
      o.x = pk2f(b2f(uq.x&0xffff)-b2f(uk.x&0xffff), b2f(uq.x>>16)-b2f(uk.x>>16));
      o.y = pk2f(b2f(uq.y&0xffff)-b2f(uk.y&0xffff), b2f(uq.y>>16)-b2f(uk.y>>16));
      qkp[ft][mt] = o;
    }
  __syncthreads();             // all waves done reading h1
  // ---- epilogue: h2 = relu(t + (qa-ka)) -> hbuf ; av -> avbuf (bf16), regs freed
  #pragma unroll
  for (int ft=0;ft<2;++ft)
    #pragma unroll
    for (int mt=0;mt<4;++mt){
      const int moff = (mt*16+mrow)*DP + fr + ft*16 + quad*4;
      const uint2 qv = qkp[ft][mt];
      float t0 = at[ft][mt][0] + b2f(qv.x&0xffff);
      float t1 = at[ft][mt][1] + b2f(qv.x>>16);
      float t2 = at[ft][mt][2] + b2f(qv.y&0xffff);
      float t3 = at[ft][mt][3] + b2f(qv.y>>16);
      t0 = t0>0.f?t0:0.f; t1 = t1>0.f?t1:0.f; t2 = t2>0.f?t2:0.f; t3 = t3>0.f?t3:0.f;
      uint2 o; o.x = pk2f(t0,t1); o.y = pk2f(t2,t3);
      *(uint2*)&hbuf[moff] = o;
      uint2 va; va.x = pk2f(av[ft][mt][0],av[ft][mt][1]); va.y = pk2f(av[ft][mt][2],av[ft][mt][3]);
      *(uint2*)&avbuf[moff] = va;
    }
  // ---- v gather prefetch (av/at regs dead; consumed after G2; barrier hides latency)
  uint2 vpre[2][4];
  #pragma unroll
  for (int ft=0;ft<2;++ft)
    #pragma unroll
    for (int mt=0;mt<4;++mt)
      vpre[ft][mt] = *(const uint2*)&lnqkv[(gb + (size_t)midx[mt])*768 + 512 + fr + ft*16 + quad*4];
  __syncthreads();
  // ---- G2: logits.T = Wa2 @ h2.T (unroll 2: 32-AGPR phase has VGPR headroom for pipelining)
  f32x4 al[2][4];
  #pragma unroll
  for (int i=0;i<2;++i)
    #pragma unroll
    for (int j=0;j<4;++j)
      #pragma unroll
      for (int r=0;r<4;++r) al[i][j][r]=0.f;
  #pragma unroll 2
  for (int ks = 0; ks < 8; ++ks){
    const int koff = ks*32 + quad*8;
    bf16x8 aW[2], bH[4];
    #pragma unroll
    for (int gt=0;gt<2;++gt) aW[gt] = *(const bf16x8*)&wa2[(fr+gt*16+mrow)*256 + koff];
    #pragma unroll
    for (int mt=0;mt<4;++mt) bH[mt] = *(const bf16x8*)&hbuf[(mt*16+mrow)*DP + koff];
    #pragma unroll
    for (int gt=0;gt<2;++gt)
      #pragma unroll
      for (int mt=0;mt<4;++mt) al[gt][mt] = MFMA16(aW[gt], bH[mt], al[gt][mt]);
  }
  // ---- softmax over 16 neighbors (= lane&15 = one DPP row) + weighted reduce
  const float sc = 0.0901684f;   // log2(e)/sqrt(256)
  #pragma unroll
  for (int gt=0;gt<2;++gt)
    #pragma unroll
    for (int mt=0;mt<4;++mt){
      const uint2 va = *(const uint2*)&avbuf[(mt*16+mrow)*DP + fr + gt*16 + quad*4];
      float avv[4];
      avv[0] = b2f(va.x&0xffff); avv[1] = b2f(va.x>>16);
      avv[2] = b2f(va.y&0xffff); avv[3] = b2f(va.y>>16);
      float rv[4];
      #pragma unroll
      for (int r=0;r<4;++r){
        u32 hv;
        if      (r==0) hv = vpre[gt][mt].x & 0xffff;
        else if (r==1) hv = vpre[gt][mt].x >> 16;
        else if (r==2) hv = vpre[gt][mt].y & 0xffff;
        else           hv = vpre[gt][mt].y >> 16;
        const float val = avv[r] + b2f(hv);
        float pr = exp2f(al[gt][mt][r]*sc);   // logits are O(1); no max-sub needed
        float wg = pr*val;
        pr = rowsum16(pr);                    // VALU-pipe DPP reduce (no LDS traffic)
        wg = rowsum16(wg);
        rv[r] = wg * __builtin_amdgcn_rcpf(pr);
      }
      if (mrow == 0){
        uint2 o; o.x = pk2f(rv[0],rv[1]); o.y = pk2f(rv[2],rv[3]);
        *(uint2*)&res[(gb + nbase + mt)*256 + fr + gt*16 + quad*4] = o;
      }
    }
}

// ---------------- final: out = ln(r1 @ W_post.T + b_post)*g+b + features ----------------
__global__ __launch_bounds__(256,2) void d2_k(
    const u16* __restrict__ r1, const u16* __restrict__ wpost,
    const float* __restrict__ bpost, const float* __restrict__ g, const float* __restrict__ bt,
    const float* __restrict__ feat, float* __restrict__ out){
  const int tid = threadIdx.x, lane = tid & 63, w = tid >> 6;
  const int mrow = lane & 15, quad = lane >> 4;
  const size_t rb = (size_t)blockIdx.x*128 + w*32;
  f32x4 acc[2][4];
  #pragma unroll
  for (int i=0;i<2;++i)
    #pragma unroll
    for (int j=0;j<4;++j)
      #pragma unroll
      for (int r=0;r<4;++r) acc[i][j][r]=0.f;
  #pragma unroll 1
  for (int ks = 0; ks < 8; ++ks){
    const int koff = ks*32 + quad*8;
    bf16x8 af[2], bf[4];
    #pragma unroll
    for (int rt=0;rt<2;++rt) af[rt] = *(const bf16x8*)&r1[(rb+rt*16+mrow)*256 + koff];
    #pragma unroll
    for (int ct=0;ct<4;++ct) bf[ct] = *(const bf16x8*)&wpost[(ct*16+mrow)*256 + koff];
    #pragma unroll
    for (int rt=0;rt<2;++rt)
      #pragma unroll
      for (int ct=0;ct<4;++ct) acc[rt][ct] = MFMA16(af[rt], bf[ct], acc[rt][ct]);
  }
  #pragma unroll
  for (int ct=0;ct<4;++ct){
    const float bv = bpost[ct*16+mrow];
    #pragma unroll
    for (int rt=0;rt<2;++rt)
      #pragma unroll
      for (int r=0;r<4;++r) acc[rt][ct][r] += bv;
  }
  #pragma unroll
  for (int rt=0;rt<2;++rt)
    #pragma unroll
    for (int r=0;r<4;++r){
      float s  = acc[rt][0][r]+acc[rt][1][r]+acc[rt][2][r]+acc[rt][3][r];
      float ss = acc[rt][0][r]*acc[rt][0][r]+acc[rt][1][r]*acc[rt][1][r]
               + acc[rt][2][r]*acc[rt][2][r]+acc[rt][3][r]*acc[rt][3][r];
      s  = rowsum16(s);
      ss = rowsum16(ss);
      const float mu = s*(1.f/64.f);
      const float var = ss*(1.f/64.f) - mu*mu;
      const float rs = rsqrtf(var + 1e-5f);
      const size_t row = rb + rt*16 + quad*4 + r;
      #pragma unroll
      for (int ct=0;ct<4;++ct){
        const int n = ct*16 + mrow;
        out[row*64 + n] = (acc[rt][ct][r]-mu)*rs*g[n] + bt[n] + feat[row*64 + n];
      }
    }
}

// ---------------- launcher ----------------
extern "C" void kernel_launch(void* const* d_in, const int* in_sizes, int n_in,
                              void* d_out, int out_size, void* d_ws, size_t ws_size,
                              hipStream_t stream){
  const float* xyz    = (const float*)d_in[0];
  const float* feat   = (const float*)d_in[1];
  const float* W_pre  = (const float*)d_in[2];
  const float* b_pre  = (const float*)d_in[3];
  const float* W_post = (const float*)d_in[4];
  const float* b_post = (const float*)d_in[5];
  const float* Wp1    = (const float*)d_in[6];
  const float* Wp2    = (const float*)d_in[7];
  const float* Wa1    = (const float*)d_in[8];
  const float* Wa2    = (const float*)d_in[9];
  const float* WQ     = (const float*)d_in[10];
  const float* WK     = (const float*)d_in[11];
  const float* WV     = (const float*)d_in[12];
  const float* Wproj  = (const float*)d_in[13];
  const float* g_dm   = (const float*)d_in[14];
  const float* b_dm   = (const float*)d_in[15];
  const float* g_dp   = (const float*)d_in[16];
  const float* b_dp   = (const float*)d_in[17];
  float* out = (float*)d_out;
  if (ws_size < WS_NEED) return;
  char* ws = (char*)d_ws;
  int* idxw   = (int*)(ws + OFF_IDX);
  u16* featb  = (u16*)(ws + OFF_FEATB);
  u16* wpreb  = (u16*)(ws + OFF_WPRE);
  u16* wqkvb  = (u16*)(ws + OFF_WQKV);
  u16* wa1b   = (u16*)(ws + OFF_WA1);
  u16* wa2b   = (u16*)(ws + OFF_WA2);
  u16* wp2b   = (u16*)(ws + OFF_WP2);
  u16* wprojb = (u16*)(ws + OFF_WPROJ);
  u16* wpostb = (u16*)(ws + OFF_WPOST);
  u16* mcombb = (u16*)(ws + OFF_MCOMB);
  u16* inp    = (u16*)(ws + OFF_INP);
  u16* qkv    = (u16*)(ws + OFF_QKV);
  u16* lnqkv  = (u16*)(ws + OFF_LNQKV);
  u16* qab    = (u16*)(ws + OFF_QA);
  u16* kab    = (u16*)(ws + OFF_KA);
  u16* resb   = (u16*)(ws + OFF_RES);
  u16* d1raw  = (u16*)(ws + OFF_D1);
  u16* r1b    = (u16*)(ws + OFF_R1);
  u16* wp1pk  = (u16*)(ws + OFF_WP1PK);   // aliases d1raw: read by attn_k before d1 GEMM writes
  u16* wp2T   = (u16*)(ws + OFF_WP2T);    // aliases qkv: consumed before qkv GEMM writes

  convert_k<<<6081,256,0,stream>>>(feat,W_pre,WQ,WK,WV,Wa1,Wa2,Wp2,Wproj,W_post,Wp1,
                                   featb,wpreb,wqkvb,wa1b,wa2b,wp2b,wprojb,wpostb,
                                   wp1pk,wp2T);
  // Mcomb = Wa1 @ Wp2 : C[f][h] = sum_k wa1[f][k] * wp2T[h][k]
  gemm128_k<<<dim3(2,2),256,0,stream>>>(wa1b,256, wp2T,256, mcombb,256, 256, nullptr, 0,0);
  knn_kernel<<<1024,256,0,stream>>>(xyz,idxw);
  // inp = features @ W_pre.T + b_pre
  gemm128_k<<<dim3(128,2),256,0,stream>>>(featb,64,  wpreb,64,  inp,256, 64,  b_pre, 0,0);
  // qkv = inp @ [WQ|WK|WV].T
  gemm128_k<<<dim3(128,6),256,0,stream>>>(inp,256,   wqkvb,256, qkv,768, 256, nullptr, 0,0);
  ln256_k<<<12288,256,0,stream>>>(qkv,lnqkv,g_dm,b_dm);
  // qa = ln(q) @ Wa1.T ; ka = ln(k) @ Wa1.T  (one launch; z selects q/k source + dest)
  gemm128_k<<<dim3(128,2,2),256,0,stream>>>(lnqkv,768, wa1b,256, qab,256, 256, nullptr,
                                            256, 4194304);
  attn_k<<<4096,512,0,stream>>>(xyz,idxw,lnqkv,qab,kab,mcombb,wp2b,wa2b,wp1pk,resb);
  // d1 = res @ Wproj.T ; r1 = ln(d1)
  gemm128_k<<<dim3(128,2),256,0,stream>>>(resb,256, wprojb,256, d1raw,256, 256, nullptr, 0,0);
  ln256_k<<<4096,256,0,stream>>>(d1raw,r1b,g_dm,b_dm);
  d2_k<<<128,256,0,stream>>>(r1b,wpostb,b_post,g_dp,b_dp,feat,out);
}

// Round 11
// 540.434 us; speedup vs baseline: 1.5462x; 1.0394x over previous
//
#include <hip/hip_runtime.h>
#include <hip/hip_bf16.h>

typedef unsigned short u16;
typedef unsigned int   u32;
typedef __attribute__((ext_vector_type(8))) short bf16x8;
typedef __attribute__((ext_vector_type(4))) float f32x4;

#define MFMA16(a,b,c) __builtin_amdgcn_mfma_f32_16x16x32_bf16((a),(b),(c),0,0,0)

__device__ __forceinline__ float b2f(u32 h){ return __uint_as_float(h<<16); }
__device__ __forceinline__ u16 f2b(float f){
  u32 u = __float_as_uint(f);
  return (u16)((u + 0x7FFFu + ((u>>16)&1u))>>16);
}
// HW packed convert: v_cvt_pk_bf16_f32 (RNE)
__device__ __forceinline__ u32 pk2f(float a,float b){
  __hip_bfloat162 h = __float22bfloat162_rn(float2{a,b});
  return *reinterpret_cast<u32*>(&h);
}
__device__ __forceinline__ u32 umin32(u32 a,u32 b){ return a<b?a:b; }
__device__ __forceinline__ u32 umax32(u32 a,u32 b){ return a>b?a:b; }

// 16-lane row-sum on the VALU pipe via DPP row_ror (d2_k LN reduce)
template<int CTRL>
__device__ __forceinline__ float dpp_add(float x){
  int t = __builtin_amdgcn_update_dpp(0, __float_as_int(x), CTRL, 0xF, 0xF, true);
  return x + __int_as_float(t);
}
__device__ __forceinline__ float rowsum16(float x){
  x = dpp_add<0x121>(x);
  x = dpp_add<0x122>(x);
  x = dpp_add<0x124>(x);
  x = dpp_add<0x128>(x);
  return x;
}

__device__ __forceinline__ void async_copy16(const void* g, void* l){
  __builtin_amdgcn_global_load_lds((const __attribute__((address_space(1))) u32*)g,
                                   (__attribute__((address_space(3))) u32*)l, 16, 0, 0);
}

// ---------------- workspace layout (bytes) ----------------
#define OFF_IDX    0ull
#define OFF_FEATB  1048576ull
#define OFF_WPRE   3145728ull
#define OFF_WQKV   3178496ull
#define OFF_WA1    3571712ull
#define OFF_WA2    3702784ull
#define OFF_WP2    3833856ull
#define OFF_WPROJ  3964928ull
#define OFF_WPOST  4096000ull
#define OFF_MCOMB  4128768ull
#define OFF_INP    4259840ull
#define OFF_QKV    12648448ull
#define OFF_LNQKV  37814272ull
#define OFF_QA     62980096ull
#define OFF_KA     71368704ull
#define OFF_RES    79757312ull
#define OFF_D1     88145920ull     // also hosts wp1pk early (d1 written only after attn)
#define OFF_R1     96534528ull
#define WS_NEED    104923136ull
#define OFF_WP1PK  OFF_D1
#define OFF_WP2T   OFF_QKV         // wp2^T consumed by mcomb GEMM before qkv GEMM writes here

// ---------------- f32 -> bf16 conversions + wp1 pack + wp2 transpose (fused) ----------------
__global__ void convert_k(const float* __restrict__ feat, const float* __restrict__ wpre,
    const float* __restrict__ wq, const float* __restrict__ wk, const float* __restrict__ wv,
    const float* __restrict__ wa1, const float* __restrict__ wa2, const float* __restrict__ wp2,
    const float* __restrict__ wproj, const float* __restrict__ wpost,
    const float* __restrict__ wp1,
    u16* __restrict__ dfeat, u16* __restrict__ dwpre, u16* __restrict__ dwqkv,
    u16* __restrict__ dwa1, u16* __restrict__ dwa2, u16* __restrict__ dwp2,
    u16* __restrict__ dwproj, u16* __restrict__ dwpost,
    u16* __restrict__ dwp1pk, u16* __restrict__ dwp2T){
  __shared__ u16 t[32][33];
  const int bid = blockIdx.x, tid = threadIdx.x;
  if (bid < 6016){
    int id = bid*256 + tid;
    const float* s; u16* d; int off;
    if      (id < 1048576){ s=feat;  d=dfeat;        off=id; }
    else if (id < 1064960){ s=wpre;  d=dwpre;        off=id-1048576; }
    else if (id < 1130496){ s=wq;    d=dwqkv;        off=id-1064960; }
    else if (id < 1196032){ s=wk;    d=dwqkv+65536;  off=id-1130496; }
    else if (id < 1261568){ s=wv;    d=dwqkv+131072; off=id-1196032; }
    else if (id < 1327104){ s=wa1;   d=dwa1;         off=id-1261568; }
    else if (id < 1392640){ s=wa2;   d=dwa2;         off=id-1327104; }
    else if (id < 1458176){ s=wp2;   d=dwp2;         off=id-1392640; }
    else if (id < 1523712){ s=wproj; d=dwproj;       off=id-1458176; }
    else if (id < 1540096){ s=wpost; d=dwpost;       off=id-1523712; }
    else return;
    d[off] = f2b(s[off]);
  } else if (bid == 6016){
    const int h = tid;
    const float w0 = wp1[h*3], w1 = wp1[h*3+1], w2 = wp1[h*3+2];
    uint4 a; a.x = pk2f(w0,w1); a.y = pk2f(w2,0.f); a.z = 0u; a.w = 0u;
    uint4 z; z.x = z.y = z.z = z.w = 0u;
    *(uint4*)&dwp1pk[h*32]    = a;
    *(uint4*)&dwp1pk[h*32+8]  = z;
    *(uint4*)&dwp1pk[h*32+16] = z;
    *(uint4*)&dwp1pk[h*32+24] = z;
  } else {
    const int tb = bid - 6017;
    const int bx = tb & 7, by = tb >> 3;
    const int tx = tid & 31, ty = tid >> 5;
    #pragma unroll
    for (int r = 0; r < 4; ++r) t[ty+8*r][tx] = f2b(wp2[(by*32+ty+8*r)*256 + bx*32+tx]);
    __syncthreads();
    #pragma unroll
    for (int r = 0; r < 4; ++r) dwp2T[(bx*32+ty+8*r)*256 + by*32+tx] = t[tx][ty+8*r];
  }
}

// ---------------- kNN: exact top-16 by (d2, idx) ----------------
__device__ __forceinline__ void ins16(u32 (&a)[16], u32 key){
  #pragma unroll
  for (int j = 15; j >= 1; --j) a[j] = umin32(umax32(a[j-1],key), a[j]);
  a[0] = umin32(a[0], key);
}

__device__ __forceinline__ float dist2(float ax,float ay,float az,float bx,float by,float bz){
  const float dx = ax-bx, dy = ay-by, dz = az-bz;
  return __fmaf_rn(dx,dx, __fmaf_rn(dy,dy, dz*dz));
}

__global__ __launch_bounds__(256,3) void knn_kernel(const float* __restrict__ xyz,
                                                    int* __restrict__ idxout){
  __shared__ __attribute__((aligned(16))) float sbuf[3*4104];
  __shared__ int lcnt[16];
  __shared__ int tcnt[16];
  __shared__ u32 tbuf[16];
  __shared__ int tiebuf[16*16];
  float* sx = sbuf; float* sy = sbuf + 4104; float* sz = sbuf + 8208;
  const int tid = threadIdx.x;
  const int b  = blockIdx.x >> 8;
  const int n0 = (blockIdx.x & 255) << 4;
  const float* base = xyz + (size_t)b*12288;
  #pragma unroll
  for (int i = 0; i < 12; ++i){
    const float4 v = *(const float4*)(base + tid*48 + i*4);
    const float vv[4] = {v.x, v.y, v.z, v.w};
    #pragma unroll
    for (int j = 0; j < 4; ++j){
      const int e = i*4 + j;
      const int c = e % 3;
      const int m = tid*16 + e/3;
      float* arr = (c==0)?sx:((c==1)?sy:sz);
      arr[m + (m>>9)] = vv[j];
    }
  }
  if (tid < 16){ lcnt[tid] = 0; tcnt[tid] = 0; }
  __syncthreads();
  const int qi = tid >> 4, p = tid & 15;
  const int n = n0 + qi;
  const int sn = n + (n>>9);
  const float qx = sx[sn], qy = sy[sn], qz = sz[sn];
  u32 a[16];
  #pragma unroll
  for (int j = 0; j < 16; ++j) a[j] = 0xFFFFFFFFu;
  const int sb = p*256 + (p>>1);
  #pragma unroll 2
  for (int i = 0; i < 256; ++i){
    const float d2 = dist2(sx[sb+i],sy[sb+i],sz[sb+i],qx,qy,qz);
    ins16(a, __float_as_uint(d2));
  }
  #pragma unroll
  for (int s = 8; s >= 1; s >>= 1){
    u32 o[16];
    #pragma unroll
    for (int j = 0; j < 16; ++j) o[j] = __shfl_down(a[j], (unsigned)s, 64);
    if (p < s){
      #pragma unroll
      for (int j = 0; j < 16; ++j) ins16(a, o[j]);
    }
  }
  if (p == 0) tbuf[qi] = a[15];
  __syncthreads();
  const u32 T = tbuf[qi];
  int* orow = idxout + ((size_t)(b<<12)+n)*16;
  const int gbase = p*256;
  for (int i = 0; i < 256; ++i){
    const float d2 = dist2(sx[sb+i],sy[sb+i],sz[sb+i],qx,qy,qz);
    const u32 kb = __float_as_uint(d2);
    if (kb < T){
      const int pos = atomicAdd(&lcnt[qi],1);
      if (pos < 16) orow[pos] = gbase + i;
    } else if (kb == T){
      const int t = atomicAdd(&tcnt[qi],1);
      if (t < 16) tiebuf[qi*16+t] = gbase + i;
    }
  }
  __syncthreads();
  if (p == 0){
    int L = lcnt[qi]; if (L > 16) L = 16;
    int tc = tcnt[qi]; if (tc > 16) tc = 16;
    const int need = 16 - L;
    for (int r = 0; r < need; ++r){
      int best = 0x7FFFFFFF, bj = -1;
      for (int j = 0; j < tc; ++j){
        const int v = tiebuf[qi*16+j];
        if (v < best){ best = v; bj = j; }
      }
      if (bj >= 0){ tiebuf[qi*16+bj] = 0x7FFFFFFF; orow[L+r] = best; }
      else orow[L+r] = n;
    }
  }
}

// ---------------- generic 128x128 bf16 GEMM: C[m][n] = sum_k A[m][k]*B[n][k] (+bias) ----------------
__global__ __launch_bounds__(256,2) void gemm128_k(
    const u16* __restrict__ A, const int lda,
    const u16* __restrict__ Bw, const int ldb,
    u16* __restrict__ C, const int ldc,
    const int K, const float* __restrict__ bias,
    const size_t zA, const size_t zC){
  __shared__ __attribute__((aligned(16))) u16 As[128*32];
  __shared__ __attribute__((aligned(16))) u16 Bs[128*32];
  A += blockIdx.z * zA;
  C += blockIdx.z * zC;
  const int tid = threadIdx.x, lane = tid & 63, w = tid >> 6;
  const int mrow = lane & 15, quad = lane >> 4;
  const size_t mbase = (size_t)blockIdx.x*128, nbase = (size_t)blockIdx.y*128;
  const int wr = (w&1)*64, wc = (w>>1)*64;
  f32x4 acc[4][4];
  #pragma unroll
  for (int i=0;i<4;++i)
    #pragma unroll
    for (int j=0;j<4;++j)
      #pragma unroll
      for (int r=0;r<4;++r) acc[i][j][r] = 0.f;
  const int sr = tid >> 2, sk = (tid & 3)*8;
  u16* lA0 = &As[w*512]; u16* lA1 = &As[2048 + w*512];
  u16* lB0 = &Bs[w*512]; u16* lB1 = &Bs[2048 + w*512];
  for (int k0 = 0; k0 < K; k0 += 32){
    __syncthreads();
    async_copy16(A  + (mbase      + sr)*(size_t)lda + k0 + sk, lA0);
    async_copy16(A  + (mbase + 64 + sr)*(size_t)lda + k0 + sk, lA1);
    async_copy16(Bw + (nbase      + sr)*(size_t)ldb + k0 + sk, lB0);
    async_copy16(Bw + (nbase + 64 + sr)*(size_t)ldb + k0 + sk, lB1);
    __syncthreads();
    bf16x8 af[4], bf[4];
    #pragma unroll
    for (int rt=0;rt<4;++rt) af[rt] = *(const bf16x8*)&As[(wr+rt*16+mrow)*32 + quad*8];
    #pragma unroll
    for (int ct=0;ct<4;++ct) bf[ct] = *(const bf16x8*)&Bs[(wc+ct*16+mrow)*32 + quad*8];
    #pragma unroll
    for (int rt=0;rt<4;++rt)
      #pragma unroll
      for (int ct=0;ct<4;++ct) acc[rt][ct] = MFMA16(af[rt], bf[ct], acc[rt][ct]);
  }
  #pragma unroll
  for (int rt=0;rt<4;++rt)
    #pragma unroll
    for (int ct=0;ct<4;++ct){
      const size_t row0 = mbase + wr + rt*16 + quad*4;
      const int col = (int)nbase + wc + ct*16 + mrow;
      const float bv = bias ? bias[col] : 0.f;
      #pragma unroll
      for (int r=0;r<4;++r) C[(row0+r)*(size_t)ldc + col] = f2b(acc[rt][ct][r] + bv);
    }
}

// ---------------- LayerNorm over 256-element groups, bf16 in/out ----------------
__global__ __launch_bounds__(256,2) void ln256_k(const u16* __restrict__ in, u16* __restrict__ out,
    const float* __restrict__ g, const float* __restrict__ bta){
  const int tid = threadIdx.x, lane = tid & 63, w = tid >> 6;
  const size_t row = (size_t)blockIdx.x*4 + w;
  const uint2 u = *(const uint2*)(in + row*256 + lane*4);
  const float x0=b2f(u.x&0xffff), x1=b2f(u.x>>16), x2=b2f(u.y&0xffff), x3=b2f(u.y>>16);
  float s  = x0+x1+x2+x3;
  float ss = x0*x0+x1*x1+x2*x2+x3*x3;
  #pragma unroll
  for (int mk=1; mk<64; mk<<=1){ s += __shfl_xor(s,mk,64); ss += __shfl_xor(ss,mk,64); }
  const float mu = s*(1.f/256.f);
  const float var = ss*(1.f/256.f) - mu*mu;
  const float rs = rsqrtf(var + 1e-5f);
  const int c = lane*4;
  const float y0=(x0-mu)*rs*g[c  ]+bta[c  ];
  const float y1=(x1-mu)*rs*g[c+1]+bta[c+1];
  const float y2=(x2-mu)*rs*g[c+2]+bta[c+2];
  const float y3=(x3-mu)*rs*g[c+3]+bta[c+3];
  uint2 o; o.x = pk2f(y0,y1); o.y = pk2f(y2,y3);
  *(uint2*)(out + row*256 + lane*4) = o;
}

// ---------------- fused per-neighbor attention kernel (v11: flipped av/al orientation) ----------------
// block = 64 rows (4 queries x 16), 512 threads = 8 waves, wave w owns f-slice [w*32,w*32+32).
// at (G1) unchanged: D[f][m]. av (G2a from h1) and al (G2b from h2) computed FLIPPED via
// MFMA16(bH, aW): D[m][g] with m on quad*4+reg, g on lane&15 -> k-reduce = 3 in-lane adds
// + 2 shfl_xor. No av parking, no avbuf; h2 in its own buffer; 3 barriers.
#define DP   264
#define RELP 40
__global__ __launch_bounds__(512,4) void attn_k(
    const float* __restrict__ xyz, const int* __restrict__ idxb,
    const u16* __restrict__ lnqkv, const u16* __restrict__ qa, const u16* __restrict__ ka,
    const u16* __restrict__ mcomb, const u16* __restrict__ wp2, const u16* __restrict__ wa2,
    const u16* __restrict__ wp1pk, u16* __restrict__ res){
  __shared__ __attribute__((aligned(16))) u16 h1buf[64*DP];   // h1 (33.8 KB)
  __shared__ __attribute__((aligned(16))) u16 h2buf[64*DP];   // h2 (33.8 KB)
  __shared__ __attribute__((aligned(16))) u16 srel[64*RELP];  // rel bf16, k-padded to 32
  __shared__ int sidx[64];
  const int tid = threadIdx.x;
  const int b = blockIdx.x >> 10;
  const int nbase = (blockIdx.x & 1023) << 2;
  const size_t gb = (size_t)b << 12;
  // ---- stage neighbor idx + rel
  if (tid < 64){
    const int m = tid;
    const int im = idxb[(gb + nbase + (m>>4))*16 + (m&15)] & 4095;
    sidx[m] = im;
    const int nn = nbase + (m>>4);
    const float* pq = xyz + (gb+nn)*3;
    const float* pm = xyz + (gb+im)*3;
    const float rx = pq[0]-pm[0], ry = pq[1]-pm[1], rz = pq[2]-pm[2];
    uint4 a; a.x = pk2f(rx,ry); a.y = pk2f(rz,0.f); a.z = 0u; a.w = 0u;
    uint4 z; z.x = z.y = z.z = z.w = 0u;
    *(uint4*)&srel[m*RELP]    = a;
    *(uint4*)&srel[m*RELP+8]  = z;
    *(uint4*)&srel[m*RELP+16] = z;
    *(uint4*)&srel[m*RELP+24] = z;
  }
  __syncthreads();
  const int lane = tid & 63, w = tid >> 6;
  const int mrow = lane & 15, quad = lane >> 4;
  const int fr = w << 5;                         // 32-wide f/h slice of this wave
  // ---- h1 via MFMA: D[h][m] for h in [fr,fr+32), m in [0,64) -> h1buf[m][h]
  {
    bf16x8 aW[2], bR[4];
    #pragma unroll
    for (int ht=0;ht<2;++ht) aW[ht] = *(const bf16x8*)&wp1pk[(fr+ht*16+mrow)*32 + quad*8];
    #pragma unroll
    for (int mt=0;mt<4;++mt) bR[mt] = *(const bf16x8*)&srel[(mt*16+mrow)*RELP + quad*8];
    #pragma unroll
    for (int ht=0;ht<2;++ht)
      #pragma unroll
      for (int mt=0;mt<4;++mt){
        f32x4 hz;
        #pragma unroll
        for (int r=0;r<4;++r) hz[r]=0.f;
        hz = MFMA16(aW[ht], bR[mt], hz);
        float h0 = hz[0]>0.f?hz[0]:0.f, h1v = hz[1]>0.f?hz[1]:0.f;
        float h2v = hz[2]>0.f?hz[2]:0.f, h3 = hz[3]>0.f?hz[3]:0.f;
        uint2 o; o.x = pk2f(h0,h1v); o.y = pk2f(h2v,h3);
        *(uint2*)&h1buf[(mt*16+mrow)*DP + fr + ht*16 + quad*4] = o;
      }
  }
  int midx[4];
  #pragma unroll
  for (int mt = 0; mt < 4; ++mt) midx[mt] = sidx[mt*16 + mrow];
  __syncthreads();             // h1 complete
  // ---- G1: at.T = Mcomb @ h1.T  (D[f][m], unchanged orientation)
  f32x4 at[2][4];
  #pragma unroll
  for (int i=0;i<2;++i)
    #pragma unroll
    for (int j=0;j<4;++j)
      #pragma unroll
      for (int r=0;r<4;++r) at[i][j][r]=0.f;
  #pragma unroll 1
  for (int ks = 0; ks < 8; ++ks){
    const int koff = ks*32 + quad*8;
    bf16x8 aM[2], bH[4];
    #pragma unroll
    for (int ft=0;ft<2;++ft) aM[ft] = *(const bf16x8*)&mcomb[(fr+ft*16+mrow)*256 + koff];
    #pragma unroll
    for (int mt=0;mt<4;++mt) bH[mt] = *(const bf16x8*)&h1buf[(mt*16+mrow)*DP + koff];
    #pragma unroll
    for (int ft=0;ft<2;++ft)
      #pragma unroll
      for (int mt=0;mt<4;++mt) at[ft][mt] = MFMA16(aM[ft], bH[mt], at[ft][mt]);
  }
  // ---- qkp gather (latency hidden under G2a)
  uint2 qkp[2][4];
  #pragma unroll
  for (int ft = 0; ft < 2; ++ft)
    #pragma unroll
    for (int mt = 0; mt < 4; ++mt){
      const int f = fr + ft*16 + quad*4;
      const uint2 uq = *(const uint2*)&qa[(gb + nbase + mt)*256 + f];
      const uint2 uk = *(const uint2*)&ka[(gb + (size_t)midx[mt])*256 + f];
      uint2 o;
      o.x = pk2f(b2f(uq.x&0xffff)-b2f(uk.x&0xffff), b2f(uq.x>>16)-b2f(uk.x>>16));
      o.y = pk2f(b2f(uq.y&0xffff)-b2f(uk.y&0xffff), b2f(uq.y>>16)-b2f(uk.y>>16));
      qkp[ft][mt] = o;
    }
  // ---- G2a: av = h1 @ Wp2.T  FLIPPED: D[m][g], m=quad*4+reg, g=lane&15
  f32x4 av[2][4];
  #pragma unroll
  for (int i=0;i<2;++i)
    #pragma unroll
    for (int j=0;j<4;++j)
      #pragma unroll
      for (int r=0;r<4;++r) av[i][j][r]=0.f;
  #pragma unroll 1
  for (int ks = 0; ks < 8; ++ks){
    const int koff = ks*32 + quad*8;
    bf16x8 aP[2], bH[4];
    #pragma unroll
    for (int gt=0;gt<2;++gt) aP[gt] = *(const bf16x8*)&wp2[(fr+gt*16+mrow)*256 + koff];
    #pragma unroll
    for (int mt=0;mt<4;++mt) bH[mt] = *(const bf16x8*)&h1buf[(mt*16+mrow)*DP + koff];
    #pragma unroll
    for (int gt=0;gt<2;++gt)
      #pragma unroll
      for (int mt=0;mt<4;++mt) av[gt][mt] = MFMA16(bH[mt], aP[gt], av[gt][mt]);
  }
  // ---- epilogue: h2 = relu(at + (qa-ka)) -> h2buf (at regs freed)
  #pragma unroll
  for (int ft=0;ft<2;++ft)
    #pragma unroll
    for (int mt=0;mt<4;++mt){
      const int moff = (mt*16+mrow)*DP + fr + ft*16 + quad*4;
      const uint2 qv = qkp[ft][mt];
      float t0 = at[ft][mt][0] + b2f(qv.x&0xffff);
      float t1 = at[ft][mt][1] + b2f(qv.x>>16);
      float t2 = at[ft][mt][2] + b2f(qv.y&0xffff);
      float t3 = at[ft][mt][3] + b2f(qv.y>>16);
      t0 = t0>0.f?t0:0.f; t1 = t1>0.f?t1:0.f; t2 = t2>0.f?t2:0.f; t3 = t3>0.f?t3:0.f;
      uint2 o; o.x = pk2f(t0,t1); o.y = pk2f(t2,t3);
      *(uint2*)&h2buf[moff] = o;
    }
  __syncthreads();             // h2 complete
  // ---- G2b: al = h2 @ Wa2.T  FLIPPED: D[m][g]
  f32x4 al[2][4];
  #pragma unroll
  for (int i=0;i<2;++i)
    #pragma unroll
    for (int j=0;j<4;++j)
      #pragma unroll
      for (int r=0;r<4;++r) al[i][j][r]=0.f;
  #pragma unroll 1
  for (int ks = 0; ks < 8; ++ks){
    const int koff = ks*32 + quad*8;
    bf16x8 aW[2], bH[4];
    #pragma unroll
    for (int gt=0;gt<2;++gt) aW[gt] = *(const bf16x8*)&wa2[(fr+gt*16+mrow)*256 + koff];
    #pragma unroll
    for (int mt=0;mt<4;++mt) bH[mt] = *(const bf16x8*)&h2buf[(mt*16+mrow)*DP + koff];
    #pragma unroll
    for (int gt=0;gt<2;++gt)
      #pragma unroll
      for (int mt=0;mt<4;++mt) al[gt][mt] = MFMA16(bH[mt], aW[gt], al[gt][mt]);
  }
  // ---- v gather in flipped layout: per (mt,r): row = sidx[mt*16+quad*4+r], col = fr+gt*16+mrow
  int4 si[4];
  #pragma unroll
  for (int mt=0;mt<4;++mt) si[mt] = *(const int4*)&sidx[mt*16 + quad*4];
  u16 vv[2][4][4];
  #pragma unroll
  for (int mt=0;mt<4;++mt){
    const int rows[4] = {si[mt].x, si[mt].y, si[mt].z, si[mt].w};
    #pragma unroll
    for (int r=0;r<4;++r){
      const size_t rb = (gb + (size_t)rows[r])*768 + 512 + fr + mrow;
      vv[0][mt][r] = lnqkv[rb];
      vv[1][mt][r] = lnqkv[rb + 16];
    }
  }
  // ---- softmax over k = quad*4+reg (in-lane + cross-quad) + weighted reduce
  const float sc = 0.0901684f;   // log2(e)/sqrt(256)
  #pragma unroll
  for (int gt=0;gt<2;++gt)
    #pragma unroll
    for (int mt=0;mt<4;++mt){
      float prs = 0.f, wgs = 0.f;
      #pragma unroll
      for (int r=0;r<4;++r){
        const float val = av[gt][mt][r] + b2f((u32)vv[gt][mt][r]);
        const float pr = exp2f(al[gt][mt][r]*sc);
        prs += pr;
        wgs += pr*val;
      }
      prs += __shfl_xor(prs, 16, 64); prs += __shfl_xor(prs, 32, 64);
      wgs += __shfl_xor(wgs, 16, 64); wgs += __shfl_xor(wgs, 32, 64);
      const float rv = wgs * __builtin_amdgcn_rcpf(prs);
      if (quad == 0)
        res[(gb + nbase + mt)*256 + fr + gt*16 + mrow] = f2b(rv);
    }
}

// ---------------- final: out = ln(r1 @ W_post.T + b_post)*g+b + features ----------------
__global__ __launch_bounds__(256,2) void d2_k(
    const u16* __restrict__ r1, const u16* __restrict__ wpost,
    const float* __restrict__ bpost, const float* __restrict__ g, const float* __restrict__ bt,
    const float* __restrict__ feat, float* __restrict__ out){
  const int tid = threadIdx.x, lane = tid & 63, w = tid >> 6;
  const int mrow = lane & 15, quad = lane >> 4;
  const size_t rb = (size_t)blockIdx.x*128 + w*32;
  f32x4 acc[2][4];
  #pragma unroll
  for (int i=0;i<2;++i)
    #pragma unroll
    for (int j=0;j<4;++j)
      #pragma unroll
      for (int r=0;r<4;++r) acc[i][j][r]=0.f;
  #pragma unroll 1
  for (int ks = 0; ks < 8; ++ks){
    const int koff = ks*32 + quad*8;
    bf16x8 af[2], bf[4];
    #pragma unroll
    for (int rt=0;rt<2;++rt) af[rt] = *(const bf16x8*)&r1[(rb+rt*16+mrow)*256 + koff];
    #pragma unroll
    for (int ct=0;ct<4;++ct) bf[ct] = *(const bf16x8*)&wpost[(ct*16+mrow)*256 + koff];
    #pragma unroll
    for (int rt=0;rt<2;++rt)
      #pragma unroll
      for (int ct=0;ct<4;++ct) acc[rt][ct] = MFMA16(af[rt], bf[ct], acc[rt][ct]);
  }
  #pragma unroll
  for (int ct=0;ct<4;++ct){
    const float bv = bpost[ct*16+mrow];
    #pragma unroll
    for (int rt=0;rt<2;++rt)
      #pragma unroll
      for (int r=0;r<4;++r) acc[rt][ct][r] += bv;
  }
  #pragma unroll
  for (int rt=0;rt<2;++rt)
    #pragma unroll
    for (int r=0;r<4;++r){
      float s  = acc[rt][0][r]+acc[rt][1][r]+acc[rt][2][r]+acc[rt][3][r];
      float ss = acc[rt][0][r]*acc[rt][0][r]+acc[rt][1][r]*acc[rt][1][r]
               + acc[rt][2][r]*acc[rt][2][r]+acc[rt][3][r]*acc[rt][3][r];
      s  = rowsum16(s);
      ss = rowsum16(ss);
      const float mu = s*(1.f/64.f);
      const float var = ss*(1.f/64.f) - mu*mu;
      const float rs = rsqrtf(var + 1e-5f);
      const size_t row = rb + rt*16 + quad*4 + r;
      #pragma unroll
      for (int ct=0;ct<4;++ct){
        const int n = ct*16 + mrow;
        out[row*64 + n] = (acc[rt][ct][r]-mu)*rs*g[n] + bt[n] + feat[row*64 + n];
      }
    }
}

// ---------------- launcher ----------------
extern "C" void kernel_launch(void* const* d_in, const int* in_sizes, int n_in,
                              void* d_out, int out_size, void* d_ws, size_t ws_size,
                              hipStream_t stream){
  const float* xyz    = (const float*)d_in[0];
  const float* feat   = (const float*)d_in[1];
  const float* W_pre  = (const float*)d_in[2];
  const float* b_pre  = (const float*)d_in[3];
  const float* W_post = (const float*)d_in[4];
  const float* b_post = (const float*)d_in[5];
  const float* Wp1    = (const float*)d_in[6];
  const float* Wp2    = (const float*)d_in[7];
  const float* Wa1    = (const float*)d_in[8];
  const float* Wa2    = (const float*)d_in[9];
  const float* WQ     = (const float*)d_in[10];
  const float* WK     = (const float*)d_in[11];
  const float* WV     = (const float*)d_in[12];
  const float* Wproj  = (const float*)d_in[13];
  const float* g_dm   = (const float*)d_in[14];
  const float* b_dm   = (const float*)d_in[15];
  const float* g_dp   = (const float*)d_in[16];
  const float* b_dp   = (const float*)d_in[17];
  float* out = (float*)d_out;
  if (ws_size < WS_NEED) return;
  char* ws = (char*)d_ws;
  int* idxw   = (int*)(ws + OFF_IDX);
  u16* featb  = (u16*)(ws + OFF_FEATB);
  u16* wpreb  = (u16*)(ws + OFF_WPRE);
  u16* wqkvb  = (u16*)(ws + OFF_WQKV);
  u16* wa1b   = (u16*)(ws + OFF_WA1);
  u16* wa2b   = (u16*)(ws + OFF_WA2);
  u16* wp2b   = (u16*)(ws + OFF_WP2);
  u16* wprojb = (u16*)(ws + OFF_WPROJ);
  u16* wpostb = (u16*)(ws + OFF_WPOST);
  u16* mcombb = (u16*)(ws + OFF_MCOMB);
  u16* inp    = (u16*)(ws + OFF_INP);
  u16* qkv    = (u16*)(ws + OFF_QKV);
  u16* lnqkv  = (u16*)(ws + OFF_LNQKV);
  u16* qab    = (u16*)(ws + OFF_QA);
  u16* kab    = (u16*)(ws + OFF_KA);
  u16* resb   = (u16*)(ws + OFF_RES);
  u16* d1raw  = (u16*)(ws + OFF_D1);
  u16* r1b    = (u16*)(ws + OFF_R1);
  u16* wp1pk  = (u16*)(ws + OFF_WP1PK);
  u16* wp2T   = (u16*)(ws + OFF_WP2T);

  convert_k<<<6081,256,0,stream>>>(feat,W_pre,WQ,WK,WV,Wa1,Wa2,Wp2,Wproj,W_post,Wp1,
                                   featb,wpreb,wqkvb,wa1b,wa2b,wp2b,wprojb,wpostb,
                                   wp1pk,wp2T);
  gemm128_k<<<dim3(2,2),256,0,stream>>>(wa1b,256, wp2T,256, mcombb,256, 256, nullptr, 0,0);
  knn_kernel<<<1024,256,0,stream>>>(xyz,idxw);
  gemm128_k<<<dim3(128,2),256,0,stream>>>(featb,64,  wpreb,64,  inp,256, 64,  b_pre, 0,0);
  gemm128_k<<<dim3(128,6),256,0,stream>>>(inp,256,   wqkvb,256, qkv,768, 256, nullptr, 0,0);
  ln256_k<<<12288,256,0,stream>>>(qkv,lnqkv,g_dm,b_dm);
  gemm128_k<<<dim3(128,2,2),256,0,stream>>>(lnqkv,768, wa1b,256, qab,256, 256, nullptr,
                                            256, 4194304);
  attn_k<<<4096,512,0,stream>>>(xyz,idxw,lnqkv,qab,kab,mcombb,wp2b,wa2b,wp1pk,resb);
  gemm128_k<<<dim3(128,2),256,0,stream>>>(resb,256, wprojb,256, d1raw,256, 256, nullptr, 0,0);
  ln256_k<<<4096,256,0,stream>>>(d1raw,r1b,g_dm,b_dm);
  d2_k<<<128,256,0,stream>>>(r1b,wpostb,b_post,g_dp,b_dp,feat,out);
}

// Round 12
// 531.584 us; speedup vs baseline: 1.5719x; 1.0166x over previous
//
#include <hip/hip_runtime.h>
#include <hip/hip_bf16.h>

typedef unsigned short u16;
typedef unsigned int   u32;
typedef __attribute__((ext_vector_type(8))) short bf16x8;
typedef __attribute__((ext_vector_type(4))) float f32x4;

#define MFMA16(a,b,c) __builtin_amdgcn_mfma_f32_16x16x32_bf16((a),(b),(c),0,0,0)

__device__ __forceinline__ float b2f(u32 h){ return __uint_as_float(h<<16); }
__device__ __forceinline__ u16 f2b(float f){
  u32 u = __float_as_uint(f);
  return (u16)((u + 0x7FFFu + ((u>>16)&1u))>>16);
}
// HW packed convert: v_cvt_pk_bf16_f32 (RNE)
__device__ __forceinline__ u32 pk2f(float a,float b){
  __hip_bfloat162 h = __float22bfloat162_rn(float2{a,b});
  return *reinterpret_cast<u32*>(&h);
}
__device__ __forceinline__ u32 umin32(u32 a,u32 b){ return a<b?a:b; }
__device__ __forceinline__ u32 umax32(u32 a,u32 b){ return a>b?a:b; }

// 16-lane row-sum on the VALU pipe via DPP row_ror (d2_k LN reduce)
template<int CTRL>
__device__ __forceinline__ float dpp_add(float x){
  int t = __builtin_amdgcn_update_dpp(0, __float_as_int(x), CTRL, 0xF, 0xF, true);
  return x + __int_as_float(t);
}
__device__ __forceinline__ float rowsum16(float x){
  x = dpp_add<0x121>(x);
  x = dpp_add<0x122>(x);
  x = dpp_add<0x124>(x);
  x = dpp_add<0x128>(x);
  return x;
}

__device__ __forceinline__ void async_copy16(const void* g, void* l){
  __builtin_amdgcn_global_load_lds((const __attribute__((address_space(1))) u32*)g,
                                   (__attribute__((address_space(3))) u32*)l, 16, 0, 0);
}

// ---------------- workspace layout (bytes) ----------------
#define OFF_IDX    0ull
#define OFF_FEATB  1048576ull
#define OFF_WPRE   3145728ull
#define OFF_WQKV   3178496ull
#define OFF_WA1    3571712ull
#define OFF_WA2    3702784ull
#define OFF_WP2    3833856ull
#define OFF_WPROJ  3964928ull
#define OFF_WPOST  4096000ull
#define OFF_MCOMB  4128768ull
#define OFF_INP    4259840ull
#define OFF_QKV    12648448ull
#define OFF_LNQKV  37814272ull
#define OFF_QA     62980096ull
#define OFF_KA     71368704ull
#define OFF_RES    79757312ull
#define OFF_D1     88145920ull     // also hosts wp1pk early (d1 written only after attn)
#define OFF_R1     96534528ull
#define WS_NEED    104923136ull
#define OFF_WP1PK  OFF_D1
#define OFF_WP2T   OFF_QKV         // wp2^T consumed by mcomb GEMM before qkv GEMM writes here

// ---------------- f32 -> bf16 conversions + wp1 pack + wp2 transpose (fused) ----------------
__global__ void convert_k(const float* __restrict__ feat, const float* __restrict__ wpre,
    const float* __restrict__ wq, const float* __restrict__ wk, const float* __restrict__ wv,
    const float* __restrict__ wa1, const float* __restrict__ wa2, const float* __restrict__ wp2,
    const float* __restrict__ wproj, const float* __restrict__ wpost,
    const float* __restrict__ wp1,
    u16* __restrict__ dfeat, u16* __restrict__ dwpre, u16* __restrict__ dwqkv,
    u16* __restrict__ dwa1, u16* __restrict__ dwa2, u16* __restrict__ dwp2,
    u16* __restrict__ dwproj, u16* __restrict__ dwpost,
    u16* __restrict__ dwp1pk, u16* __restrict__ dwp2T){
  __shared__ u16 t[32][33];
  const int bid = blockIdx.x, tid = threadIdx.x;
  if (bid < 6016){
    int id = bid*256 + tid;
    const float* s; u16* d; int off;
    if      (id < 1048576){ s=feat;  d=dfeat;        off=id; }
    else if (id < 1064960){ s=wpre;  d=dwpre;        off=id-1048576; }
    else if (id < 1130496){ s=wq;    d=dwqkv;        off=id-1064960; }
    else if (id < 1196032){ s=wk;    d=dwqkv+65536;  off=id-1130496; }
    else if (id < 1261568){ s=wv;    d=dwqkv+131072; off=id-1196032; }
    else if (id < 1327104){ s=wa1;   d=dwa1;         off=id-1261568; }
    else if (id < 1392640){ s=wa2;   d=dwa2;         off=id-1327104; }
    else if (id < 1458176){ s=wp2;   d=dwp2;         off=id-1392640; }
    else if (id < 1523712){ s=wproj; d=dwproj;       off=id-1458176; }
    else if (id < 1540096){ s=wpost; d=dwpost;       off=id-1523712; }
    else return;
    d[off] = f2b(s[off]);
  } else if (bid == 6016){
    const int h = tid;
    const float w0 = wp1[h*3], w1 = wp1[h*3+1], w2 = wp1[h*3+2];
    uint4 a; a.x = pk2f(w0,w1); a.y = pk2f(w2,0.f); a.z = 0u; a.w = 0u;
    uint4 z; z.x = z.y = z.z = z.w = 0u;
    *(uint4*)&dwp1pk[h*32]    = a;
    *(uint4*)&dwp1pk[h*32+8]  = z;
    *(uint4*)&dwp1pk[h*32+16] = z;
    *(uint4*)&dwp1pk[h*32+24] = z;
  } else {
    const int tb = bid - 6017;
    const int bx = tb & 7, by = tb >> 3;
    const int tx = tid & 31, ty = tid >> 5;
    #pragma unroll
    for (int r = 0; r < 4; ++r) t[ty+8*r][tx] = f2b(wp2[(by*32+ty+8*r)*256 + bx*32+tx]);
    __syncthreads();
    #pragma unroll
    for (int r = 0; r < 4; ++r) dwp2T[(bx*32+ty+8*r)*256 + by*32+tx] = t[tx][ty+8*r];
  }
}

// ---------------- kNN: exact top-16 by (d2, idx) ----------------
__device__ __forceinline__ void ins16(u32 (&a)[16], u32 key){
  #pragma unroll
  for (int j = 15; j >= 1; --j) a[j] = umin32(umax32(a[j-1],key), a[j]);
  a[0] = umin32(a[0], key);
}

__device__ __forceinline__ float dist2(float ax,float ay,float az,float bx,float by,float bz){
  const float dx = ax-bx, dy = ay-by, dz = az-bz;
  return __fmaf_rn(dx,dx, __fmaf_rn(dy,dy, dz*dz));
}

__global__ __launch_bounds__(256,3) void knn_kernel(const float* __restrict__ xyz,
                                                    int* __restrict__ idxout){
  __shared__ __attribute__((aligned(16))) float sbuf[3*4104];
  __shared__ int lcnt[16];
  __shared__ int tcnt[16];
  __shared__ u32 tbuf[16];
  __shared__ int tiebuf[16*16];
  float* sx = sbuf; float* sy = sbuf + 4104; float* sz = sbuf + 8208;
  const int tid = threadIdx.x;
  const int b  = blockIdx.x >> 8;
  const int n0 = (blockIdx.x & 255) << 4;
  const float* base = xyz + (size_t)b*12288;
  #pragma unroll
  for (int i = 0; i < 12; ++i){
    const float4 v = *(const float4*)(base + tid*48 + i*4);
    const float vv[4] = {v.x, v.y, v.z, v.w};
    #pragma unroll
    for (int j = 0; j < 4; ++j){
      const int e = i*4 + j;
      const int c = e % 3;
      const int m = tid*16 + e/3;
      float* arr = (c==0)?sx:((c==1)?sy:sz);
      arr[m + (m>>9)] = vv[j];
    }
  }
  if (tid < 16){ lcnt[tid] = 0; tcnt[tid] = 0; }
  __syncthreads();
  const int qi = tid >> 4, p = tid & 15;
  const int n = n0 + qi;
  const int sn = n + (n>>9);
  const float qx = sx[sn], qy = sy[sn], qz = sz[sn];
  u32 a[16];
  #pragma unroll
  for (int j = 0; j < 16; ++j) a[j] = 0xFFFFFFFFu;
  const int sb = p*256 + (p>>1);
  #pragma unroll 2
  for (int i = 0; i < 256; ++i){
    const float d2 = dist2(sx[sb+i],sy[sb+i],sz[sb+i],qx,qy,qz);
    ins16(a, __float_as_uint(d2));
  }
  #pragma unroll
  for (int s = 8; s >= 1; s >>= 1){
    u32 o[16];
    #pragma unroll
    for (int j = 0; j < 16; ++j) o[j] = __shfl_down(a[j], (unsigned)s, 64);
    if (p < s){
      #pragma unroll
      for (int j = 0; j < 16; ++j) ins16(a, o[j]);
    }
  }
  if (p == 0) tbuf[qi] = a[15];
  __syncthreads();
  const u32 T = tbuf[qi];
  int* orow = idxout + ((size_t)(b<<12)+n)*16;
  const int gbase = p*256;
  for (int i = 0; i < 256; ++i){
    const float d2 = dist2(sx[sb+i],sy[sb+i],sz[sb+i],qx,qy,qz);
    const u32 kb = __float_as_uint(d2);
    if (kb < T){
      const int pos = atomicAdd(&lcnt[qi],1);
      if (pos < 16) orow[pos] = gbase + i;
    } else if (kb == T){
      const int t = atomicAdd(&tcnt[qi],1);
      if (t < 16) tiebuf[qi*16+t] = gbase + i;
    }
  }
  __syncthreads();
  if (p == 0){
    int L = lcnt[qi]; if (L > 16) L = 16;
    int tc = tcnt[qi]; if (tc > 16) tc = 16;
    const int need = 16 - L;
    for (int r = 0; r < need; ++r){
      int best = 0x7FFFFFFF, bj = -1;
      for (int j = 0; j < tc; ++j){
        const int v = tiebuf[qi*16+j];
        if (v < best){ best = v; bj = j; }
      }
      if (bj >= 0){ tiebuf[qi*16+bj] = 0x7FFFFFFF; orow[L+r] = best; }
      else orow[L+r] = n;
    }
  }
}

// ---------------- generic 128x128 bf16 GEMM: C[m][n] = sum_k A[m][k]*B[n][k] (+bias) ----------------
__global__ __launch_bounds__(256,2) void gemm128_k(
    const u16* __restrict__ A, const int lda,
    const u16* __restrict__ Bw, const int ldb,
    u16* __restrict__ C, const int ldc,
    const int K, const float* __restrict__ bias,
    const size_t zA, const size_t zC){
  __shared__ __attribute__((aligned(16))) u16 As[128*32];
  __shared__ __attribute__((aligned(16))) u16 Bs[128*32];
  A += blockIdx.z * zA;
  C += blockIdx.z * zC;
  const int tid = threadIdx.x, lane = tid & 63, w = tid >> 6;
  const int mrow = lane & 15, quad = lane >> 4;
  const size_t mbase = (size_t)blockIdx.x*128, nbase = (size_t)blockIdx.y*128;
  const int wr = (w&1)*64, wc = (w>>1)*64;
  f32x4 acc[4][4];
  #pragma unroll
  for (int i=0;i<4;++i)
    #pragma unroll
    for (int j=0;j<4;++j)
      #pragma unroll
      for (int r=0;r<4;++r) acc[i][j][r] = 0.f;
  const int sr = tid >> 2, sk = (tid & 3)*8;
  u16* lA0 = &As[w*512]; u16* lA1 = &As[2048 + w*512];
  u16* lB0 = &Bs[w*512]; u16* lB1 = &Bs[2048 + w*512];
  for (int k0 = 0; k0 < K; k0 += 32){
    __syncthreads();
    async_copy16(A  + (mbase      + sr)*(size_t)lda + k0 + sk, lA0);
    async_copy16(A  + (mbase + 64 + sr)*(size_t)lda + k0 + sk, lA1);
    async_copy16(Bw + (nbase      + sr)*(size_t)ldb + k0 + sk, lB0);
    async_copy16(Bw + (nbase + 64 + sr)*(size_t)ldb + k0 + sk, lB1);
    __syncthreads();
    bf16x8 af[4], bf[4];
    #pragma unroll
    for (int rt=0;rt<4;++rt) af[rt] = *(const bf16x8*)&As[(wr+rt*16+mrow)*32 + quad*8];
    #pragma unroll
    for (int ct=0;ct<4;++ct) bf[ct] = *(const bf16x8*)&Bs[(wc+ct*16+mrow)*32 + quad*8];
    #pragma unroll
    for (int rt=0;rt<4;++rt)
      #pragma unroll
      for (int ct=0;ct<4;++ct) acc[rt][ct] = MFMA16(af[rt], bf[ct], acc[rt][ct]);
  }
  #pragma unroll
  for (int rt=0;rt<4;++rt)
    #pragma unroll
    for (int ct=0;ct<4;++ct){
      const size_t row0 = mbase + wr + rt*16 + quad*4;
      const int col = (int)nbase + wc + ct*16 + mrow;
      const float bv = bias ? bias[col] : 0.f;
      #pragma unroll
      for (int r=0;r<4;++r) C[(row0+r)*(size_t)ldc + col] = f2b(acc[rt][ct][r] + bv);
    }
}

// ---------------- LayerNorm over 256-element groups, bf16 in/out ----------------
__global__ __launch_bounds__(256,2) void ln256_k(const u16* __restrict__ in, u16* __restrict__ out,
    const float* __restrict__ g, const float* __restrict__ bta){
  const int tid = threadIdx.x, lane = tid & 63, w = tid >> 6;
  const size_t row = (size_t)blockIdx.x*4 + w;
  const uint2 u = *(const uint2*)(in + row*256 + lane*4);
  const float x0=b2f(u.x&0xffff), x1=b2f(u.x>>16), x2=b2f(u.y&0xffff), x3=b2f(u.y>>16);
  float s  = x0+x1+x2+x3;
  float ss = x0*x0+x1*x1+x2*x2+x3*x3;
  #pragma unroll
  for (int mk=1; mk<64; mk<<=1){ s += __shfl_xor(s,mk,64); ss += __shfl_xor(ss,mk,64); }
  const float mu = s*(1.f/256.f);
  const float var = ss*(1.f/256.f) - mu*mu;
  const float rs = rsqrtf(var + 1e-5f);
  const int c = lane*4;
  const float y0=(x0-mu)*rs*g[c  ]+bta[c  ];
  const float y1=(x1-mu)*rs*g[c+1]+bta[c+1];
  const float y2=(x2-mu)*rs*g[c+2]+bta[c+2];
  const float y3=(x3-mu)*rs*g[c+3]+bta[c+3];
  uint2 o; o.x = pk2f(y0,y1); o.y = pk2f(y2,y3);
  *(uint2*)(out + row*256 + lane*4) = o;
}

// ---------------- fused per-neighbor attention kernel (v12: merged G1+G2a k-loop) ----------------
// block = 64 rows (4 queries x 16), 512 threads = 8 waves, wave w owns f-slice [w*32,w*32+32).
// Single merged k-loop computes at (normal: D[f][m]) AND av (flipped: D[m][g]) from the same
// bH fragments: 8 loads -> 16 MFMAs per k-step (v11 had 12 loads over two loops).
// al (G2b from h2) flipped, unroll 2. 3 barriers. 64 AGPR + ~48 VGPR fits (512,4) budget.
#define DP   264
#define RELP 40
__global__ __launch_bounds__(512,4) void attn_k(
    const float* __restrict__ xyz, const int* __restrict__ idxb,
    const u16* __restrict__ lnqkv, const u16* __restrict__ qa, const u16* __restrict__ ka,
    const u16* __restrict__ mcomb, const u16* __restrict__ wp2, const u16* __restrict__ wa2,
    const u16* __restrict__ wp1pk, u16* __restrict__ res){
  __shared__ __attribute__((aligned(16))) u16 h1buf[64*DP];   // h1 (33.8 KB)
  __shared__ __attribute__((aligned(16))) u16 h2buf[64*DP];   // h2 (33.8 KB)
  __shared__ __attribute__((aligned(16))) u16 srel[64*RELP];  // rel bf16, k-padded to 32
  __shared__ int sidx[64];
  const int tid = threadIdx.x;
  const int b = blockIdx.x >> 10;
  const int nbase = (blockIdx.x & 1023) << 2;
  const size_t gb = (size_t)b << 12;
  // ---- stage neighbor idx + rel
  if (tid < 64){
    const int m = tid;
    const int im = idxb[(gb + nbase + (m>>4))*16 + (m&15)] & 4095;
    sidx[m] = im;
    const int nn = nbase + (m>>4);
    const float* pq = xyz + (gb+nn)*3;
    const float* pm = xyz + (gb+im)*3;
    const float rx = pq[0]-pm[0], ry = pq[1]-pm[1], rz = pq[2]-pm[2];
    uint4 a; a.x = pk2f(rx,ry); a.y = pk2f(rz,0.f); a.z = 0u; a.w = 0u;
    uint4 z; z.x = z.y = z.z = z.w = 0u;
    *(uint4*)&srel[m*RELP]    = a;
    *(uint4*)&srel[m*RELP+8]  = z;
    *(uint4*)&srel[m*RELP+16] = z;
    *(uint4*)&srel[m*RELP+24] = z;
  }
  __syncthreads();
  const int lane = tid & 63, w = tid >> 6;
  const int mrow = lane & 15, quad = lane >> 4;
  const int fr = w << 5;                         // 32-wide f/h slice of this wave
  // ---- h1 via MFMA: D[h][m] for h in [fr,fr+32), m in [0,64) -> h1buf[m][h]
  {
    bf16x8 aW[2], bR[4];
    #pragma unroll
    for (int ht=0;ht<2;++ht) aW[ht] = *(const bf16x8*)&wp1pk[(fr+ht*16+mrow)*32 + quad*8];
    #pragma unroll
    for (int mt=0;mt<4;++mt) bR[mt] = *(const bf16x8*)&srel[(mt*16+mrow)*RELP + quad*8];
    #pragma unroll
    for (int ht=0;ht<2;++ht)
      #pragma unroll
      for (int mt=0;mt<4;++mt){
        f32x4 hz;
        #pragma unroll
        for (int r=0;r<4;++r) hz[r]=0.f;
        hz = MFMA16(aW[ht], bR[mt], hz);
        float h0 = hz[0]>0.f?hz[0]:0.f, h1v = hz[1]>0.f?hz[1]:0.f;
        float h2v = hz[2]>0.f?hz[2]:0.f, h3 = hz[3]>0.f?hz[3]:0.f;
        uint2 o; o.x = pk2f(h0,h1v); o.y = pk2f(h2v,h3);
        *(uint2*)&h1buf[(mt*16+mrow)*DP + fr + ht*16 + quad*4] = o;
      }
  }
  int midx[4];
  #pragma unroll
  for (int mt = 0; mt < 4; ++mt) midx[mt] = sidx[mt*16 + mrow];
  __syncthreads();             // h1 complete
  // ---- merged G1+G2a: at.T = Mcomb @ h1.T (D[f][m]) and av = h1 @ Wp2.T (flipped D[m][g])
  f32x4 at[2][4], av[2][4];
  #pragma unroll
  for (int i=0;i<2;++i)
    #pragma unroll
    for (int j=0;j<4;++j)
      #pragma unroll
      for (int r=0;r<4;++r){ at[i][j][r]=0.f; av[i][j][r]=0.f; }
  #pragma unroll 1
  for (int ks = 0; ks < 8; ++ks){
    const int koff = ks*32 + quad*8;
    bf16x8 aM[2], aP[2], bH[4];
    #pragma unroll
    for (int ft=0;ft<2;++ft){
      aM[ft] = *(const bf16x8*)&mcomb[(fr+ft*16+mrow)*256 + koff];
      aP[ft] = *(const bf16x8*)&wp2  [(fr+ft*16+mrow)*256 + koff];
    }
    #pragma unroll
    for (int mt=0;mt<4;++mt) bH[mt] = *(const bf16x8*)&h1buf[(mt*16+mrow)*DP + koff];
    #pragma unroll
    for (int ft=0;ft<2;++ft)
      #pragma unroll
      for (int mt=0;mt<4;++mt){
        at[ft][mt] = MFMA16(aM[ft], bH[mt], at[ft][mt]);
        av[ft][mt] = MFMA16(bH[mt], aP[ft], av[ft][mt]);
      }
  }
  // ---- qkp gather (latency hidden under epilogue/barrier)
  uint2 qkp[2][4];
  #pragma unroll
  for (int ft = 0; ft < 2; ++ft)
    #pragma unroll
    for (int mt = 0; mt < 4; ++mt){
      const int f = fr + ft*16 + quad*4;
      const uint2 uq = *(const uint2*)&qa[(gb + nbase + mt)*256 + f];
      const uint2 uk = *(const uint2*)&ka[(gb + (size_t)midx[mt])*256 + f];
      uint2 o;
      o.x = pk2f(b2f(uq.x&0xffff)-b2f(uk.x&0xffff), b2f(uq.x>>16)-b2f(uk.x>>16));
      o.y = pk2f(b2f(uq.y&0xffff)-b2f(uk.y&0xffff), b2f(uq.y>>16)-b2f(uk.y>>16));
      qkp[ft][mt] = o;
    }
  // ---- epilogue: h2 = relu(at + (qa-ka)) -> h2buf (at regs freed)
  #pragma unroll
  for (int ft=0;ft<2;++ft)
    #pragma unroll
    for (int mt=0;mt<4;++mt){
      const int moff = (mt*16+mrow)*DP + fr + ft*16 + quad*4;
      const uint2 qv = qkp[ft][mt];
      float t0 = at[ft][mt][0] + b2f(qv.x&0xffff);
      float t1 = at[ft][mt][1] + b2f(qv.x>>16);
      float t2 = at[ft][mt][2] + b2f(qv.y&0xffff);
      float t3 = at[ft][mt][3] + b2f(qv.y>>16);
      t0 = t0>0.f?t0:0.f; t1 = t1>0.f?t1:0.f; t2 = t2>0.f?t2:0.f; t3 = t3>0.f?t3:0.f;
      uint2 o; o.x = pk2f(t0,t1); o.y = pk2f(t2,t3);
      *(uint2*)&h2buf[moff] = o;
    }
  __syncthreads();             // h2 complete
  // ---- G2b: al = h2 @ Wa2.T  FLIPPED: D[m][g] (32-AGPR phase; unroll 2 for load pipelining)
  f32x4 al[2][4];
  #pragma unroll
  for (int i=0;i<2;++i)
    #pragma unroll
    for (int j=0;j<4;++j)
      #pragma unroll
      for (int r=0;r<4;++r) al[i][j][r]=0.f;
  #pragma unroll 2
  for (int ks = 0; ks < 8; ++ks){
    const int koff = ks*32 + quad*8;
    bf16x8 aW[2], bH[4];
    #pragma unroll
    for (int gt=0;gt<2;++gt) aW[gt] = *(const bf16x8*)&wa2[(fr+gt*16+mrow)*256 + koff];
    #pragma unroll
    for (int mt=0;mt<4;++mt) bH[mt] = *(const bf16x8*)&h2buf[(mt*16+mrow)*DP + koff];
    #pragma unroll
    for (int gt=0;gt<2;++gt)
      #pragma unroll
      for (int mt=0;mt<4;++mt) al[gt][mt] = MFMA16(bH[mt], aW[gt], al[gt][mt]);
  }
  // ---- v gather in flipped layout: per (mt,r): row = sidx[mt*16+quad*4+r], col = fr+gt*16+mrow
  int4 si[4];
  #pragma unroll
  for (int mt=0;mt<4;++mt) si[mt] = *(const int4*)&sidx[mt*16 + quad*4];
  u16 vv[2][4][4];
  #pragma unroll
  for (int mt=0;mt<4;++mt){
    const int rows[4] = {si[mt].x, si[mt].y, si[mt].z, si[mt].w};
    #pragma unroll
    for (int r=0;r<4;++r){
      const size_t rb = (gb + (size_t)rows[r])*768 + 512 + fr + mrow;
      vv[0][mt][r] = lnqkv[rb];
      vv[1][mt][r] = lnqkv[rb + 16];
    }
  }
  // ---- softmax over k = quad*4+reg (in-lane + cross-quad) + weighted reduce
  const float sc = 0.0901684f;   // log2(e)/sqrt(256)
  #pragma unroll
  for (int gt=0;gt<2;++gt)
    #pragma unroll
    for (int mt=0;mt<4;++mt){
      float prs = 0.f, wgs = 0.f;
      #pragma unroll
      for (int r=0;r<4;++r){
        const float val = av[gt][mt][r] + b2f((u32)vv[gt][mt][r]);
        const float pr = exp2f(al[gt][mt][r]*sc);
        prs += pr;
        wgs += pr*val;
      }
      prs += __shfl_xor(prs, 16, 64); prs += __shfl_xor(prs, 32, 64);
      wgs += __shfl_xor(wgs, 16, 64); wgs += __shfl_xor(wgs, 32, 64);
      const float rv = wgs * __builtin_amdgcn_rcpf(prs);
      if (quad == 0)
        res[(gb + nbase + mt)*256 + fr + gt*16 + mrow] = f2b(rv);
    }
}

// ---------------- final: out = ln(r1 @ W_post.T + b_post)*g+b + features ----------------
__global__ __launch_bounds__(256,2) void d2_k(
    const u16* __restrict__ r1, const u16* __restrict__ wpost,
    const float* __restrict__ bpost, const float* __restrict__ g, const float* __restrict__ bt,
    const float* __restrict__ feat, float* __restrict__ out){
  const int tid = threadIdx.x, lane = tid & 63, w = tid >> 6;
  const int mrow = lane & 15, quad = lane >> 4;
  const size_t rb = (size_t)blockIdx.x*128 + w*32;
  f32x4 acc[2][4];
  #pragma unroll
  for (int i=0;i<2;++i)
    #pragma unroll
    for (int j=0;j<4;++j)
      #pragma unroll
      for (int r=0;r<4;++r) acc[i][j][r]=0.f;
  #pragma unroll 1
  for (int ks = 0; ks < 8; ++ks){
    const int koff = ks*32 + quad*8;
    bf16x8 af[2], bf[4];
    #pragma unroll
    for (int rt=0;rt<2;++rt) af[rt] = *(const bf16x8*)&r1[(rb+rt*16+mrow)*256 + koff];
    #pragma unroll
    for (int ct=0;ct<4;++ct) bf[ct] = *(const bf16x8*)&wpost[(ct*16+mrow)*256 + koff];
    #pragma unroll
    for (int rt=0;rt<2;++rt)
      #pragma unroll
      for (int ct=0;ct<4;++ct) acc[rt][ct] = MFMA16(af[rt], bf[ct], acc[rt][ct]);
  }
  #pragma unroll
  for (int ct=0;ct<4;++ct){
    const float bv = bpost[ct*16+mrow];
    #pragma unroll
    for (int rt=0;rt<2;++rt)
      #pragma unroll
      for (int r=0;r<4;++r) acc[rt][ct][r] += bv;
  }
  #pragma unroll
  for (int rt=0;rt<2;++rt)
    #pragma unroll
    for (int r=0;r<4;++r){
      float s  = acc[rt][0][r]+acc[rt][1][r]+acc[rt][2][r]+acc[rt][3][r];
      float ss = acc[rt][0][r]*acc[rt][0][r]+acc[rt][1][r]*acc[rt][1][r]
               + acc[rt][2][r]*acc[rt][2][r]+acc[rt][3][r]*acc[rt][3][r];
      s  = rowsum16(s);
      ss = rowsum16(ss);
      const float mu = s*(1.f/64.f);
      const float var = ss*(1.f/64.f) - mu*mu;
      const float rs = rsqrtf(var + 1e-5f);
      const size_t row = rb + rt*16 + quad*4 + r;
      #pragma unroll
      for (int ct=0;ct<4;++ct){
        const int n = ct*16 + mrow;
        out[row*64 + n] = (acc[rt][ct][r]-mu)*rs*g[n] + bt[n] + feat[row*64 + n];
      }
    }
}

// ---------------- launcher ----------------
extern "C" void kernel_launch(void* const* d_in, const int* in_sizes, int n_in,
                              void* d_out, int out_size, void* d_ws, size_t ws_size,
                              hipStream_t stream){
  const float* xyz    = (const float*)d_in[0];
  const float* feat   = (const float*)d_in[1];
  const float* W_pre  = (const float*)d_in[2];
  const float* b_pre  = (const float*)d_in[3];
  const float* W_post = (const float*)d_in[4];
  const float* b_post = (const float*)d_in[5];
  const float* Wp1    = (const float*)d_in[6];
  const float* Wp2    = (const float*)d_in[7];
  const float* Wa1    = (const float*)d_in[8];
  const float* Wa2    = (const float*)d_in[9];
  const float* WQ     = (const float*)d_in[10];
  const float* WK     = (const float*)d_in[11];
  const float* WV     = (const float*)d_in[12];
  const float* Wproj  = (const float*)d_in[13];
  const float* g_dm   = (const float*)d_in[14];
  const float* b_dm   = (const float*)d_in[15];
  const float* g_dp   = (const float*)d_in[16];
  const float* b_dp   = (const float*)d_in[17];
  float* out = (float*)d_out;
  if (ws_size < WS_NEED) return;
  char* ws = (char*)d_ws;
  int* idxw   = (int*)(ws + OFF_IDX);
  u16* featb  = (u16*)(ws + OFF_FEATB);
  u16* wpreb  = (u16*)(ws + OFF_WPRE);
  u16* wqkvb  = (u16*)(ws + OFF_WQKV);
  u16* wa1b   = (u16*)(ws + OFF_WA1);
  u16* wa2b   = (u16*)(ws + OFF_WA2);
  u16* wp2b   = (u16*)(ws + OFF_WP2);
  u16* wprojb = (u16*)(ws + OFF_WPROJ);
  u16* wpostb = (u16*)(ws + OFF_WPOST);
  u16* mcombb = (u16*)(ws + OFF_MCOMB);
  u16* inp    = (u16*)(ws + OFF_INP);
  u16* qkv    = (u16*)(ws + OFF_QKV);
  u16* lnqkv  = (u16*)(ws + OFF_LNQKV);
  u16* qab    = (u16*)(ws + OFF_QA);
  u16* kab    = (u16*)(ws + OFF_KA);
  u16* resb   = (u16*)(ws + OFF_RES);
  u16* d1raw  = (u16*)(ws + OFF_D1);
  u16* r1b    = (u16*)(ws + OFF_R1);
  u16* wp1pk  = (u16*)(ws + OFF_WP1PK);
  u16* wp2T   = (u16*)(ws + OFF_WP2T);

  convert_k<<<6081,256,0,stream>>>(feat,W_pre,WQ,WK,WV,Wa1,Wa2,Wp2,Wproj,W_post,Wp1,
                                   featb,wpreb,wqkvb,wa1b,wa2b,wp2b,wprojb,wpostb,
                                   wp1pk,wp2T);
  gemm128_k<<<dim3(2,2),256,0,stream>>>(wa1b,256, wp2T,256, mcombb,256, 256, nullptr, 0,0);
  knn_kernel<<<1024,256,0,stream>>>(xyz,idxw);
  gemm128_k<<<dim3(128,2),256,0,stream>>>(featb,64,  wpreb,64,  inp,256, 64,  b_pre, 0,0);
  gemm128_k<<<dim3(128,6),256,0,stream>>>(inp,256,   wqkvb,256, qkv,768, 256, nullptr, 0,0);
  ln256_k<<<12288,256,0,stream>>>(qkv,lnqkv,g_dm,b_dm);
  gemm128_k<<<dim3(128,2,2),256,0,stream>>>(lnqkv,768, wa1b,256, qab,256, 256, nullptr,
                                            256, 4194304);
  attn_k<<<4096,512,0,stream>>>(xyz,idxw,lnqkv,qab,kab,mcombb,wp2b,wa2b,wp1pk,resb);
  gemm128_k<<<dim3(128,2),256,0,stream>>>(resb,256, wprojb,256, d1raw,256, 256, nullptr, 0,0);
  ln256_k<<<4096,256,0,stream>>>(d1raw,r1b,g_dm,b_dm);
  d2_k<<<128,256,0,stream>>>(r1b,wpostb,b_post,g_dp,b_dp,feat,out);
}